// Round 2
// baseline (834.540 us; speedup 1.0000x reference)
//
#include <hip/hip_runtime.h>
#include <math.h>

// Mamba block, fp32, single-scan + closed-form seeding + fused epilogue.
// k_pre  : M = w_cls@w_out (10x82) into ws.
// k0_feat: features once + local scan -> per-pos (yloc, Dp, C) record staged in
//          LDS, then ONE batched float4 writeout per subtile.
// k2_comb: sequential combine over tiles -> Hin per tile (carry across phases).
// k4_out : z-proj, closed-form corr, gate, fused M-GEMM logits.
// R9 (this round):
//  - launch_bounds (256,2): empirical VGPR cap = 512/(2n) -> 128. R8's (256,4)
//    pinned VGPR=64 and SPILLED the 21-reg weight array (FETCH 50->210MB).
//    Reg-weights kept; spill should vanish.
//  - k0: D2 (dt_proj) folded into scan E (delta computed inline from s_db
//    cols 0..3, w_dt in 3 regs): -1 barrier/subtile, -s_dtw/s_dtb LDS.
//  - k0 E: software-pipelined (prefetch next-l dt/B/C/xc before exp/fma chain).
//  - k4 C: break->predication + hoist 12 feat loads (L2-miss latency overlap).
// HARD-WON CONSTRAINTS:
//  - launch_bounds 2nd arg n caps VGPR ~512/(2n): (256,6)->40 (R6 spill),
//    (256,4)->64 (R8 spill with wreg). Use (256,2) when reg arrays present.
//  - R8 lesson: raising LDS block-ceiling 4->6 did NOT raise achieved
//    occupancy (43%) — kernels are LDS-pipe/latency bound, not residency.
//  - shared per-item weights (conv) stay in LDS; per-COLUMN weights ->
//    registers (k-split across the 2-thread pair).
// OLD path (proven): fallback if ws too small.

namespace {
constexpr int DMODEL=41, DIN=82, NSTATE=16, NLAB=10, BATCH=32, SEQ=8192;
// old path
constexpr int CHUNK=512, NCHUNK=SEQ/CHUNK, TSUB=16, NSUB=CHUNK/TSUB, RWS=TSUB+3;
constexpr int XPAD=44, SPAD=83, CPAD=84, JPAD=36;
constexpr int NPH_OLD = BATCH*NCHUNK*DIN*NSTATE;
// new path
constexpr int T0 = 64;              // positions per k0/k4 tile
constexpr int FREC = 184;           // yloc@0(82+2pad) | Dp@84(82+2pad) | C@168(16)
inline size_t tier_bytes(int P){
  size_t SEG = (size_t)SEQ/P, tiles = SEG/T0;
  return ((size_t)BATCH*SEG*FREC + 3*((size_t)BATCH*tiles*1312)
          + (size_t)BATCH*1312 + 4096)*4;
}
}

__device__ __forceinline__ float siluf(float v)     { return v / (1.f + expf(-v)); }
__device__ __forceinline__ float softplusf(float v) { return (v > 20.f) ? v : log1pf(expf(v)); }
// fast variants (validated R4/R5: absmax unchanged)
__device__ __forceinline__ float silu_f(float v){
  return v * __builtin_amdgcn_rcpf(1.f + __expf(-v));
}
__device__ __forceinline__ float softplus_f(float v){
  return (v > 20.f) ? v : __logf(1.f + __expf(v));
}

// ============================================================================
// NEW PATH
// ============================================================================

__global__ __launch_bounds__(256) void k_pre(
    const float* __restrict__ w_out, const float* __restrict__ w_cls,
    float* __restrict__ M){
  const int w = blockIdx.x*256 + threadIdx.x;
  if (w < NLAB*DIN){
    const int n = w/82, dd = w - n*82;
    float a = 0.f;
#pragma unroll
    for (int dm=0;dm<41;dm++) a = fmaf(w_cls[n*41+dm], w_out[dm*82+dd], a);
    M[w] = a;
  }
}

__launch_bounds__(256, 2)
__global__ void k0_feat(
    const float* __restrict__ xg, const float* __restrict__ w_in,
    const float* __restrict__ w_conv, const float* __restrict__ b_conv,
    const float* __restrict__ w_xproj, const float* __restrict__ w_dt,
    const float* __restrict__ b_dt, const float* __restrict__ A_log,
    const float* __restrict__ Dvec, int off, int SEG,
    float* __restrict__ feat, float* __restrict__ Pg, float* __restrict__ Hg)
{
  __shared__ float s_x[19*44];    // raw x rows (pos p0-3 .. p0+15)
  __shared__ float s_xs[19*82];   // xs rows incl conv halo
  __shared__ float s_xc[16*84];   // xc (pad 84); scan overwrites with yloc
  __shared__ float s_q[16*84];    // scan stages Dp here (pad 84)
  __shared__ float s_db[16*36];   // dt@0..2, B@4..19, C@20..35
  __shared__ float s_cw[4*82];    // conv w transposed [k][d]
  __shared__ float s_cb[82], s_A0[82], s_Dv[82];
  __shared__ int   s_flag[82];
  // ~24.7 KB

  const int tid = threadIdx.x;
  const int tile = blockIdx.x, b = blockIdx.y;
  const int base_pos = off + tile*T0;

  for (int i=tid;i<328;i+=256){ int dd=i/4,k=i-dd*4; s_cw[k*82+dd]=w_conv[i]; }
  if (tid<82){
    s_cb[tid]=b_conv[tid]; s_Dv[tid]=Dvec[tid];
    float A0=-expf(A_log[tid*16]); s_A0[tid]=A0;
    bool ok=(A0<0.f);
#pragma unroll
    for (int s=1;s<16;s++){
      float As=-expf(A_log[tid*16+s]);
      ok = ok && (fabsf(As-(float)(s+1)*A0) <= 1e-3f*(float)(s+1)*fabsf(A0));
    }
    s_flag[tid]=ok?1:0;
  }

  const int d = tid>>1, sg = tid&1;
  // in_proj xs-half weights in REGISTERS, k-split across the column pair:
  //   sg=0 -> k=0..19 (wreg[0..19], wreg[20]=0), sg=1 -> k=20..40 (wreg[0..20])
  float wreg[21];
#pragma unroll
  for (int t=0;t<21;t++) wreg[t]=0.f;
  // dt_proj weights per-column in registers (D2 folded into scan)
  float dtw0=0.f, dtw1=0.f, dtw2=0.f, dtb=0.f;
  if (tid<164){
#pragma unroll
    for (int t=0;t<21;t++){
      if (sg)          wreg[t]=w_in[d*41+20+t];
      else if (t<20)   wreg[t]=w_in[d*41+t];
    }
    dtw0=w_dt[d*3+0]; dtw1=w_dt[d*3+1]; dtw2=w_dt[d*3+2];
    dtb=b_dt[d];
  }
  __syncthreads();

  float h[8], A0d=-1.f, Dp=0.f;
  int flag=1;
  if (tid<164){
    flag = s_flag[d]; A0d = s_A0[d];
#pragma unroll
    for (int i=0;i<8;i++) h[i]=0.f;
  }

  for (int it=0; it<T0/16; ++it){
    const int p0 = base_pos + it*16;
    // ---- A: halo shift + raw x load ----
    if (it>0){
      for (int i=tid;i<246;i+=256){ int r=i/82, dd=i-r*82; s_xs[r*82+dd]=s_xs[(16+r)*82+dd]; }
    }
    {
      const int rlo=(it==0)?0:3, cnt=(19-rlo)*41;
      for (int i=tid;i<cnt;i+=256){
        int r=rlo+i/41, k=i-(i/41)*41;
        int pos=p0-3+r;
        s_x[r*44+k] = (pos>=0) ? xg[((size_t)b*SEQ+(size_t)pos)*41+k] : 0.f;
      }
    }
    __syncthreads();
    // ---- B: in_proj (xs half), 2 threads/column k-split, reg weights ----
    if (tid<164){
      const int kb = sg*20;
      auto bodyB = [&](int r){
        float a=0.f;
#pragma unroll
        for (int q=0;q<5;q++){
          const float4 xv = *(const float4*)&s_x[r*44+kb+4*q];
          a=fmaf(xv.x,wreg[4*q+0],a); a=fmaf(xv.y,wreg[4*q+1],a);
          a=fmaf(xv.z,wreg[4*q+2],a); a=fmaf(xv.w,wreg[4*q+3],a);
        }
        if (sg) a=fmaf(s_x[r*44+40], wreg[20], a);
        const float tot = a + __shfl_down(a,1);
        if (!sg) s_xs[r*82+d]=tot;
      };
      if (it==0){ bodyB(0); bodyB(1); bodyB(2); }
#pragma unroll 4
      for (int r=3;r<19;++r) bodyB(r);
    }
    __syncthreads();
    // ---- C: conv + silu -> s_xc ----
    for (int w=tid;w<1312;w+=256){
      const int l=w&15, dd=w>>4;
      float a=s_cb[dd];
#pragma unroll
      for (int k=0;k<4;k++) a=fmaf(s_xs[(l+k)*82+dd], s_cw[k*82+dd], a);
      s_xc[l*84+dd]=silu_f(a);
    }
    __syncthreads();
    // ---- D: x_proj (35 rows) -> dt/B/C in s_db only (float4 activations) ----
    for (int w=tid;w<560;w+=256){
      const int l=w&15, j=w>>4;
      const float2* wp=(const float2*)(w_xproj + j*82);
      const float4* gp=(const float4*)&s_xc[l*84];
      float a=0.f;
#pragma unroll
      for (int dq=0;dq<20;dq++){
        const float4 gv=gp[dq];
        const float2 w0=wp[2*dq], w1=wp[2*dq+1];
        a=fmaf(gv.x,w0.x,a); a=fmaf(gv.y,w0.y,a);
        a=fmaf(gv.z,w1.x,a); a=fmaf(gv.w,w1.y,a);
      }
      {
        const float2 w0=wp[40];
        a=fmaf(s_xc[l*84+80],w0.x,a); a=fmaf(s_xc[l*84+81],w0.y,a);
      }
      const int col=(j<3)?j:j+1;
      s_db[l*36+col]=a;
    }
    __syncthreads();
    // ---- E: local scan (delta inline — D2 folded); software-pipelined.
    //      stages yloc into s_xc, Dp into s_q (in place) ----
    if (tid<164){
      float4 q4 = *(const float4*)&s_db[0*36+0];      // dt0,dt1,dt2,(garbage)
      float  xc = s_xc[0*84+d];
      float4 B0 = *(const float4*)&s_db[0*36+4+sg*8];
      float4 B1 = *(const float4*)&s_db[0*36+8+sg*8];
      float4 C0 = *(const float4*)&s_db[0*36+20+sg*8];
      float4 C1 = *(const float4*)&s_db[0*36+24+sg*8];
#pragma unroll 1
      for (int l=0;l<16;l++){
        // prefetch next-l operands before the serial exp/fma chain
        float4 nq4, nB0, nB1, nC0, nC1; float nxc;
        if (l<15){
          nq4=*(const float4*)&s_db[(l+1)*36+0];
          nxc=s_xc[(l+1)*84+d];
          nB0=*(const float4*)&s_db[(l+1)*36+4+sg*8];
          nB1=*(const float4*)&s_db[(l+1)*36+8+sg*8];
          nC0=*(const float4*)&s_db[(l+1)*36+20+sg*8];
          nC1=*(const float4*)&s_db[(l+1)*36+24+sg*8];
        }
        // delta (identical op order to old D2)
        float a=dtb;
        a=fmaf(q4.x,dtw0,a); a=fmaf(q4.y,dtw1,a); a=fmaf(q4.z,dtw2,a);
        const float dl  = softplus_f(a);
        const float dxc = dl*xc;
        Dp += dl;
        const float Bv[8]={B0.x,B0.y,B0.z,B0.w,B1.x,B1.y,B1.z,B1.w};
        const float Cv[8]={C0.x,C0.y,C0.z,C0.w,C1.x,C1.y,C1.z,C1.w};
        float y=0.f;
        if (flag){
          const float q=__expf(dl*A0d);
          const float q2=q*q, q4p=q2*q2;
          float e = sg ? q4p*q4p*q : q;
#pragma unroll
          for (int s=0;s<8;s++){
            h[s]=fmaf(e,h[s],dxc*Bv[s]);
            y=fmaf(h[s],Cv[s],y);
            if(s<7) e*=q;
          }
        } else {
#pragma unroll
          for (int s=0;s<8;s++){
            const float e=__expf(dl*(-__expf(A_log[d*16+sg*8+s])));
            h[s]=fmaf(e,h[s],dxc*Bv[s]);
            y=fmaf(h[s],Cv[s],y);
          }
        }
        y += __shfl_down(y,1);
        if (sg==0){
          // pair lanes are lockstep: both read xc above before these writes
          s_xc[l*84+d] = y + xc*s_Dv[d];   // yloc
          s_q [l*84+d] = Dp;               // prefix-sum of delta
        }
        if (l<15){ q4=nq4; xc=nxc; B0=nB0; B1=nB1; C0=nC0; C1=nC1; }
      }
    }
    __syncthreads();
    // ---- F: batched record writeout (736 float4 = 16 recs x 184 floats) ----
    {
      float* fb = feat + ((size_t)b*SEG + (size_t)(tile*T0+it*16))*FREC;
      for (int i=tid;i<736;i+=256){
        const int l=i/46, q=i-l*46;
        float4 v;
        if (q<20){
          v = *(const float4*)&s_xc[l*84+4*q];
        } else if (q==20){
          v.x=s_xc[l*84+80]; v.y=s_xc[l*84+81]; v.z=0.f; v.w=0.f;
        } else if (q<41){
          v = *(const float4*)&s_q[l*84+4*(q-21)];
        } else if (q==41){
          v.x=s_q[l*84+80]; v.y=s_q[l*84+81]; v.z=0.f; v.w=0.f;
        } else {
          v = *(const float4*)&s_db[l*36+20+4*(q-42)];
        }
        *(float4*)&fb[(size_t)l*FREC + 4*q] = v;
      }
    }
    // no trailing barrier: next C/D writes to s_xc/s_q/s_db are 2+ barriers away
  }

  if (tid<164){
    float Pv[8];
    if (flag){
      const float Qt=__expf(Dp*A0d);
      const float Q2=Qt*Qt, Q4=Q2*Q2, Q8=Q4*Q4;
      float c = sg ? Q8*Qt : Qt;
#pragma unroll
      for (int i=0;i<8;i++){ Pv[i]=c; c*=Qt; }
    } else {
#pragma unroll
      for (int i=0;i<8;i++) Pv[i]=__expf(Dp*(-__expf(A_log[d*16+sg*8+i])));
    }
    const size_t base = ((size_t)(b*gridDim.x+tile))*1312 + (size_t)d*16 + sg*8;
    *(float4*)&Pg[base]   = make_float4(Pv[0],Pv[1],Pv[2],Pv[3]);
    *(float4*)&Pg[base+4] = make_float4(Pv[4],Pv[5],Pv[6],Pv[7]);
    *(float4*)&Hg[base]   = make_float4(h[0],h[1],h[2],h[3]);
    *(float4*)&Hg[base+4] = make_float4(h[4],h[5],h[6],h[7]);
  }
}

__global__ __launch_bounds__(256) void k2_comb(
    const float* __restrict__ Pg, const float* __restrict__ Hg,
    float* __restrict__ Hin, float* __restrict__ carry, int TPP, int first)
{
  const int g = blockIdx.x*256 + threadIdx.x;   // < 32*1312
  const int b = g/1312, r = g - b*1312;
  float h = first ? 0.f : carry[g];
#pragma unroll 4
  for (int t=0;t<TPP;t++){
    const size_t idx = ((size_t)(b*TPP+t))*1312 + r;
    Hin[idx]=h;
    h = fmaf(Pg[idx], h, Hg[idx]);
  }
  carry[g]=h;
}

__launch_bounds__(256, 2)
__global__ void k4_out(
    const float* __restrict__ xg, const float* __restrict__ w_in,
    const float* __restrict__ A_log, const float* __restrict__ Mg,
    const float* __restrict__ b_cls, int off, int SEG,
    const float* __restrict__ feat, const float* __restrict__ Hin,
    float* __restrict__ outg)
{
  __shared__ float s_x[16*44];    // raw x rows
  __shared__ float s_z[16*82];    // silu(z)
  __shared__ float s_g[16*82];    // gated value
  __shared__ float s_c[16*16];    // C rows
  __shared__ float s_hin[1312];   // s-major [s*82+d]
  __shared__ float s_M[10*82];    // fused Wc*Wo
  __shared__ float s_A0[82], s_bc[10];
  __shared__ int   s_flag[82];
  // ~23.6 KB

  const int tid = threadIdx.x;
  const int tile = blockIdx.x, b = blockIdx.y;

  for (int i=tid;i<1312;i+=256){
    const int dd=i>>4, s=i&15;
    s_hin[s*82+dd] = Hin[((size_t)(b*gridDim.x+tile))*1312 + i];
  }
  for (int i=tid;i<820;i+=256) s_M[i]=Mg[i];
  if (tid<10) s_bc[tid]=b_cls[tid];
  if (tid<82){
    float A0=-expf(A_log[tid*16]); s_A0[tid]=A0;
    bool ok=(A0<0.f);
#pragma unroll
    for (int s=1;s<16;s++){
      float As=-expf(A_log[tid*16+s]);
      ok = ok && (fabsf(As-(float)(s+1)*A0) <= 1e-3f*(float)(s+1)*fabsf(A0));
    }
    s_flag[tid]=ok?1:0;
  }
  // in_proj z-half weights in REGISTERS (same pair k-split as k0_feat)
  const int ez = tid>>1, sgz = tid&1;
  float wz[21];
#pragma unroll
  for (int t=0;t<21;t++) wz[t]=0.f;
  if (tid<164){
#pragma unroll
    for (int t=0;t<21;t++){
      if (sgz)        wz[t]=w_in[(82+ez)*41+20+t];
      else if (t<20)  wz[t]=w_in[(82+ez)*41+t];
    }
  }
  // hoisted (l,d) decomposition for the 1312-item stage
  int lk[6], dk[6];
#pragma unroll
  for (int k=0;k<6;k++){ const int w=tid+256*k; lk[k]=w/82; dk[k]=w-lk[k]*82; }

  for (int it=0; it<T0/16; ++it){
    const int lp0 = tile*T0 + it*16;
    const int gp0 = off + lp0;
    __syncthreads();
    // ---- A: load raw x + C rows ----
    for (int i=tid;i<656;i+=256){
      const int r=i/41, k=i-r*41;
      s_x[r*44+k] = xg[((size_t)b*SEQ+(size_t)(gp0+r))*41+k];
    }
    for (int i=tid;i<64;i+=256){
      const int l=i>>2, q=i&3;
      ((float4*)&s_c[l*16])[q] =
          ((const float4*)(feat + ((size_t)b*SEG+(size_t)(lp0+l))*FREC + 168))[q];
    }
    __syncthreads();
    // ---- B: z-proj, 2 threads/column k-split, reg weights -> silu ----
    if (tid<164){
      const int kb = sgz*20;
#pragma unroll 4
      for (int r=0;r<16;++r){
        float a=0.f;
#pragma unroll
        for (int q=0;q<5;q++){
          const float4 xv=*(const float4*)&s_x[r*44+kb+4*q];
          a=fmaf(xv.x,wz[4*q+0],a); a=fmaf(xv.y,wz[4*q+1],a);
          a=fmaf(xv.z,wz[4*q+2],a); a=fmaf(xv.w,wz[4*q+3],a);
        }
        if (sgz) a=fmaf(s_x[r*44+40], wz[20], a);
        const float tot = a + __shfl_down(a,1);
        if (!sgz) s_z[r*82+ez] = silu_f(tot);
      }
    }
    __syncthreads();
    // ---- C: closed-form correction + gate (feat loads hoisted together) ----
    {
      float ylv[6], Dpv[6];
#pragma unroll
      for (int k=0;k<6;k++){
        const int w=tid+256*k;
        if (w<1312){
          const float* fp = feat + ((size_t)b*SEG+(size_t)(lp0+lk[k]))*FREC;
          ylv[k]=fp[dk[k]]; Dpv[k]=fp[84+dk[k]];
        } else { ylv[k]=0.f; Dpv[k]=0.f; }
      }
#pragma unroll
      for (int k=0;k<6;k++){
        const int w=tid+256*k;
        if (w<1312){
          const int l=lk[k], dd=dk[k];
          float acc=ylv[k];
          if (s_flag[dd]){
            const float Qt=__expf(s_A0[dd]*Dpv[k]);
            float e=Qt;
#pragma unroll
            for (int s=0;s<16;s++){
              acc = fmaf(s_c[l*16+s]*e, s_hin[s*82+dd], acc);
              if (s<15) e*=Qt;
            }
          } else {
#pragma unroll
            for (int s=0;s<16;s++){
              const float As = -__expf(A_log[dd*16+s]);
              acc = fmaf(s_c[l*16+s]*__expf(As*Dpv[k]), s_hin[s*82+dd], acc);
            }
          }
          s_g[l*82+dd] = acc * s_z[l*82+dd];
        }
      }
    }
    __syncthreads();
    // ---- D: fused logits = M*g + b, contiguous store ----
    if (tid<160){
      const int l=tid/10, n=tid-(tid/10)*10;
      float a=s_bc[n];
      const float2* gp=(const float2*)&s_g[l*82];
      const float2* mp=(const float2*)&s_M[n*82];
#pragma unroll
      for (int q=0;q<41;q++){
        const float2 gv=gp[q], mv=mp[q];
        a=fmaf(gv.x,mv.x,a); a=fmaf(gv.y,mv.y,a);
      }
      outg[((size_t)b*SEQ+(size_t)gp0)*10 + tid] = a;
    }
    // no trailing barrier: top-of-loop sync protects s_x/s_c overwrite
  }
}

// ============================================================================
// OLD PATH (proven fallback)
// ============================================================================

template <int PASS>
__launch_bounds__(256, 2)
__global__ void mamba_chunk(
    const float* __restrict__ xg, const float* __restrict__ w_in,
    const float* __restrict__ w_conv, const float* __restrict__ b_conv,
    const float* __restrict__ w_xproj, const float* __restrict__ w_dt,
    const float* __restrict__ b_dt, const float* __restrict__ A_log,
    const float* __restrict__ Dvec, const float* __restrict__ w_out,
    const float* __restrict__ w_cls, const float* __restrict__ b_cls,
    float* __restrict__ Pg, float* __restrict__ Hg,
    const float* __restrict__ Hin, float* __restrict__ outg)
{
  __shared__ float s_x[RWS*XPAD];
  __shared__ float s_xs[RWS*SPAD];
  __shared__ float s_xc[TSUB*CPAD];
  __shared__ float s_z[TSUB*SPAD];
  __shared__ float s_xdbc[TSUB*JPAD];
  __shared__ float w_in_t[DMODEL*164];
  __shared__ float w_xp_t[DIN*35];
  __shared__ float s_cw[DIN*4];
  __shared__ float s_cb[DIN];
  __shared__ float s_dtw[DIN*3];
  __shared__ float s_dtb[DIN];

  const int tid=threadIdx.x;
  const int b=blockIdx.x/NCHUNK, c=blockIdx.x%NCHUNK, l0c=c*CHUNK;
  constexpr int NJ=(PASS==3)?35:19;
  constexpr int NE=(PASS==3)?164:DIN;

  for (int i=tid;i<DMODEL*164;i+=256){ int k=i/164,e=i-k*164; w_in_t[i]=w_in[e*DMODEL+k]; }
  for (int i=tid;i<DIN*35;i+=256){ int dd=i/35,j=i-dd*35; w_xp_t[i]=w_xproj[j*DIN+dd]; }
  for (int i=tid;i<DIN*4;i+=256) s_cw[i]=w_conv[i];
  for (int i=tid;i<DIN*3;i+=256) s_dtw[i]=w_dt[i];
  if (tid<DIN){ s_cb[tid]=b_conv[tid]; s_dtb[tid]=b_dt[tid]; }

  float h[NSTATE], Pp[NSTATE], As[NSTATE];
  float A0=-1.f, Dd=0.f;
  bool structured=true;
  if (tid<DIN){
#pragma unroll
    for (int s=0;s<NSTATE;++s) As[s]=-expf(A_log[tid*NSTATE+s]);
    A0=As[0];
#pragma unroll
    for (int s=0;s<NSTATE;++s)
      structured = structured && (fabsf(As[s]-(float)(s+1)*A0)<=1e-3f*(float)(s+1)*fabsf(A0));
    structured = structured && (A0<0.f);
    if (PASS==3){
      Dd=Dvec[tid];
      size_t base=((size_t)(b*NCHUNK+c))*(DIN*NSTATE)+(size_t)tid*NSTATE;
#pragma unroll
      for (int s=0;s<NSTATE;++s) h[s]=Hin[base+s];
    } else {
#pragma unroll
      for (int s=0;s<NSTATE;++s){ h[s]=0.f; Pp[s]=1.f; }
    }
  }
  __syncthreads();

  for (int t=0;t<NSUB;++t){
    const int p0=l0c+t*TSUB;
    for (int i=tid;i<RWS*DMODEL;i+=256){
      int r=i/DMODEL,k=i-r*DMODEL;
      int pos=p0-3+r;
      s_x[r*XPAD+k]=(pos>=0)?xg[(size_t)b*SEQ*DMODEL+(size_t)pos*DMODEL+k]:0.f;
    }
    __syncthreads();
    {
      const int e=tid;
      if (e<NE){
        float acc[RWS];
#pragma unroll
        for (int r=0;r<RWS;++r) acc[r]=0.f;
#pragma unroll
        for (int kq=0;kq<40;kq+=4){
          const float w0=w_in_t[(kq+0)*164+e], w1=w_in_t[(kq+1)*164+e];
          const float w2=w_in_t[(kq+2)*164+e], w3=w_in_t[(kq+3)*164+e];
#pragma unroll
          for (int r=0;r<RWS;++r){
            const float4 xv=*(const float4*)&s_x[r*XPAD+kq];
            acc[r]=fmaf(xv.x,w0,acc[r]); acc[r]=fmaf(xv.y,w1,acc[r]);
            acc[r]=fmaf(xv.z,w2,acc[r]); acc[r]=fmaf(xv.w,w3,acc[r]);
          }
        }
        const float wl=w_in_t[40*164+e];
#pragma unroll
        for (int r=0;r<RWS;++r) acc[r]=fmaf(s_x[r*XPAD+40],wl,acc[r]);
        if (e<DIN){
#pragma unroll
          for (int r=0;r<RWS;++r) s_xs[r*SPAD+e]=acc[r];
        } else {
#pragma unroll
          for (int r=3;r<RWS;++r) s_z[(r-3)*SPAD+(e-DIN)]=acc[r];
        }
      }
    }
    __syncthreads();
    for (int w=tid;w<TSUB*DIN;w+=256){
      const int l=w&15,e=w>>4;
      float a=s_cb[e];
#pragma unroll
      for (int k=0;k<4;++k) a=fmaf(s_xs[(l+k)*SPAD+e],s_cw[e*4+k],a);
      s_xc[l*CPAD+e]=siluf(a);
    }
    __syncthreads();
    for (int w=tid;w<TSUB*NJ;w+=256){
      const int l=w&15,j=w>>4;
      float a=0.f;
#pragma unroll
      for (int dq=0;dq<80;dq+=4){
        const float4 xv=*(const float4*)&s_xc[l*CPAD+dq];
        a=fmaf(xv.x,w_xp_t[(dq+0)*35+j],a); a=fmaf(xv.y,w_xp_t[(dq+1)*35+j],a);
        a=fmaf(xv.z,w_xp_t[(dq+2)*35+j],a); a=fmaf(xv.w,w_xp_t[(dq+3)*35+j],a);
      }
      a=fmaf(s_xc[l*CPAD+80],w_xp_t[80*35+j],a);
      a=fmaf(s_xc[l*CPAD+81],w_xp_t[81*35+j],a);
      const int col=(j<3)?j:j+1;
      s_xdbc[l*JPAD+col]=a;
    }
    __syncthreads();
    for (int w=tid;w<TSUB*DIN;w+=256){
      const int l=w&15,dd=w>>4;
      float a=s_dtb[dd];
      a=fmaf(s_xdbc[l*JPAD+0],s_dtw[dd*3+0],a);
      a=fmaf(s_xdbc[l*JPAD+1],s_dtw[dd*3+1],a);
      a=fmaf(s_xdbc[l*JPAD+2],s_dtw[dd*3+2],a);
      s_xs[l*SPAD+dd]=softplusf(a);
    }
    __syncthreads();
    if (tid<DIN){
      const int dd=tid;
#pragma unroll 1
      for (int l=0;l<TSUB;++l){
        const float dl=s_xs[l*SPAD+dd];
        const float xcd=s_xc[l*CPAD+dd];
        const float dxc=dl*xcd;
        const float4 B0=*(const float4*)&s_xdbc[l*JPAD+4];
        const float4 B1=*(const float4*)&s_xdbc[l*JPAD+8];
        const float4 B2=*(const float4*)&s_xdbc[l*JPAD+12];
        const float4 B3=*(const float4*)&s_xdbc[l*JPAD+16];
        const float Bv[NSTATE]={B0.x,B0.y,B0.z,B0.w,B1.x,B1.y,B1.z,B1.w,
                                B2.x,B2.y,B2.z,B2.w,B3.x,B3.y,B3.z,B3.w};
        float Cv[NSTATE];
        if (PASS==3){
          const float4 C0=*(const float4*)&s_xdbc[l*JPAD+20];
          const float4 C1=*(const float4*)&s_xdbc[l*JPAD+24];
          const float4 C2=*(const float4*)&s_xdbc[l*JPAD+28];
          const float4 C3=*(const float4*)&s_xdbc[l*JPAD+32];
          Cv[0]=C0.x;Cv[1]=C0.y;Cv[2]=C0.z;Cv[3]=C0.w;
          Cv[4]=C1.x;Cv[5]=C1.y;Cv[6]=C1.z;Cv[7]=C1.w;
          Cv[8]=C2.x;Cv[9]=C2.y;Cv[10]=C2.z;Cv[11]=C2.w;
          Cv[12]=C3.x;Cv[13]=C3.y;Cv[14]=C3.z;Cv[15]=C3.w;
        }
        float y=(PASS==3)?Dd*xcd:0.f;
        if (structured){
          const float q=expf(dl*A0);
          float e=q;
#pragma unroll
          for (int s=0;s<NSTATE;++s){
            h[s]=fmaf(e,h[s],dxc*Bv[s]);
            if (PASS==1) Pp[s]*=e; else y=fmaf(h[s],Cv[s],y);
            if (s<NSTATE-1) e*=q;
          }
        } else {
#pragma unroll
          for (int s=0;s<NSTATE;++s){
            const float e=expf(dl*As[s]);
            h[s]=fmaf(e,h[s],dxc*Bv[s]);
            if (PASS==1) Pp[s]*=e; else y=fmaf(h[s],Cv[s],y);
          }
        }
        if (PASS==3) s_xs[l*SPAD+dd]=y;
      }
    }
    __syncthreads();
    if (PASS==3){
      for (int w=tid;w<TSUB*DIN;w+=256){
        const int l=w&15,dd=w>>4;
        s_xc[l*CPAD+dd]=s_xs[l*SPAD+dd]*siluf(s_z[l*SPAD+dd]);
      }
      __syncthreads();
      for (int w=tid;w<TSUB*DMODEL;w+=256){
        const int l=w&15,dm=w>>4;
        const float2* wp=(const float2*)(w_out+dm*DIN);
        const float2* gp=(const float2*)&s_xc[l*CPAD];
        float a=0.f;
#pragma unroll
        for (int dq=0;dq<41;++dq){
          const float2 wv=wp[dq], gv=gp[dq];
          a=fmaf(wv.x,gv.x,a); a=fmaf(wv.y,gv.y,a);
        }
        s_x[l*XPAD+dm]=a;
      }
      __syncthreads();
      for (int w=tid;w<TSUB*NLAB;w+=256){
        const int l=w&15,n=w>>4;
        float a=b_cls[n];
#pragma unroll
        for (int dm=0;dm<DMODEL;++dm) a=fmaf(w_cls[n*DMODEL+dm],s_x[l*XPAD+dm],a);
        s_xdbc[l*NLAB+n]=a;
      }
      __syncthreads();
      for (int i=tid;i<TSUB*NLAB;i+=256)
        outg[((size_t)(b*SEQ+p0))*NLAB+i]=s_xdbc[i];
      __syncthreads();
    }
  }

  if (PASS==1 && tid<DIN){
    size_t base=((size_t)(b*NCHUNK+c))*(DIN*NSTATE)+(size_t)tid*NSTATE;
#pragma unroll
    for (int s=0;s<NSTATE;++s){ Pg[base+s]=Pp[s]; Hg[base+s]=h[s]; }
  }
}

__global__ __launch_bounds__(256) void mamba_combine(
    const float* __restrict__ P, const float* __restrict__ H, float* __restrict__ Hin){
  const int g=blockIdx.x*256+threadIdx.x;
  const int b=g/(DIN*NSTATE), ds=g-b*(DIN*NSTATE);
  float h=0.f;
#pragma unroll 1
  for (int c=0;c<NCHUNK;++c){
    const size_t idx=((size_t)(b*NCHUNK+c))*(DIN*NSTATE)+ds;
    Hin[idx]=h;
    h=fmaf(P[idx],h,H[idx]);
  }
}

// ============================================================================

extern "C" void kernel_launch(void* const* d_in, const int* in_sizes, int n_in,
                              void* d_out, int out_size, void* d_ws, size_t ws_size,
                              hipStream_t stream) {
  const float* xg     = (const float*)d_in[0];
  const float* w_in   = (const float*)d_in[1];
  const float* w_conv = (const float*)d_in[2];
  const float* b_conv = (const float*)d_in[3];
  const float* w_xp   = (const float*)d_in[4];
  const float* w_dt   = (const float*)d_in[5];
  const float* b_dt   = (const float*)d_in[6];
  const float* A_log  = (const float*)d_in[7];
  const float* Dv     = (const float*)d_in[8];
  const float* w_out  = (const float*)d_in[9];
  const float* w_cls  = (const float*)d_in[10];
  const float* b_cls  = (const float*)d_in[11];
  float* outg = (float*)d_out;

  int P = 0;
  for (int p : {1,2,4,8}) if (ws_size >= tier_bytes(p)) { P = p; break; }

  if (P) {
    const int SEG = SEQ/P, tiles = SEG/T0;
    const size_t featF = (size_t)BATCH*SEG*FREC;
    const size_t phF   = (size_t)BATCH*tiles*1312;
    float* feat  = (float*)d_ws;
    float* Pg    = feat + featF;
    float* Hg    = Pg + phF;
    float* Hin   = Hg + phF;
    float* carry = Hin + phF;
    float* Mg    = carry + (size_t)BATCH*1312;
    k_pre<<<dim3(4),256,0,stream>>>(w_out, w_cls, Mg);
    for (int p=0;p<P;p++){
      const int off = p*SEG;
      k0_feat<<<dim3(tiles,BATCH),256,0,stream>>>(
          xg,w_in,w_conv,b_conv,w_xp,w_dt,b_dt,A_log,Dv,off,SEG,feat,Pg,Hg);
      k2_comb<<<dim3((BATCH*1312)/256),256,0,stream>>>(Pg,Hg,Hin,carry,tiles,p==0?1:0);
      k4_out<<<dim3(tiles,BATCH),256,0,stream>>>(
          xg,w_in,A_log,Mg,b_cls,off,SEG,feat,Hin,outg);
    }
  } else {
    float* Pg  = (float*)d_ws;
    float* Hg  = Pg + NPH_OLD;
    float* Hin = Hg + NPH_OLD;
    dim3 grid(BATCH*NCHUNK), blk(256);
    mamba_chunk<1><<<grid,blk,0,stream>>>(xg,w_in,w_conv,b_conv,w_xp,w_dt,b_dt,
                                          A_log,Dv,w_out,w_cls,b_cls,Pg,Hg,nullptr,nullptr);
    mamba_combine<<<dim3((BATCH*DIN*NSTATE)/256),blk,0,stream>>>(Pg,Hg,Hin);
    mamba_chunk<3><<<grid,blk,0,stream>>>(xg,w_in,w_conv,b_conv,w_xp,w_dt,b_dt,
                                          A_log,Dv,w_out,w_cls,b_cls,nullptr,nullptr,Hin,outg);
  }
}

// Round 3
// 678.528 us; speedup vs baseline: 1.2299x; 1.2299x over previous
//
#include <hip/hip_runtime.h>
#include <math.h>

// Mamba block, fp32, single-scan + closed-form seeding + fused epilogue.
// k_pre  : M = w_cls@w_out (10x82) into ws.
// k0_feat: features once + local scan -> per-pos (yloc, Dp, C) record staged in
//          LDS, then ONE batched float4 writeout per subtile.
// k2_comb: sequential combine over tiles -> Hin per tile (carry across phases).
// k4_out : z-proj (LDS weights), closed-form corr, gate, fused M-GEMM logits.
// R10 (this round): REVERT to R7 structure ((256,4), LDS weights, 64 VGPR,
//   4 blocks/CU) + phase-local LDS-traffic cuts only:
//   - D: 2 x_proj columns per thread (row read reused 2x)
//   - C: conv vectorized b128 (s_xs/s_xc/s_q/s_cw padded to stride 84)
//   - F: float4 record assembly (FREC 184, 16B-aligned chunks)
// HARD-WON CONSTRAINTS (R8/R9 post-mortems):
//  - __launch_bounds__(256,n): n = resident blocks/CU AND VGPR cap ~256/n.
//    (256,2) -> 2 blocks (occ 23.6%, -34% perf) even though VGPR fine.
//    (256,4) -> 64 VGPR cap: NO loop-carried register arrays (wreg[21]
//    spilled -> FETCH 50->210MB). Phase-local temporaries only.
//  - R8: raising LDS block-ceiling 4->6 did NOT raise achieved occupancy;
//    kernels are LDS-pipe bound -> cut ds-instruction count, not residency.
//  - weights MUST be in LDS (R7): global weights miss under feat streaming.
// OLD path (proven): fallback if ws too small.

namespace {
constexpr int DMODEL=41, DIN=82, NSTATE=16, NLAB=10, BATCH=32, SEQ=8192;
// old path
constexpr int CHUNK=512, NCHUNK=SEQ/CHUNK, TSUB=16, NSUB=CHUNK/TSUB, RWS=TSUB+3;
constexpr int XPAD=44, SPAD=83, CPAD=84, JPAD=36;
constexpr int NPH_OLD = BATCH*NCHUNK*DIN*NSTATE;
// new path
constexpr int T0 = 64;              // positions per k0/k4 tile
constexpr int FREC = 184;           // yloc@0(82+2) | Dp@84(82+2) | C@168(16)
inline size_t tier_bytes(int P){
  size_t SEG = (size_t)SEQ/P, tiles = SEG/T0;
  return ((size_t)BATCH*SEG*FREC + 3*((size_t)BATCH*tiles*1312)
          + (size_t)BATCH*1312 + 4096)*4;
}
}

__device__ __forceinline__ float siluf(float v)     { return v / (1.f + expf(-v)); }
__device__ __forceinline__ float softplusf(float v) { return (v > 20.f) ? v : log1pf(expf(v)); }
// fast variants (validated: absmax ~1.2e-7, passes)
__device__ __forceinline__ float silu_f(float v){
  return v * __builtin_amdgcn_rcpf(1.f + __expf(-v));
}
__device__ __forceinline__ float softplus_f(float v){
  return (v > 20.f) ? v : __logf(1.f + __expf(v));
}

// in_proj helper: NR rows from r0, col e(<82), weights in LDS [k*82+e],
// x stride 44, out stride 84
template<int NR>
__device__ __forceinline__ void inproj_rows(int r0, int e,
    const float* __restrict__ sx, const float* __restrict__ wt,
    float* __restrict__ sxs) {
  float acc[NR];
#pragma unroll
  for (int i=0;i<NR;i++) acc[i]=0.f;
#pragma unroll
  for (int kq=0;kq<40;kq+=4){
    const float w0=wt[(kq+0)*82+e], w1=wt[(kq+1)*82+e];
    const float w2=wt[(kq+2)*82+e], w3=wt[(kq+3)*82+e];
#pragma unroll
    for (int i=0;i<NR;i++){
      const float4 xv = *(const float4*)&sx[(r0+i)*44+kq];
      acc[i]=fmaf(xv.x,w0,acc[i]); acc[i]=fmaf(xv.y,w1,acc[i]);
      acc[i]=fmaf(xv.z,w2,acc[i]); acc[i]=fmaf(xv.w,w3,acc[i]);
    }
  }
  const float wl = wt[40*82+e];
#pragma unroll
  for (int i=0;i<NR;i++)
    sxs[(r0+i)*84+e] = fmaf(sx[(r0+i)*44+40], wl, acc[i]);
}

// ============================================================================
// NEW PATH
// ============================================================================

__global__ __launch_bounds__(256) void k_pre(
    const float* __restrict__ w_out, const float* __restrict__ w_cls,
    float* __restrict__ M){
  const int w = blockIdx.x*256 + threadIdx.x;
  if (w < NLAB*DIN){
    const int n = w/82, dd = w - n*82;
    float a = 0.f;
#pragma unroll
    for (int dm=0;dm<41;dm++) a = fmaf(w_cls[n*41+dm], w_out[dm*82+dd], a);
    M[w] = a;
  }
}

__launch_bounds__(256, 4)
__global__ void k0_feat(
    const float* __restrict__ xg, const float* __restrict__ w_in,
    const float* __restrict__ w_conv, const float* __restrict__ b_conv,
    const float* __restrict__ w_xproj, const float* __restrict__ w_dt,
    const float* __restrict__ b_dt, const float* __restrict__ A_log,
    const float* __restrict__ Dvec, int off, int SEG,
    float* __restrict__ feat, float* __restrict__ Pg, float* __restrict__ Hg)
{
  __shared__ __align__(16) float s_x[19*44];   // raw x rows (pos p0-3 .. p0+15)
  __shared__ __align__(16) float s_xs[19*84];  // xs rows incl conv halo (pad 84)
  __shared__ __align__(16) float s_xc[16*84];  // xc; scan overwrites with yloc
  __shared__ __align__(16) float s_q[16*84];   // delta; scan overwrites with Dp
  __shared__ __align__(16) float s_db[16*36];  // dt@0..2, B@4..19, C@20..35
  __shared__ __align__(16) float w_t[41*82];   // in_proj xs-half transposed [k][e]
  __shared__ __align__(16) float s_cw[4*84];   // conv w transposed [k][d] (pad 84)
  __shared__ __align__(16) float s_cb[82];
  __shared__ float s_dtw[3*82];
  __shared__ float s_dtb[82], s_A0[82], s_Dv[82];
  __shared__ int   s_flag[82];
  // ~40.2 KB -> 4 blocks/CU

  const int tid = threadIdx.x;
  const int tile = blockIdx.x, b = blockIdx.y;
  const int base_pos = off + tile*T0;

  for (int i=tid;i<41*82;i+=256){ int k=i/82,e=i-k*82; w_t[i]=w_in[e*41+k]; }
  for (int i=tid;i<328;i+=256){ int dd=i/4,k=i-dd*4; s_cw[k*84+dd]=w_conv[i]; }
  for (int i=tid;i<246;i+=256){ int dd=i/3,k=i-dd*3; s_dtw[k*82+dd]=w_dt[i]; }
  if (tid<82){
    s_cb[tid]=b_conv[tid]; s_dtb[tid]=b_dt[tid]; s_Dv[tid]=Dvec[tid];
    float A0=-expf(A_log[tid*16]); s_A0[tid]=A0;
    bool ok=(A0<0.f);
#pragma unroll
    for (int s=1;s<16;s++){
      float As=-expf(A_log[tid*16+s]);
      ok = ok && (fabsf(As-(float)(s+1)*A0) <= 1e-3f*(float)(s+1)*fabsf(A0));
    }
    s_flag[tid]=ok?1:0;
  }
  __syncthreads();

  const int d = tid>>1, sg = tid&1;
  float h[8], As[8], A0d=-1.f, Dp=0.f;
  int flag=1;
  if (tid<164){
    flag = s_flag[d]; A0d = s_A0[d];
    if (!flag){
#pragma unroll
      for (int i=0;i<8;i++) As[i]=-expf(A_log[d*16+sg*8+i]);
    }
#pragma unroll
    for (int i=0;i<8;i++) h[i]=0.f;
  }

  for (int it=0; it<T0/16; ++it){
    const int p0 = base_pos + it*16;
    // ---- A: halo shift + raw x load ----
    if (it>0){
      for (int i=tid;i<246;i+=256){ int r=i/82, dd=i-r*82; s_xs[r*84+dd]=s_xs[(16+r)*84+dd]; }
    }
    {
      const int rlo=(it==0)?0:3, cnt=(19-rlo)*41;
      for (int i=tid;i<cnt;i+=256){
        int r=rlo+i/41, k=i-(i/41)*41;
        int pos=p0-3+r;
        s_x[r*44+k] = (pos>=0) ? xg[((size_t)b*SEQ+(size_t)pos)*41+k] : 0.f;
      }
    }
    __syncthreads();
    // ---- B: in_proj (xs half), 2 threads/column, weights in LDS ----
    if (tid<164){
      const int e=(tid<82)?tid:tid-82, rh=(tid>=82);
      if (it==0){ if(!rh) inproj_rows<10>(0,e,s_x,w_t,s_xs); else inproj_rows<9>(10,e,s_x,w_t,s_xs); }
      else      { inproj_rows<8>(rh?11:3,e,s_x,w_t,s_xs); }
    }
    __syncthreads();
    // ---- C: conv + silu -> s_xc (vectorized b128, 336 items) ----
    for (int w=tid;w<336;w+=256){
      const int l=w&15, dg=w>>4;
      if (dg<20){
        float4 a = *(const float4*)&s_cb[4*dg];
#pragma unroll
        for (int k=0;k<4;k++){
          const float4 xv = *(const float4*)&s_xs[(l+k)*84+4*dg];
          const float4 cw = *(const float4*)&s_cw[k*84+4*dg];
          a.x=fmaf(xv.x,cw.x,a.x); a.y=fmaf(xv.y,cw.y,a.y);
          a.z=fmaf(xv.z,cw.z,a.z); a.w=fmaf(xv.w,cw.w,a.w);
        }
        a.x=silu_f(a.x); a.y=silu_f(a.y); a.z=silu_f(a.z); a.w=silu_f(a.w);
        *(float4*)&s_xc[l*84+4*dg] = a;
      } else {
#pragma unroll
        for (int dd=80;dd<82;++dd){
          float a=s_cb[dd];
#pragma unroll
          for (int k=0;k<4;k++) a=fmaf(s_xs[(l+k)*84+dd], s_cw[k*84+dd], a);
          s_xc[l*84+dd]=silu_f(a);
        }
      }
    }
    __syncthreads();
    // ---- D: x_proj (35 rows), 2 cols/thread (row read reused), 288 items ----
    for (int w=tid;w<288;w+=256){
      const int l=w&15, jp=w>>4;          // jp 0..17
      const int j0=2*jp;
      const int j1=(jp<17)?(j0+1):34;     // clamp: jp=17 duplicates j=34 (benign)
      const float2* wp0=(const float2*)(w_xproj + j0*82);
      const float2* wp1=(const float2*)(w_xproj + j1*82);
      const float4* gp=(const float4*)&s_xc[l*84];
      float a0=0.f, a1=0.f;
#pragma unroll
      for (int dq=0;dq<20;dq++){
        const float4 gv=gp[dq];
        const float2 w00=wp0[2*dq], w01=wp0[2*dq+1];
        const float2 w10=wp1[2*dq], w11=wp1[2*dq+1];
        a0=fmaf(gv.x,w00.x,a0); a0=fmaf(gv.y,w00.y,a0);
        a0=fmaf(gv.z,w01.x,a0); a0=fmaf(gv.w,w01.y,a0);
        a1=fmaf(gv.x,w10.x,a1); a1=fmaf(gv.y,w10.y,a1);
        a1=fmaf(gv.z,w11.x,a1); a1=fmaf(gv.w,w11.y,a1);
      }
      const float x80=s_xc[l*84+80], x81=s_xc[l*84+81];
      { const float2 wl0=wp0[40];
        a0=fmaf(x80,wl0.x,a0); a0=fmaf(x81,wl0.y,a0); }
      { const float2 wl1=wp1[40];
        a1=fmaf(x80,wl1.x,a1); a1=fmaf(x81,wl1.y,a1); }
      const int c0=(j0<3)?j0:j0+1;
      const int c1=(j1<3)?j1:j1+1;
      s_db[l*36+c0]=a0;
      s_db[l*36+c1]=a1;
    }
    __syncthreads();
    // ---- D2: dt_proj + softplus -> delta ----
    for (int w=tid;w<1312;w+=256){
      const int l=w&15, dd=w>>4;
      float a=s_dtb[dd];
      a=fmaf(s_db[l*36+0],s_dtw[0*82+dd],a);
      a=fmaf(s_db[l*36+1],s_dtw[1*82+dd],a);
      a=fmaf(s_db[l*36+2],s_dtw[2*82+dd],a);
      s_q[l*84+dd]=softplus_f(a);
    }
    __syncthreads();
    // ---- E: local scan; stage yloc into s_xc, Dp into s_q (in place) ----
    if (tid<164){
#pragma unroll 1
      for (int l=0;l<16;l++){
        const float dl  = s_q[l*84+d];
        const float xc  = s_xc[l*84+d];
        const float dxc = dl*xc;
        Dp += dl;
        const float4 B0=*(const float4*)&s_db[l*36+4+sg*8];
        const float4 B1=*(const float4*)&s_db[l*36+8+sg*8];
        const float4 C0=*(const float4*)&s_db[l*36+20+sg*8];
        const float4 C1=*(const float4*)&s_db[l*36+24+sg*8];
        const float Bv[8]={B0.x,B0.y,B0.z,B0.w,B1.x,B1.y,B1.z,B1.w};
        const float Cv[8]={C0.x,C0.y,C0.z,C0.w,C1.x,C1.y,C1.z,C1.w};
        float y=0.f;
        if (flag){
          const float q=__expf(dl*A0d);
          const float q2=q*q, q4=q2*q2;
          float e = sg ? q4*q4*q : q;
#pragma unroll
          for (int s=0;s<8;s++){
            h[s]=fmaf(e,h[s],dxc*Bv[s]);
            y=fmaf(h[s],Cv[s],y);
            if(s<7) e*=q;
          }
        } else {
#pragma unroll
          for (int s=0;s<8;s++){
            const float e=__expf(dl*As[s]);
            h[s]=fmaf(e,h[s],dxc*Bv[s]);
            y=fmaf(h[s],Cv[s],y);
          }
        }
        y += __shfl_down(y,1);
        if (sg==0){
          // pair lanes are lockstep: both read xc/dl above before these writes
          s_xc[l*84+d] = y + xc*s_Dv[d];   // yloc
          s_q [l*84+d] = Dp;               // prefix-sum of delta
        }
      }
    }
    __syncthreads();
    // ---- F: batched record writeout (736 float4 = 16 recs x 184 floats) ----
    {
      float* fb = feat + ((size_t)b*SEG + (size_t)(tile*T0+it*16))*FREC;
      for (int i=tid;i<736;i+=256){
        const int l=i/46, q=i-l*46;
        float4 v;
        if (q<20){
          v = *(const float4*)&s_xc[l*84+4*q];
        } else if (q==20){
          v.x=s_xc[l*84+80]; v.y=s_xc[l*84+81]; v.z=0.f; v.w=0.f;
        } else if (q<41){
          v = *(const float4*)&s_q[l*84+4*(q-21)];
        } else if (q==41){
          v.x=s_q[l*84+80]; v.y=s_q[l*84+81]; v.z=0.f; v.w=0.f;
        } else {
          v = *(const float4*)&s_db[l*36+20+4*(q-42)];
        }
        *(float4*)&fb[(size_t)l*FREC + 4*q] = v;
      }
    }
    // no trailing barrier: next C/D writes to s_xc/s_q/s_db are 2+ barriers away
  }

  if (tid<164){
    float Pv[8];
    if (flag){
      const float Qt=__expf(Dp*A0d);
      const float Q2=Qt*Qt, Q4=Q2*Q2, Q8=Q4*Q4;
      float c = sg ? Q8*Qt : Qt;
#pragma unroll
      for (int i=0;i<8;i++){ Pv[i]=c; c*=Qt; }
    } else {
#pragma unroll
      for (int i=0;i<8;i++) Pv[i]=__expf(Dp*As[i]);
    }
    const size_t base = ((size_t)(b*gridDim.x+tile))*1312 + (size_t)d*16 + sg*8;
    *(float4*)&Pg[base]   = make_float4(Pv[0],Pv[1],Pv[2],Pv[3]);
    *(float4*)&Pg[base+4] = make_float4(Pv[4],Pv[5],Pv[6],Pv[7]);
    *(float4*)&Hg[base]   = make_float4(h[0],h[1],h[2],h[3]);
    *(float4*)&Hg[base+4] = make_float4(h[4],h[5],h[6],h[7]);
  }
}

__global__ __launch_bounds__(256) void k2_comb(
    const float* __restrict__ Pg, const float* __restrict__ Hg,
    float* __restrict__ Hin, float* __restrict__ carry, int TPP, int first)
{
  const int g = blockIdx.x*256 + threadIdx.x;   // < 32*1312
  const int b = g/1312, r = g - b*1312;
  float h = first ? 0.f : carry[g];
#pragma unroll 4
  for (int t=0;t<TPP;t++){
    const size_t idx = ((size_t)(b*TPP+t))*1312 + r;
    Hin[idx]=h;
    h = fmaf(Pg[idx], h, Hg[idx]);
  }
  carry[g]=h;
}

__launch_bounds__(256, 4)
__global__ void k4_out(
    const float* __restrict__ xg, const float* __restrict__ w_in,
    const float* __restrict__ A_log, const float* __restrict__ Mg,
    const float* __restrict__ b_cls, int off, int SEG,
    const float* __restrict__ feat, const float* __restrict__ Hin,
    float* __restrict__ outg)
{
  __shared__ __align__(16) float s_x[16*44];   // raw x rows
  __shared__ __align__(16) float w_zt[41*82];  // in_proj z-half transposed [k][e]
  __shared__ __align__(16) float s_z[16*82];   // silu(z)
  __shared__ __align__(16) float s_g[16*82];   // gated value
  __shared__ __align__(16) float s_c[16*16];   // C rows
  __shared__ __align__(16) float s_hin[1312];  // s-major [s*82+d]
  __shared__ __align__(16) float s_M[10*82];   // fused Wc*Wo
  __shared__ float s_A0[82], s_bc[10];
  __shared__ int   s_flag[82];
  // ~37.1 KB -> 4 blocks/CU

  const int tid = threadIdx.x;
  const int tile = blockIdx.x, b = blockIdx.y;

  for (int i=tid;i<41*82;i+=256){ int k=i/82,e=i-k*82; w_zt[i]=w_in[(82+e)*41+k]; }
  for (int i=tid;i<1312;i+=256){
    const int dd=i>>4, s=i&15;
    s_hin[s*82+dd] = Hin[((size_t)(b*gridDim.x+tile))*1312 + i];
  }
  for (int i=tid;i<820;i+=256) s_M[i]=Mg[i];
  if (tid<10) s_bc[tid]=b_cls[tid];
  if (tid<82){
    float A0=-expf(A_log[tid*16]); s_A0[tid]=A0;
    bool ok=(A0<0.f);
#pragma unroll
    for (int s=1;s<16;s++){
      float As=-expf(A_log[tid*16+s]);
      ok = ok && (fabsf(As-(float)(s+1)*A0) <= 1e-3f*(float)(s+1)*fabsf(A0));
    }
    s_flag[tid]=ok?1:0;
  }
  // hoisted (l,d) decomposition for the 1312-item stage
  int lk[6], dk[6];
#pragma unroll
  for (int k=0;k<6;k++){ const int w=tid+256*k; lk[k]=w/82; dk[k]=w-lk[k]*82; }

  for (int it=0; it<T0/16; ++it){
    const int lp0 = tile*T0 + it*16;
    const int gp0 = off + lp0;
    __syncthreads();
    // ---- A: load raw x + C rows ----
    for (int i=tid;i<656;i+=256){
      const int r=i/41, k=i-r*41;
      s_x[r*44+k] = xg[((size_t)b*SEQ+(size_t)(gp0+r))*41+k];
    }
    for (int i=tid;i<64;i+=256){
      const int l=i>>2, q=i&3;
      ((float4*)&s_c[l*16])[q] =
          ((const float4*)(feat + ((size_t)b*SEG+(size_t)(lp0+l))*FREC + 168))[q];
    }
    __syncthreads();
    // ---- B: z-proj (LDS weights), 2 threads/column, 8 rows -> silu ----
    if (tid<164){
      const int e=(tid<82)?tid:tid-82, l0=(tid>=82)?8:0;
      float acc[8];
#pragma unroll
      for (int i=0;i<8;i++) acc[i]=0.f;
#pragma unroll
      for (int kq=0;kq<40;kq+=4){
        const float w0=w_zt[(kq+0)*82+e], w1=w_zt[(kq+1)*82+e];
        const float w2=w_zt[(kq+2)*82+e], w3=w_zt[(kq+3)*82+e];
#pragma unroll
        for (int i=0;i<8;i++){
          const float4 xv=*(const float4*)&s_x[(l0+i)*44+kq];
          acc[i]=fmaf(xv.x,w0,acc[i]); acc[i]=fmaf(xv.y,w1,acc[i]);
          acc[i]=fmaf(xv.z,w2,acc[i]); acc[i]=fmaf(xv.w,w3,acc[i]);
        }
      }
      const float wl=w_zt[40*82+e];
#pragma unroll
      for (int i=0;i<8;i++)
        s_z[(l0+i)*82+e] = silu_f(fmaf(s_x[(l0+i)*44+40], wl, acc[i]));
    }
    __syncthreads();
    // ---- C: closed-form correction + gate ----
#pragma unroll
    for (int k=0;k<6;k++){
      const int w=tid+256*k;
      if (w>=1312) break;
      const int l=lk[k], dd=dk[k];
      const float* fp = feat + ((size_t)b*SEG+(size_t)(lp0+l))*FREC;
      const float yl = fp[dd];
      const float Dp = fp[84+dd];
      float acc=yl;
      if (s_flag[dd]){
        const float Qt=__expf(s_A0[dd]*Dp);
        float e=Qt;
#pragma unroll
        for (int s=0;s<16;s++){
          acc = fmaf(s_c[l*16+s]*e, s_hin[s*82+dd], acc);
          if (s<15) e*=Qt;
        }
      } else {
#pragma unroll
        for (int s=0;s<16;s++){
          const float As = -__expf(A_log[dd*16+s]);
          acc = fmaf(s_c[l*16+s]*__expf(As*Dp), s_hin[s*82+dd], acc);
        }
      }
      s_g[l*82+dd] = acc * s_z[l*82+dd];
    }
    __syncthreads();
    // ---- D: fused logits = M*g + b, contiguous store ----
    if (tid<160){
      const int l=tid/10, n=tid-(tid/10)*10;
      float a=s_bc[n];
      const float2* gp=(const float2*)&s_g[l*82];
      const float2* mp=(const float2*)&s_M[n*82];
#pragma unroll
      for (int q=0;q<41;q++){
        const float2 gv=gp[q], mv=mp[q];
        a=fmaf(gv.x,mv.x,a); a=fmaf(gv.y,mv.y,a);
      }
      outg[((size_t)b*SEQ+(size_t)gp0)*10 + tid] = a;
    }
    // no trailing barrier: top-of-loop sync protects s_x/s_c overwrite
  }
}

// ============================================================================
// OLD PATH (proven fallback)
// ============================================================================

template <int PASS>
__launch_bounds__(256, 2)
__global__ void mamba_chunk(
    const float* __restrict__ xg, const float* __restrict__ w_in,
    const float* __restrict__ w_conv, const float* __restrict__ b_conv,
    const float* __restrict__ w_xproj, const float* __restrict__ w_dt,
    const float* __restrict__ b_dt, const float* __restrict__ A_log,
    const float* __restrict__ Dvec, const float* __restrict__ w_out,
    const float* __restrict__ w_cls, const float* __restrict__ b_cls,
    float* __restrict__ Pg, float* __restrict__ Hg,
    const float* __restrict__ Hin, float* __restrict__ outg)
{
  __shared__ float s_x[RWS*XPAD];
  __shared__ float s_xs[RWS*SPAD];
  __shared__ float s_xc[TSUB*CPAD];
  __shared__ float s_z[TSUB*SPAD];
  __shared__ float s_xdbc[TSUB*JPAD];
  __shared__ float w_in_t[DMODEL*164];
  __shared__ float w_xp_t[DIN*35];
  __shared__ float s_cw[DIN*4];
  __shared__ float s_cb[DIN];
  __shared__ float s_dtw[DIN*3];
  __shared__ float s_dtb[DIN];

  const int tid=threadIdx.x;
  const int b=blockIdx.x/NCHUNK, c=blockIdx.x%NCHUNK, l0c=c*CHUNK;
  constexpr int NJ=(PASS==3)?35:19;
  constexpr int NE=(PASS==3)?164:DIN;

  for (int i=tid;i<DMODEL*164;i+=256){ int k=i/164,e=i-k*164; w_in_t[i]=w_in[e*DMODEL+k]; }
  for (int i=tid;i<DIN*35;i+=256){ int dd=i/35,j=i-dd*35; w_xp_t[i]=w_xproj[j*DIN+dd]; }
  for (int i=tid;i<DIN*4;i+=256) s_cw[i]=w_conv[i];
  for (int i=tid;i<DIN*3;i+=256) s_dtw[i]=w_dt[i];
  if (tid<DIN){ s_cb[tid]=b_conv[tid]; s_dtb[tid]=b_dt[tid]; }

  float h[NSTATE], Pp[NSTATE], As[NSTATE];
  float A0=-1.f, Dd=0.f;
  bool structured=true;
  if (tid<DIN){
#pragma unroll
    for (int s=0;s<NSTATE;++s) As[s]=-expf(A_log[tid*NSTATE+s]);
    A0=As[0];
#pragma unroll
    for (int s=0;s<NSTATE;++s)
      structured = structured && (fabsf(As[s]-(float)(s+1)*A0)<=1e-3f*(float)(s+1)*fabsf(A0));
    structured = structured && (A0<0.f);
    if (PASS==3){
      Dd=Dvec[tid];
      size_t base=((size_t)(b*NCHUNK+c))*(DIN*NSTATE)+(size_t)tid*NSTATE;
#pragma unroll
      for (int s=0;s<NSTATE;++s) h[s]=Hin[base+s];
    } else {
#pragma unroll
      for (int s=0;s<NSTATE;++s){ h[s]=0.f; Pp[s]=1.f; }
    }
  }
  __syncthreads();

  for (int t=0;t<NSUB;++t){
    const int p0=l0c+t*TSUB;
    for (int i=tid;i<RWS*DMODEL;i+=256){
      int r=i/DMODEL,k=i-r*DMODEL;
      int pos=p0-3+r;
      s_x[r*XPAD+k]=(pos>=0)?xg[(size_t)b*SEQ*DMODEL+(size_t)pos*DMODEL+k]:0.f;
    }
    __syncthreads();
    {
      const int e=tid;
      if (e<NE){
        float acc[RWS];
#pragma unroll
        for (int r=0;r<RWS;++r) acc[r]=0.f;
#pragma unroll
        for (int kq=0;kq<40;kq+=4){
          const float w0=w_in_t[(kq+0)*164+e], w1=w_in_t[(kq+1)*164+e];
          const float w2=w_in_t[(kq+2)*164+e], w3=w_in_t[(kq+3)*164+e];
#pragma unroll
          for (int r=0;r<RWS;++r){
            const float4 xv=*(const float4*)&s_x[r*XPAD+kq];
            acc[r]=fmaf(xv.x,w0,acc[r]); acc[r]=fmaf(xv.y,w1,acc[r]);
            acc[r]=fmaf(xv.z,w2,acc[r]); acc[r]=fmaf(xv.w,w3,acc[r]);
          }
        }
        const float wl=w_in_t[40*164+e];
#pragma unroll
        for (int r=0;r<RWS;++r) acc[r]=fmaf(s_x[r*XPAD+40],wl,acc[r]);
        if (e<DIN){
#pragma unroll
          for (int r=0;r<RWS;++r) s_xs[r*SPAD+e]=acc[r];
        } else {
#pragma unroll
          for (int r=3;r<RWS;++r) s_z[(r-3)*SPAD+(e-DIN)]=acc[r];
        }
      }
    }
    __syncthreads();
    for (int w=tid;w<TSUB*DIN;w+=256){
      const int l=w&15,e=w>>4;
      float a=s_cb[e];
#pragma unroll
      for (int k=0;k<4;++k) a=fmaf(s_xs[(l+k)*SPAD+e],s_cw[e*4+k],a);
      s_xc[l*CPAD+e]=siluf(a);
    }
    __syncthreads();
    for (int w=tid;w<TSUB*NJ;w+=256){
      const int l=w&15,j=w>>4;
      float a=0.f;
#pragma unroll
      for (int dq=0;dq<80;dq+=4){
        const float4 xv=*(const float4*)&s_xc[l*CPAD+dq];
        a=fmaf(xv.x,w_xp_t[(dq+0)*35+j],a); a=fmaf(xv.y,w_xp_t[(dq+1)*35+j],a);
        a=fmaf(xv.z,w_xp_t[(dq+2)*35+j],a); a=fmaf(xv.w,w_xp_t[(dq+3)*35+j],a);
      }
      a=fmaf(s_xc[l*CPAD+80],w_xp_t[80*35+j],a);
      a=fmaf(s_xc[l*CPAD+81],w_xp_t[81*35+j],a);
      const int col=(j<3)?j:j+1;
      s_xdbc[l*JPAD+col]=a;
    }
    __syncthreads();
    for (int w=tid;w<TSUB*DIN;w+=256){
      const int l=w&15,dd=w>>4;
      float a=s_dtb[dd];
      a=fmaf(s_xdbc[l*JPAD+0],s_dtw[dd*3+0],a);
      a=fmaf(s_xdbc[l*JPAD+1],s_dtw[dd*3+1],a);
      a=fmaf(s_xdbc[l*JPAD+2],s_dtw[dd*3+2],a);
      s_xs[l*SPAD+dd]=softplusf(a);
    }
    __syncthreads();
    if (tid<DIN){
      const int dd=tid;
#pragma unroll 1
      for (int l=0;l<TSUB;++l){
        const float dl=s_xs[l*SPAD+dd];
        const float xcd=s_xc[l*CPAD+dd];
        const float dxc=dl*xcd;
        const float4 B0=*(const float4*)&s_xdbc[l*JPAD+4];
        const float4 B1=*(const float4*)&s_xdbc[l*JPAD+8];
        const float4 B2=*(const float4*)&s_xdbc[l*JPAD+12];
        const float4 B3=*(const float4*)&s_xdbc[l*JPAD+16];
        const float Bv[NSTATE]={B0.x,B0.y,B0.z,B0.w,B1.x,B1.y,B1.z,B1.w,
                                B2.x,B2.y,B2.z,B2.w,B3.x,B3.y,B3.z,B3.w};
        float Cv[NSTATE];
        if (PASS==3){
          const float4 C0=*(const float4*)&s_xdbc[l*JPAD+20];
          const float4 C1=*(const float4*)&s_xdbc[l*JPAD+24];
          const float4 C2=*(const float4*)&s_xdbc[l*JPAD+28];
          const float4 C3=*(const float4*)&s_xdbc[l*JPAD+32];
          Cv[0]=C0.x;Cv[1]=C0.y;Cv[2]=C0.z;Cv[3]=C0.w;
          Cv[4]=C1.x;Cv[5]=C1.y;Cv[6]=C1.z;Cv[7]=C1.w;
          Cv[8]=C2.x;Cv[9]=C2.y;Cv[10]=C2.z;Cv[11]=C2.w;
          Cv[12]=C3.x;Cv[13]=C3.y;Cv[14]=C3.z;Cv[15]=C3.w;
        }
        float y=(PASS==3)?Dd*xcd:0.f;
        if (structured){
          const float q=expf(dl*A0);
          float e=q;
#pragma unroll
          for (int s=0;s<NSTATE;++s){
            h[s]=fmaf(e,h[s],dxc*Bv[s]);
            if (PASS==1) Pp[s]*=e; else y=fmaf(h[s],Cv[s],y);
            if (s<NSTATE-1) e*=q;
          }
        } else {
#pragma unroll
          for (int s=0;s<NSTATE;++s){
            const float e=expf(dl*As[s]);
            h[s]=fmaf(e,h[s],dxc*Bv[s]);
            if (PASS==1) Pp[s]*=e; else y=fmaf(h[s],Cv[s],y);
          }
        }
        if (PASS==3) s_xs[l*SPAD+dd]=y;
      }
    }
    __syncthreads();
    if (PASS==3){
      for (int w=tid;w<TSUB*DIN;w+=256){
        const int l=w&15,dd=w>>4;
        s_xc[l*CPAD+dd]=s_xs[l*SPAD+dd]*siluf(s_z[l*SPAD+dd]);
      }
      __syncthreads();
      for (int w=tid;w<TSUB*DMODEL;w+=256){
        const int l=w&15,dm=w>>4;
        const float2* wp=(const float2*)(w_out+dm*DIN);
        const float2* gp=(const float2*)&s_xc[l*CPAD];
        float a=0.f;
#pragma unroll
        for (int dq=0;dq<41;++dq){
          const float2 wv=wp[dq], gv=gp[dq];
          a=fmaf(wv.x,gv.x,a); a=fmaf(wv.y,gv.y,a);
        }
        s_x[l*XPAD+dm]=a;
      }
      __syncthreads();
      for (int w=tid;w<TSUB*NLAB;w+=256){
        const int l=w&15,n=w>>4;
        float a=b_cls[n];
#pragma unroll
        for (int dm=0;dm<DMODEL;++dm) a=fmaf(w_cls[n*DMODEL+dm],s_x[l*XPAD+dm],a);
        s_xdbc[l*NLAB+n]=a;
      }
      __syncthreads();
      for (int i=tid;i<TSUB*NLAB;i+=256)
        outg[((size_t)(b*SEQ+p0))*NLAB+i]=s_xdbc[i];
      __syncthreads();
    }
  }

  if (PASS==1 && tid<DIN){
    size_t base=((size_t)(b*NCHUNK+c))*(DIN*NSTATE)+(size_t)tid*NSTATE;
#pragma unroll
    for (int s=0;s<NSTATE;++s){ Pg[base+s]=Pp[s]; Hg[base+s]=h[s]; }
  }
}

__global__ __launch_bounds__(256) void mamba_combine(
    const float* __restrict__ P, const float* __restrict__ H, float* __restrict__ Hin){
  const int g=blockIdx.x*256+threadIdx.x;
  const int b=g/(DIN*NSTATE), ds=g-b*(DIN*NSTATE);
  float h=0.f;
#pragma unroll 1
  for (int c=0;c<NCHUNK;++c){
    const size_t idx=((size_t)(b*NCHUNK+c))*(DIN*NSTATE)+ds;
    Hin[idx]=h;
    h=fmaf(P[idx],h,H[idx]);
  }
}

// ============================================================================

extern "C" void kernel_launch(void* const* d_in, const int* in_sizes, int n_in,
                              void* d_out, int out_size, void* d_ws, size_t ws_size,
                              hipStream_t stream) {
  const float* xg     = (const float*)d_in[0];
  const float* w_in   = (const float*)d_in[1];
  const float* w_conv = (const float*)d_in[2];
  const float* b_conv = (const float*)d_in[3];
  const float* w_xp   = (const float*)d_in[4];
  const float* w_dt   = (const float*)d_in[5];
  const float* b_dt   = (const float*)d_in[6];
  const float* A_log  = (const float*)d_in[7];
  const float* Dv     = (const float*)d_in[8];
  const float* w_out  = (const float*)d_in[9];
  const float* w_cls  = (const float*)d_in[10];
  const float* b_cls  = (const float*)d_in[11];
  float* outg = (float*)d_out;

  int P = 0;
  for (int p : {1,2,4,8}) if (ws_size >= tier_bytes(p)) { P = p; break; }

  if (P) {
    const int SEG = SEQ/P, tiles = SEG/T0;
    const size_t featF = (size_t)BATCH*SEG*FREC;
    const size_t phF   = (size_t)BATCH*tiles*1312;
    float* feat  = (float*)d_ws;
    float* Pg    = feat + featF;
    float* Hg    = Pg + phF;
    float* Hin   = Hg + phF;
    float* carry = Hin + phF;
    float* Mg    = carry + (size_t)BATCH*1312;
    k_pre<<<dim3(4),256,0,stream>>>(w_out, w_cls, Mg);
    for (int p=0;p<P;p++){
      const int off = p*SEG;
      k0_feat<<<dim3(tiles,BATCH),256,0,stream>>>(
          xg,w_in,w_conv,b_conv,w_xp,w_dt,b_dt,A_log,Dv,off,SEG,feat,Pg,Hg);
      k2_comb<<<dim3((BATCH*1312)/256),256,0,stream>>>(Pg,Hg,Hin,carry,tiles,p==0?1:0);
      k4_out<<<dim3(tiles,BATCH),256,0,stream>>>(
          xg,w_in,A_log,Mg,b_cls,off,SEG,feat,Hin,outg);
    }
  } else {
    float* Pg  = (float*)d_ws;
    float* Hg  = Pg + NPH_OLD;
    float* Hin = Hg + NPH_OLD;
    dim3 grid(BATCH*NCHUNK), blk(256);
    mamba_chunk<1><<<grid,blk,0,stream>>>(xg,w_in,w_conv,b_conv,w_xp,w_dt,b_dt,
                                          A_log,Dv,w_out,w_cls,b_cls,Pg,Hg,nullptr,nullptr);
    mamba_combine<<<dim3((BATCH*DIN*NSTATE)/256),blk,0,stream>>>(Pg,Hg,Hin);
    mamba_chunk<3><<<grid,blk,0,stream>>>(xg,w_in,w_conv,b_conv,w_xp,w_dt,b_dt,
                                          A_log,Dv,w_out,w_cls,b_cls,nullptr,nullptr,Hin,outg);
  }
}

// Round 4
// 663.925 us; speedup vs baseline: 1.2570x; 1.0220x over previous
//
#include <hip/hip_runtime.h>
#include <math.h>

// Mamba block, fp32, single-scan + closed-form seeding + fused epilogue.
// k_pre  : M = w_cls@w_out (10x82) into ws.
// k0_feat: features once + local scan -> per-pos (yloc, Dp, C) record staged in
//          LDS, then ONE batched float4 writeout per subtile.
// k2_comb: sequential combine over tiles -> Hin per tile (carry across phases).
// k4_out : z-proj (LDS weights), closed-form corr, gate, fused M-GEMM logits.
// R11: base = R7 (proven 644.9us) + register-neutral LDS-cycle cuts only:
//   - k0-D: 2 x_proj cols/thread (288 items), SAME float2/stride-82 pattern.
//   - k0-D2 folded into E (delta from one broadcast float4 of s_db; w_dt in
//     4 regs). -1 barrier. Paid for by dropping the dead As[8] carried array
//     (structured-A fallback recomputes from A_log; never taken at runtime).
//   - k4-C: s_c read as 4x float4 (64B-aligned broadcast), same fp order.
// HARD-WON CONSTRAINTS:
//  - __launch_bounds__(256,n): n = resident blocks AND VGPR cap ~256/n.
//    (256,2)->2 blocks resident (occ 24%, -34%). (256,4)->64 VGPR: NO big
//    reg arrays; R10's bundled stride-84 C/D rewrite spilled (~120MB scratch).
//  - k0/k4 are LDS-PIPE bound (cycle model matches 346us measured): buy
//    ds-cycles only if register-neutral. Occupancy is NOT the lever (R8).
//  - weights MUST be in LDS (R7): global weights miss under feat streaming.
// OLD path (proven): fallback if ws too small.

namespace {
constexpr int DMODEL=41, DIN=82, NSTATE=16, NLAB=10, BATCH=32, SEQ=8192;
// old path
constexpr int CHUNK=512, NCHUNK=SEQ/CHUNK, TSUB=16, NSUB=CHUNK/TSUB, RWS=TSUB+3;
constexpr int XPAD=44, SPAD=83, CPAD=84, JPAD=36;
constexpr int NPH_OLD = BATCH*NCHUNK*DIN*NSTATE;
// new path
constexpr int T0 = 64;              // positions per k0/k4 tile
constexpr int FREC = 180;           // yloc@0(82) | Dp@82(82) | C@164(16)
inline size_t tier_bytes(int P){
  size_t SEG = (size_t)SEQ/P, tiles = SEG/T0;
  return ((size_t)BATCH*SEG*FREC + 3*((size_t)BATCH*tiles*1312)
          + (size_t)BATCH*1312 + 4096)*4;
}
}

__device__ __forceinline__ float siluf(float v)     { return v / (1.f + expf(-v)); }
__device__ __forceinline__ float softplusf(float v) { return (v > 20.f) ? v : log1pf(expf(v)); }
// fast variants (validated: absmax unchanged at 5.96e-8)
__device__ __forceinline__ float silu_f(float v){
  return v * __builtin_amdgcn_rcpf(1.f + __expf(-v));
}
__device__ __forceinline__ float softplus_f(float v){
  return (v > 20.f) ? v : __logf(1.f + __expf(v));
}

// in_proj helper: NR rows from r0, col e(<82), weights in LDS [k*82+e],
// x stride 44, out stride 82
template<int NR>
__device__ __forceinline__ void inproj_rows(int r0, int e,
    const float* __restrict__ sx, const float* __restrict__ wt,
    float* __restrict__ sxs) {
  float acc[NR];
#pragma unroll
  for (int i=0;i<NR;i++) acc[i]=0.f;
#pragma unroll
  for (int kq=0;kq<40;kq+=4){
    const float w0=wt[(kq+0)*82+e], w1=wt[(kq+1)*82+e];
    const float w2=wt[(kq+2)*82+e], w3=wt[(kq+3)*82+e];
#pragma unroll
    for (int i=0;i<NR;i++){
      const float4 xv = *(const float4*)&sx[(r0+i)*44+kq];
      acc[i]=fmaf(xv.x,w0,acc[i]); acc[i]=fmaf(xv.y,w1,acc[i]);
      acc[i]=fmaf(xv.z,w2,acc[i]); acc[i]=fmaf(xv.w,w3,acc[i]);
    }
  }
  const float wl = wt[40*82+e];
#pragma unroll
  for (int i=0;i<NR;i++)
    sxs[(r0+i)*82+e] = fmaf(sx[(r0+i)*44+40], wl, acc[i]);
}

// ============================================================================
// NEW PATH
// ============================================================================

__global__ __launch_bounds__(256) void k_pre(
    const float* __restrict__ w_out, const float* __restrict__ w_cls,
    float* __restrict__ M){
  const int w = blockIdx.x*256 + threadIdx.x;
  if (w < NLAB*DIN){
    const int n = w/82, dd = w - n*82;
    float a = 0.f;
#pragma unroll
    for (int dm=0;dm<41;dm++) a = fmaf(w_cls[n*41+dm], w_out[dm*82+dd], a);
    M[w] = a;
  }
}

__launch_bounds__(256, 4)
__global__ void k0_feat(
    const float* __restrict__ xg, const float* __restrict__ w_in,
    const float* __restrict__ w_conv, const float* __restrict__ b_conv,
    const float* __restrict__ w_xproj, const float* __restrict__ w_dt,
    const float* __restrict__ b_dt, const float* __restrict__ A_log,
    const float* __restrict__ Dvec, int off, int SEG,
    float* __restrict__ feat, float* __restrict__ Pg, float* __restrict__ Hg)
{
  __shared__ float s_x[19*44];    // raw x rows (pos p0-3 .. p0+15)
  __shared__ float s_xs[19*82];   // xs rows incl conv halo
  __shared__ float s_xc[16*82];   // xc; scan overwrites with yloc
  __shared__ float s_q[16*82];    // scan stages Dp here
  __shared__ float s_db[16*36];   // dt@0..2, B@4..19, C@20..35
  __shared__ float w_t[41*82];    // in_proj xs-half transposed [k][e] (LDS!)
  __shared__ float s_cw[4*82];    // conv w transposed [k][d]
  __shared__ float s_cb[82], s_A0[82], s_Dv[82];
  __shared__ int   s_flag[82];
  // ~38.6 KB -> 4 blocks/CU

  const int tid = threadIdx.x;
  const int tile = blockIdx.x, b = blockIdx.y;
  const int base_pos = off + tile*T0;

  for (int i=tid;i<41*82;i+=256){ int k=i/82,e=i-k*82; w_t[i]=w_in[e*41+k]; }
  for (int i=tid;i<328;i+=256){ int dd=i/4,k=i-dd*4; s_cw[k*82+dd]=w_conv[i]; }
  if (tid<82){
    s_cb[tid]=b_conv[tid]; s_Dv[tid]=Dvec[tid];
    float A0=-expf(A_log[tid*16]); s_A0[tid]=A0;
    bool ok=(A0<0.f);
#pragma unroll
    for (int s=1;s<16;s++){
      float As=-expf(A_log[tid*16+s]);
      ok = ok && (fabsf(As-(float)(s+1)*A0) <= 1e-3f*(float)(s+1)*fabsf(A0));
    }
    s_flag[tid]=ok?1:0;
  }
  __syncthreads();

  const int d = tid>>1, sg = tid&1;
  float h[8], A0d=-1.f, Dp=0.f;
  float dtw0=0.f, dtw1=0.f, dtw2=0.f, dtb=0.f;   // dt_proj col weights (4 regs)
  int flag=1;
  if (tid<164){
    flag = s_flag[d]; A0d = s_A0[d];
    dtw0=w_dt[d*3+0]; dtw1=w_dt[d*3+1]; dtw2=w_dt[d*3+2];
    dtb=b_dt[d];
#pragma unroll
    for (int i=0;i<8;i++) h[i]=0.f;
  }

  for (int it=0; it<T0/16; ++it){
    const int p0 = base_pos + it*16;
    // ---- A: halo shift + raw x load ----
    if (it>0){
      for (int i=tid;i<246;i+=256){ int r=i/82, dd=i-r*82; s_xs[r*82+dd]=s_xs[(16+r)*82+dd]; }
    }
    {
      const int rlo=(it==0)?0:3, cnt=(19-rlo)*41;
      for (int i=tid;i<cnt;i+=256){
        int r=rlo+i/41, k=i-(i/41)*41;
        int pos=p0-3+r;
        s_x[r*44+k] = (pos>=0) ? xg[((size_t)b*SEQ+(size_t)pos)*41+k] : 0.f;
      }
    }
    __syncthreads();
    // ---- B: in_proj (xs half), 2 threads/column, weights in LDS ----
    if (tid<164){
      const int e=(tid<82)?tid:tid-82, rh=(tid>=82);
      if (it==0){ if(!rh) inproj_rows<10>(0,e,s_x,w_t,s_xs); else inproj_rows<9>(10,e,s_x,w_t,s_xs); }
      else      { inproj_rows<8>(rh?11:3,e,s_x,w_t,s_xs); }
    }
    __syncthreads();
    // ---- C: conv + silu -> s_xc ----
    for (int w=tid;w<1312;w+=256){
      const int l=w&15, dd=w>>4;
      float a=s_cb[dd];
#pragma unroll
      for (int k=0;k<4;k++) a=fmaf(s_xs[(l+k)*82+dd], s_cw[k*82+dd], a);
      s_xc[l*82+dd]=silu_f(a);
    }
    __syncthreads();
    // ---- D: x_proj (35 rows), 2 cols/thread (s_xc row read reused 2x) ----
    for (int w=tid;w<288;w+=256){
      const int l=w&15, jp=w>>4;            // jp 0..17
      const int j0=2*jp;
      const int j1=(jp<17)?(j0+1):34;       // jp=17 duplicates j=34 (benign)
      const float2* wp0=(const float2*)(w_xproj + j0*82);
      const float2* wp1=(const float2*)(w_xproj + j1*82);
      const float2* gp=(const float2*)&s_xc[l*82];
      float a0=0.f, a1=0.f;
#pragma unroll
      for (int dq=0;dq<41;dq++){
        const float2 gv=gp[dq];
        const float2 wv0=wp0[dq], wv1=wp1[dq];
        a0=fmaf(gv.x,wv0.x,a0); a0=fmaf(gv.y,wv0.y,a0);
        a1=fmaf(gv.x,wv1.x,a1); a1=fmaf(gv.y,wv1.y,a1);
      }
      const int c0=(j0<3)?j0:j0+1;
      const int c1=(j1<3)?j1:j1+1;
      s_db[l*36+c0]=a0;
      s_db[l*36+c1]=a1;
    }
    __syncthreads();
    // ---- E: local scan; delta inline (D2 folded; same fp order);
    //      stages yloc into s_xc, Dp into s_q (in place) ----
    if (tid<164){
#pragma unroll 1
      for (int l=0;l<16;l++){
        const float4 qv = *(const float4*)&s_db[l*36];   // dt0,dt1,dt2,(unused)
        float ad=dtb;
        ad=fmaf(qv.x,dtw0,ad); ad=fmaf(qv.y,dtw1,ad); ad=fmaf(qv.z,dtw2,ad);
        const float dl  = softplus_f(ad);
        const float xc  = s_xc[l*82+d];
        const float dxc = dl*xc;
        Dp += dl;
        const float4 B0=*(const float4*)&s_db[l*36+4+sg*8];
        const float4 B1=*(const float4*)&s_db[l*36+8+sg*8];
        const float4 C0=*(const float4*)&s_db[l*36+20+sg*8];
        const float4 C1=*(const float4*)&s_db[l*36+24+sg*8];
        const float Bv[8]={B0.x,B0.y,B0.z,B0.w,B1.x,B1.y,B1.z,B1.w};
        const float Cv[8]={C0.x,C0.y,C0.z,C0.w,C1.x,C1.y,C1.z,C1.w};
        float y=0.f;
        if (flag){
          const float q=__expf(dl*A0d);
          const float q2=q*q, q4=q2*q2;
          float e = sg ? q4*q4*q : q;
#pragma unroll
          for (int s=0;s<8;s++){
            h[s]=fmaf(e,h[s],dxc*Bv[s]);
            y=fmaf(h[s],Cv[s],y);
            if(s<7) e*=q;
          }
        } else {
#pragma unroll
          for (int s=0;s<8;s++){
            const float e=__expf(dl*(-__expf(A_log[d*16+sg*8+s])));
            h[s]=fmaf(e,h[s],dxc*Bv[s]);
            y=fmaf(h[s],Cv[s],y);
          }
        }
        y += __shfl_down(y,1);
        if (sg==0){
          // pair lanes are lockstep: both read xc above before these writes
          s_xc[l*82+d] = y + xc*s_Dv[d];   // yloc
          s_q [l*82+d] = Dp;               // prefix-sum of delta
        }
      }
    }
    __syncthreads();
    // ---- F: batched record writeout (720 float4 = 16 recs x 180 floats) ----
    {
      float* fb = feat + ((size_t)b*SEG + (size_t)(tile*T0+it*16))*FREC;
      for (int i=tid;i<720;i+=256){
        const int l=i/45, q=i-l*45;
        const int f=4*q;
        float4 v;
        if (q<20){
          v.x=s_xc[l*82+f+0]; v.y=s_xc[l*82+f+1];
          v.z=s_xc[l*82+f+2]; v.w=s_xc[l*82+f+3];
        } else if (q==20){
          v.x=s_xc[l*82+80]; v.y=s_xc[l*82+81];
          v.z=s_q[l*82+0];   v.w=s_q[l*82+1];
        } else if (q<=40){
          v.x=s_q[l*82+f-82]; v.y=s_q[l*82+f-81];
          v.z=s_q[l*82+f-80]; v.w=s_q[l*82+f-79];
        } else {
          const int c=f-164;
          v.x=s_db[l*36+20+c+0]; v.y=s_db[l*36+20+c+1];
          v.z=s_db[l*36+20+c+2]; v.w=s_db[l*36+20+c+3];
        }
        *(float4*)&fb[(size_t)l*FREC + f] = v;
      }
    }
    // no trailing barrier: next C/D writes to s_xc/s_db are 2+ barriers away
  }

  if (tid<164){
    float Pv[8];
    if (flag){
      const float Qt=__expf(Dp*A0d);
      const float Q2=Qt*Qt, Q4=Q2*Q2, Q8=Q4*Q4;
      float c = sg ? Q8*Qt : Qt;
#pragma unroll
      for (int i=0;i<8;i++){ Pv[i]=c; c*=Qt; }
    } else {
#pragma unroll
      for (int i=0;i<8;i++) Pv[i]=__expf(Dp*(-__expf(A_log[d*16+sg*8+i])));
    }
    const size_t base = ((size_t)(b*gridDim.x+tile))*1312 + (size_t)d*16 + sg*8;
    *(float4*)&Pg[base]   = make_float4(Pv[0],Pv[1],Pv[2],Pv[3]);
    *(float4*)&Pg[base+4] = make_float4(Pv[4],Pv[5],Pv[6],Pv[7]);
    *(float4*)&Hg[base]   = make_float4(h[0],h[1],h[2],h[3]);
    *(float4*)&Hg[base+4] = make_float4(h[4],h[5],h[6],h[7]);
  }
}

__global__ __launch_bounds__(256) void k2_comb(
    const float* __restrict__ Pg, const float* __restrict__ Hg,
    float* __restrict__ Hin, float* __restrict__ carry, int TPP, int first)
{
  const int g = blockIdx.x*256 + threadIdx.x;   // < 32*1312
  const int b = g/1312, r = g - b*1312;
  float h = first ? 0.f : carry[g];
#pragma unroll 4
  for (int t=0;t<TPP;t++){
    const size_t idx = ((size_t)(b*TPP+t))*1312 + r;
    Hin[idx]=h;
    h = fmaf(Pg[idx], h, Hg[idx]);
  }
  carry[g]=h;
}

__launch_bounds__(256, 4)
__global__ void k4_out(
    const float* __restrict__ xg, const float* __restrict__ w_in,
    const float* __restrict__ A_log, const float* __restrict__ Mg,
    const float* __restrict__ b_cls, int off, int SEG,
    const float* __restrict__ feat, const float* __restrict__ Hin,
    float* __restrict__ outg)
{
  __shared__ float s_x[16*44];    // raw x rows
  __shared__ float w_zt[41*82];   // in_proj z-half transposed [k][e] (LDS!)
  __shared__ float s_z[16*82];    // silu(z)
  __shared__ float s_g[16*82];    // gated value
  __shared__ float s_c[16*16];    // C rows
  __shared__ float s_hin[1312];   // s-major [s*82+d]
  __shared__ float s_M[10*82];    // fused Wc*Wo
  __shared__ float s_A0[82], s_bc[10];
  __shared__ int   s_flag[82];
  // ~37.1 KB -> 4 blocks/CU

  const int tid = threadIdx.x;
  const int tile = blockIdx.x, b = blockIdx.y;

  for (int i=tid;i<41*82;i+=256){ int k=i/82,e=i-k*82; w_zt[i]=w_in[(82+e)*41+k]; }
  for (int i=tid;i<1312;i+=256){
    const int dd=i>>4, s=i&15;
    s_hin[s*82+dd] = Hin[((size_t)(b*gridDim.x+tile))*1312 + i];
  }
  for (int i=tid;i<820;i+=256) s_M[i]=Mg[i];
  if (tid<10) s_bc[tid]=b_cls[tid];
  if (tid<82){
    float A0=-expf(A_log[tid*16]); s_A0[tid]=A0;
    bool ok=(A0<0.f);
#pragma unroll
    for (int s=1;s<16;s++){
      float As=-expf(A_log[tid*16+s]);
      ok = ok && (fabsf(As-(float)(s+1)*A0) <= 1e-3f*(float)(s+1)*fabsf(A0));
    }
    s_flag[tid]=ok?1:0;
  }
  // hoisted (l,d) decomposition for the 1312-item stage
  int lk[6], dk[6];
#pragma unroll
  for (int k=0;k<6;k++){ const int w=tid+256*k; lk[k]=w/82; dk[k]=w-lk[k]*82; }

  for (int it=0; it<T0/16; ++it){
    const int lp0 = tile*T0 + it*16;
    const int gp0 = off + lp0;
    __syncthreads();
    // ---- A: load raw x + C rows ----
    for (int i=tid;i<656;i+=256){
      const int r=i/41, k=i-r*41;
      s_x[r*44+k] = xg[((size_t)b*SEQ+(size_t)(gp0+r))*41+k];
    }
    for (int i=tid;i<64;i+=256){
      const int l=i>>2, q=i&3;
      ((float4*)&s_c[l*16])[q] =
          ((const float4*)(feat + ((size_t)b*SEG+(size_t)(lp0+l))*FREC + 164))[q];
    }
    __syncthreads();
    // ---- B: z-proj (LDS weights), 2 threads/column, 8 rows -> silu ----
    if (tid<164){
      const int e=(tid<82)?tid:tid-82, l0=(tid>=82)?8:0;
      float acc[8];
#pragma unroll
      for (int i=0;i<8;i++) acc[i]=0.f;
#pragma unroll
      for (int kq=0;kq<40;kq+=4){
        const float w0=w_zt[(kq+0)*82+e], w1=w_zt[(kq+1)*82+e];
        const float w2=w_zt[(kq+2)*82+e], w3=w_zt[(kq+3)*82+e];
#pragma unroll
        for (int i=0;i<8;i++){
          const float4 xv=*(const float4*)&s_x[(l0+i)*44+kq];
          acc[i]=fmaf(xv.x,w0,acc[i]); acc[i]=fmaf(xv.y,w1,acc[i]);
          acc[i]=fmaf(xv.z,w2,acc[i]); acc[i]=fmaf(xv.w,w3,acc[i]);
        }
      }
      const float wl=w_zt[40*82+e];
#pragma unroll
      for (int i=0;i<8;i++)
        s_z[(l0+i)*82+e] = silu_f(fmaf(s_x[(l0+i)*44+40], wl, acc[i]));
    }
    __syncthreads();
    // ---- C: closed-form correction + gate (s_c as 4x float4, same order) ----
#pragma unroll
    for (int k=0;k<6;k++){
      const int w=tid+256*k;
      if (w>=1312) break;
      const int l=lk[k], dd=dk[k];
      const float* fp = feat + ((size_t)b*SEG+(size_t)(lp0+l))*FREC;
      const float yl = fp[dd];
      const float Dp = fp[82+dd];
      float acc=yl;
      if (s_flag[dd]){
        const float Qt=__expf(s_A0[dd]*Dp);
        const float4* cp=(const float4*)&s_c[l*16];
        float e=Qt;
#pragma unroll
        for (int s4=0;s4<4;s4++){
          const float4 cv=cp[s4];
          const int sb=4*s4;
          acc = fmaf(cv.x*e, s_hin[(sb+0)*82+dd], acc); e*=Qt;
          acc = fmaf(cv.y*e, s_hin[(sb+1)*82+dd], acc); e*=Qt;
          acc = fmaf(cv.z*e, s_hin[(sb+2)*82+dd], acc); e*=Qt;
          acc = fmaf(cv.w*e, s_hin[(sb+3)*82+dd], acc);
          if (s4<3) e*=Qt;
        }
      } else {
#pragma unroll
        for (int s=0;s<16;s++){
          const float As = -__expf(A_log[dd*16+s]);
          acc = fmaf(s_c[l*16+s]*__expf(As*Dp), s_hin[s*82+dd], acc);
        }
      }
      s_g[l*82+dd] = acc * s_z[l*82+dd];
    }
    __syncthreads();
    // ---- D: fused logits = M*g + b, contiguous store ----
    if (tid<160){
      const int l=tid/10, n=tid-(tid/10)*10;
      float a=s_bc[n];
      const float2* gp=(const float2*)&s_g[l*82];
      const float2* mp=(const float2*)&s_M[n*82];
#pragma unroll
      for (int q=0;q<41;q++){
        const float2 gv=gp[q], mv=mp[q];
        a=fmaf(gv.x,mv.x,a); a=fmaf(gv.y,mv.y,a);
      }
      outg[((size_t)b*SEQ+(size_t)gp0)*10 + tid] = a;
    }
    // no trailing barrier: top-of-loop sync protects s_x/s_c overwrite
  }
}

// ============================================================================
// OLD PATH (proven fallback)
// ============================================================================

template <int PASS>
__launch_bounds__(256, 2)
__global__ void mamba_chunk(
    const float* __restrict__ xg, const float* __restrict__ w_in,
    const float* __restrict__ w_conv, const float* __restrict__ b_conv,
    const float* __restrict__ w_xproj, const float* __restrict__ w_dt,
    const float* __restrict__ b_dt, const float* __restrict__ A_log,
    const float* __restrict__ Dvec, const float* __restrict__ w_out,
    const float* __restrict__ w_cls, const float* __restrict__ b_cls,
    float* __restrict__ Pg, float* __restrict__ Hg,
    const float* __restrict__ Hin, float* __restrict__ outg)
{
  __shared__ float s_x[RWS*XPAD];
  __shared__ float s_xs[RWS*SPAD];
  __shared__ float s_xc[TSUB*CPAD];
  __shared__ float s_z[TSUB*SPAD];
  __shared__ float s_xdbc[TSUB*JPAD];
  __shared__ float w_in_t[DMODEL*164];
  __shared__ float w_xp_t[DIN*35];
  __shared__ float s_cw[DIN*4];
  __shared__ float s_cb[DIN];
  __shared__ float s_dtw[DIN*3];
  __shared__ float s_dtb[DIN];

  const int tid=threadIdx.x;
  const int b=blockIdx.x/NCHUNK, c=blockIdx.x%NCHUNK, l0c=c*CHUNK;
  constexpr int NJ=(PASS==3)?35:19;
  constexpr int NE=(PASS==3)?164:DIN;

  for (int i=tid;i<DMODEL*164;i+=256){ int k=i/164,e=i-k*164; w_in_t[i]=w_in[e*DMODEL+k]; }
  for (int i=tid;i<DIN*35;i+=256){ int dd=i/35,j=i-dd*35; w_xp_t[i]=w_xproj[j*DIN+dd]; }
  for (int i=tid;i<DIN*4;i+=256) s_cw[i]=w_conv[i];
  for (int i=tid;i<DIN*3;i+=256) s_dtw[i]=w_dt[i];
  if (tid<DIN){ s_cb[tid]=b_conv[tid]; s_dtb[tid]=b_dt[tid]; }

  float h[NSTATE], Pp[NSTATE], As[NSTATE];
  float A0=-1.f, Dd=0.f;
  bool structured=true;
  if (tid<DIN){
#pragma unroll
    for (int s=0;s<NSTATE;++s) As[s]=-expf(A_log[tid*NSTATE+s]);
    A0=As[0];
#pragma unroll
    for (int s=0;s<NSTATE;++s)
      structured = structured && (fabsf(As[s]-(float)(s+1)*A0)<=1e-3f*(float)(s+1)*fabsf(A0));
    structured = structured && (A0<0.f);
    if (PASS==3){
      Dd=Dvec[tid];
      size_t base=((size_t)(b*NCHUNK+c))*(DIN*NSTATE)+(size_t)tid*NSTATE;
#pragma unroll
      for (int s=0;s<NSTATE;++s) h[s]=Hin[base+s];
    } else {
#pragma unroll
      for (int s=0;s<NSTATE;++s){ h[s]=0.f; Pp[s]=1.f; }
    }
  }
  __syncthreads();

  for (int t=0;t<NSUB;++t){
    const int p0=l0c+t*TSUB;
    for (int i=tid;i<RWS*DMODEL;i+=256){
      int r=i/DMODEL,k=i-r*DMODEL;
      int pos=p0-3+r;
      s_x[r*XPAD+k]=(pos>=0)?xg[(size_t)b*SEQ*DMODEL+(size_t)pos*DMODEL+k]:0.f;
    }
    __syncthreads();
    {
      const int e=tid;
      if (e<NE){
        float acc[RWS];
#pragma unroll
        for (int r=0;r<RWS;++r) acc[r]=0.f;
#pragma unroll
        for (int kq=0;kq<40;kq+=4){
          const float w0=w_in_t[(kq+0)*164+e], w1=w_in_t[(kq+1)*164+e];
          const float w2=w_in_t[(kq+2)*164+e], w3=w_in_t[(kq+3)*164+e];
#pragma unroll
          for (int r=0;r<RWS;++r){
            const float4 xv=*(const float4*)&s_x[r*XPAD+kq];
            acc[r]=fmaf(xv.x,w0,acc[r]); acc[r]=fmaf(xv.y,w1,acc[r]);
            acc[r]=fmaf(xv.z,w2,acc[r]); acc[r]=fmaf(xv.w,w3,acc[r]);
          }
        }
        const float wl=w_in_t[40*164+e];
#pragma unroll
        for (int r=0;r<RWS;++r) acc[r]=fmaf(s_x[r*XPAD+40],wl,acc[r]);
        if (e<DIN){
#pragma unroll
          for (int r=0;r<RWS;++r) s_xs[r*SPAD+e]=acc[r];
        } else {
#pragma unroll
          for (int r=3;r<RWS;++r) s_z[(r-3)*SPAD+(e-DIN)]=acc[r];
        }
      }
    }
    __syncthreads();
    for (int w=tid;w<TSUB*DIN;w+=256){
      const int l=w&15,e=w>>4;
      float a=s_cb[e];
#pragma unroll
      for (int k=0;k<4;++k) a=fmaf(s_xs[(l+k)*SPAD+e],s_cw[e*4+k],a);
      s_xc[l*CPAD+e]=siluf(a);
    }
    __syncthreads();
    for (int w=tid;w<TSUB*NJ;w+=256){
      const int l=w&15,j=w>>4;
      float a=0.f;
#pragma unroll
      for (int dq=0;dq<80;dq+=4){
        const float4 xv=*(const float4*)&s_xc[l*CPAD+dq];
        a=fmaf(xv.x,w_xp_t[(dq+0)*35+j],a); a=fmaf(xv.y,w_xp_t[(dq+1)*35+j],a);
        a=fmaf(xv.z,w_xp_t[(dq+2)*35+j],a); a=fmaf(xv.w,w_xp_t[(dq+3)*35+j],a);
      }
      a=fmaf(s_xc[l*CPAD+80],w_xp_t[80*35+j],a);
      a=fmaf(s_xc[l*CPAD+81],w_xp_t[81*35+j],a);
      const int col=(j<3)?j:j+1;
      s_xdbc[l*JPAD+col]=a;
    }
    __syncthreads();
    for (int w=tid;w<TSUB*DIN;w+=256){
      const int l=w&15,dd=w>>4;
      float a=s_dtb[dd];
      a=fmaf(s_xdbc[l*JPAD+0],s_dtw[dd*3+0],a);
      a=fmaf(s_xdbc[l*JPAD+1],s_dtw[dd*3+1],a);
      a=fmaf(s_xdbc[l*JPAD+2],s_dtw[dd*3+2],a);
      s_xs[l*SPAD+dd]=softplusf(a);
    }
    __syncthreads();
    if (tid<DIN){
      const int dd=tid;
#pragma unroll 1
      for (int l=0;l<TSUB;++l){
        const float dl=s_xs[l*SPAD+dd];
        const float xcd=s_xc[l*CPAD+dd];
        const float dxc=dl*xcd;
        const float4 B0=*(const float4*)&s_xdbc[l*JPAD+4];
        const float4 B1=*(const float4*)&s_xdbc[l*JPAD+8];
        const float4 B2=*(const float4*)&s_xdbc[l*JPAD+12];
        const float4 B3=*(const float4*)&s_xdbc[l*JPAD+16];
        const float Bv[NSTATE]={B0.x,B0.y,B0.z,B0.w,B1.x,B1.y,B1.z,B1.w,
                                B2.x,B2.y,B2.z,B2.w,B3.x,B3.y,B3.z,B3.w};
        float Cv[NSTATE];
        if (PASS==3){
          const float4 C0=*(const float4*)&s_xdbc[l*JPAD+20];
          const float4 C1=*(const float4*)&s_xdbc[l*JPAD+24];
          const float4 C2=*(const float4*)&s_xdbc[l*JPAD+28];
          const float4 C3=*(const float4*)&s_xdbc[l*JPAD+32];
          Cv[0]=C0.x;Cv[1]=C0.y;Cv[2]=C0.z;Cv[3]=C0.w;
          Cv[4]=C1.x;Cv[5]=C1.y;Cv[6]=C1.z;Cv[7]=C1.w;
          Cv[8]=C2.x;Cv[9]=C2.y;Cv[10]=C2.z;Cv[11]=C2.w;
          Cv[12]=C3.x;Cv[13]=C3.y;Cv[14]=C3.z;Cv[15]=C3.w;
        }
        float y=(PASS==3)?Dd*xcd:0.f;
        if (structured){
          const float q=expf(dl*A0);
          float e=q;
#pragma unroll
          for (int s=0;s<NSTATE;++s){
            h[s]=fmaf(e,h[s],dxc*Bv[s]);
            if (PASS==1) Pp[s]*=e; else y=fmaf(h[s],Cv[s],y);
            if (s<NSTATE-1) e*=q;
          }
        } else {
#pragma unroll
          for (int s=0;s<NSTATE;++s){
            const float e=expf(dl*As[s]);
            h[s]=fmaf(e,h[s],dxc*Bv[s]);
            if (PASS==1) Pp[s]*=e; else y=fmaf(h[s],Cv[s],y);
          }
        }
        if (PASS==3) s_xs[l*SPAD+dd]=y;
      }
    }
    __syncthreads();
    if (PASS==3){
      for (int w=tid;w<TSUB*DIN;w+=256){
        const int l=w&15,dd=w>>4;
        s_xc[l*CPAD+dd]=s_xs[l*SPAD+dd]*siluf(s_z[l*SPAD+dd]);
      }
      __syncthreads();
      for (int w=tid;w<TSUB*DMODEL;w+=256){
        const int l=w&15,dm=w>>4;
        const float2* wp=(const float2*)(w_out+dm*DIN);
        const float2* gp=(const float2*)&s_xc[l*CPAD];
        float a=0.f;
#pragma unroll
        for (int dq=0;dq<41;++dq){
          const float2 wv=wp[dq], gv=gp[dq];
          a=fmaf(wv.x,gv.x,a); a=fmaf(wv.y,gv.y,a);
        }
        s_x[l*XPAD+dm]=a;
      }
      __syncthreads();
      for (int w=tid;w<TSUB*NLAB;w+=256){
        const int l=w&15,n=w>>4;
        float a=b_cls[n];
#pragma unroll
        for (int dm=0;dm<DMODEL;++dm) a=fmaf(w_cls[n*DMODEL+dm],s_x[l*XPAD+dm],a);
        s_xdbc[l*NLAB+n]=a;
      }
      __syncthreads();
      for (int i=tid;i<TSUB*NLAB;i+=256)
        outg[((size_t)(b*SEQ+p0))*NLAB+i]=s_xdbc[i];
      __syncthreads();
    }
  }

  if (PASS==1 && tid<DIN){
    size_t base=((size_t)(b*NCHUNK+c))*(DIN*NSTATE)+(size_t)tid*NSTATE;
#pragma unroll
    for (int s=0;s<NSTATE;++s){ Pg[base+s]=Pp[s]; Hg[base+s]=h[s]; }
  }
}

__global__ __launch_bounds__(256) void mamba_combine(
    const float* __restrict__ P, const float* __restrict__ H, float* __restrict__ Hin){
  const int g=blockIdx.x*256+threadIdx.x;
  const int b=g/(DIN*NSTATE), ds=g-b*(DIN*NSTATE);
  float h=0.f;
#pragma unroll 1
  for (int c=0;c<NCHUNK;++c){
    const size_t idx=((size_t)(b*NCHUNK+c))*(DIN*NSTATE)+ds;
    Hin[idx]=h;
    h=fmaf(P[idx],h,H[idx]);
  }
}

// ============================================================================

extern "C" void kernel_launch(void* const* d_in, const int* in_sizes, int n_in,
                              void* d_out, int out_size, void* d_ws, size_t ws_size,
                              hipStream_t stream) {
  const float* xg     = (const float*)d_in[0];
  const float* w_in   = (const float*)d_in[1];
  const float* w_conv = (const float*)d_in[2];
  const float* b_conv = (const float*)d_in[3];
  const float* w_xp   = (const float*)d_in[4];
  const float* w_dt   = (const float*)d_in[5];
  const float* b_dt   = (const float*)d_in[6];
  const float* A_log  = (const float*)d_in[7];
  const float* Dv     = (const float*)d_in[8];
  const float* w_out  = (const float*)d_in[9];
  const float* w_cls  = (const float*)d_in[10];
  const float* b_cls  = (const float*)d_in[11];
  float* outg = (float*)d_out;

  int P = 0;
  for (int p : {1,2,4,8}) if (ws_size >= tier_bytes(p)) { P = p; break; }

  if (P) {
    const int SEG = SEQ/P, tiles = SEG/T0;
    const size_t featF = (size_t)BATCH*SEG*FREC;
    const size_t phF   = (size_t)BATCH*tiles*1312;
    float* feat  = (float*)d_ws;
    float* Pg    = feat + featF;
    float* Hg    = Pg + phF;
    float* Hin   = Hg + phF;
    float* carry = Hin + phF;
    float* Mg    = carry + (size_t)BATCH*1312;
    k_pre<<<dim3(4),256,0,stream>>>(w_out, w_cls, Mg);
    for (int p=0;p<P;p++){
      const int off = p*SEG;
      k0_feat<<<dim3(tiles,BATCH),256,0,stream>>>(
          xg,w_in,w_conv,b_conv,w_xp,w_dt,b_dt,A_log,Dv,off,SEG,feat,Pg,Hg);
      k2_comb<<<dim3((BATCH*1312)/256),256,0,stream>>>(Pg,Hg,Hin,carry,tiles,p==0?1:0);
      k4_out<<<dim3(tiles,BATCH),256,0,stream>>>(
          xg,w_in,A_log,Mg,b_cls,off,SEG,feat,Hin,outg);
    }
  } else {
    float* Pg  = (float*)d_ws;
    float* Hg  = Pg + NPH_OLD;
    float* Hin = Hg + NPH_OLD;
    dim3 grid(BATCH*NCHUNK), blk(256);
    mamba_chunk<1><<<grid,blk,0,stream>>>(xg,w_in,w_conv,b_conv,w_xp,w_dt,b_dt,
                                          A_log,Dv,w_out,w_cls,b_cls,Pg,Hg,nullptr,nullptr);
    mamba_combine<<<dim3((BATCH*DIN*NSTATE)/256),blk,0,stream>>>(Pg,Hg,Hin);
    mamba_chunk<3><<<grid,blk,0,stream>>>(xg,w_in,w_conv,b_conv,w_xp,w_dt,b_dt,
                                          A_log,Dv,w_out,w_cls,b_cls,nullptr,nullptr,Hin,outg);
  }
}

// Round 5
// 656.446 us; speedup vs baseline: 1.2713x; 1.0114x over previous
//
#include <hip/hip_runtime.h>
#include <math.h>

// Mamba block, fp32, single-scan + closed-form seeding + fused epilogue.
// k_pre  : M = w_cls@w_out (10x82) into ws.
// k0_feat: features once + local scan -> per-pos (yloc, Dp, C) record staged in
//          LDS, then ONE batched float4 writeout per subtile (full-line writes,
//          no partial-dirty-line RMW). Weights in LDS.
// k2_comb: sequential combine over tiles -> Hin per tile (carry across phases).
// k4_out : z-proj (LDS weights), closed-form corr, gate, fused M-GEMM logits.
// R12: base = R7 (proven 644.9us) + exactly TWO register-neutral k0 edits:
//   - D: 2 x_proj cols/thread (288 items; s_xc row float2 reused for both
//     cols). Phase-local temps only; D's peak liveness < B's -> no VGPR delta.
//   - A: halo shift as float2 (123 moves instead of 246 scalar).
//   Everything else byte-identical to R7 (D2, E w/ As[8], C, F, k4, k2, old).
// HARD-WON CONSTRAINTS (R8-R11 post-mortems):
//  - __launch_bounds__(256,n): n = resident blocks AND VGPR cap ~256/n.
//    (256,2) -> 2 blocks resident (occ 24%, -34%) even though VGPR fine.
//    (256,4) -> 64 VGPR hard cap: ANY growth of loop-carried state spills
//    (R8 wreg[21]: FETCH 50->210MB; R11 E-fold dtw/dtb+qv: FETCH 50->77MB).
//    Phase-local temporaries below the B-phase peak (~20) are safe.
//  - k0/k4 are LDS-pipe/issue bound, NOT occupancy bound (R8: ceiling 4->6
//    blocks left occupancy at 43%) and NOT HBM bound (12.6%). Broadcast LDS
//    reads (same addr across lanes) are ~free: k4-C float4 was neutral (R11).
//  - weights MUST be in LDS (R7): global weights miss under feat streaming.
// OLD path (proven): fallback if ws too small.

namespace {
constexpr int DMODEL=41, DIN=82, NSTATE=16, NLAB=10, BATCH=32, SEQ=8192;
// old path
constexpr int CHUNK=512, NCHUNK=SEQ/CHUNK, TSUB=16, NSUB=CHUNK/TSUB, RWS=TSUB+3;
constexpr int XPAD=44, SPAD=83, CPAD=84, JPAD=36;
constexpr int NPH_OLD = BATCH*NCHUNK*DIN*NSTATE;
// new path
constexpr int T0 = 64;              // positions per k0/k4 tile
constexpr int FREC = 180;           // yloc@0(82) | Dp@82(82) | C@164(16)
inline size_t tier_bytes(int P){
  size_t SEG = (size_t)SEQ/P, tiles = SEG/T0;
  return ((size_t)BATCH*SEG*FREC + 3*((size_t)BATCH*tiles*1312)
          + (size_t)BATCH*1312 + 4096)*4;
}
}

__device__ __forceinline__ float siluf(float v)     { return v / (1.f + expf(-v)); }
__device__ __forceinline__ float softplusf(float v) { return (v > 20.f) ? v : log1pf(expf(v)); }
// fast variants (validated: absmax unchanged at 5.96e-8)
__device__ __forceinline__ float silu_f(float v){
  return v * __builtin_amdgcn_rcpf(1.f + __expf(-v));
}
__device__ __forceinline__ float softplus_f(float v){
  return (v > 20.f) ? v : __logf(1.f + __expf(v));
}

// in_proj helper: NR rows from r0, col e(<82), weights in LDS [k*82+e],
// x stride 44, out stride 82
template<int NR>
__device__ __forceinline__ void inproj_rows(int r0, int e,
    const float* __restrict__ sx, const float* __restrict__ wt,
    float* __restrict__ sxs) {
  float acc[NR];
#pragma unroll
  for (int i=0;i<NR;i++) acc[i]=0.f;
#pragma unroll
  for (int kq=0;kq<40;kq+=4){
    const float w0=wt[(kq+0)*82+e], w1=wt[(kq+1)*82+e];
    const float w2=wt[(kq+2)*82+e], w3=wt[(kq+3)*82+e];
#pragma unroll
    for (int i=0;i<NR;i++){
      const float4 xv = *(const float4*)&sx[(r0+i)*44+kq];
      acc[i]=fmaf(xv.x,w0,acc[i]); acc[i]=fmaf(xv.y,w1,acc[i]);
      acc[i]=fmaf(xv.z,w2,acc[i]); acc[i]=fmaf(xv.w,w3,acc[i]);
    }
  }
  const float wl = wt[40*82+e];
#pragma unroll
  for (int i=0;i<NR;i++)
    sxs[(r0+i)*82+e] = fmaf(sx[(r0+i)*44+40], wl, acc[i]);
}

// ============================================================================
// NEW PATH
// ============================================================================

__global__ __launch_bounds__(256) void k_pre(
    const float* __restrict__ w_out, const float* __restrict__ w_cls,
    float* __restrict__ M){
  const int w = blockIdx.x*256 + threadIdx.x;
  if (w < NLAB*DIN){
    const int n = w/82, dd = w - n*82;
    float a = 0.f;
#pragma unroll
    for (int dm=0;dm<41;dm++) a = fmaf(w_cls[n*41+dm], w_out[dm*82+dd], a);
    M[w] = a;
  }
}

__launch_bounds__(256, 4)
__global__ void k0_feat(
    const float* __restrict__ xg, const float* __restrict__ w_in,
    const float* __restrict__ w_conv, const float* __restrict__ b_conv,
    const float* __restrict__ w_xproj, const float* __restrict__ w_dt,
    const float* __restrict__ b_dt, const float* __restrict__ A_log,
    const float* __restrict__ Dvec, int off, int SEG,
    float* __restrict__ feat, float* __restrict__ Pg, float* __restrict__ Hg)
{
  __shared__ float s_x[19*44];    // raw x rows (pos p0-3 .. p0+15)
  __shared__ float s_xs[19*82];   // xs rows incl conv halo
  __shared__ float s_xc[16*82];   // xc; scan overwrites with yloc
  __shared__ float s_q[16*82];    // delta; scan overwrites with Dp
  __shared__ float s_db[16*36];   // dt@0..2, B@4..19, C@20..35
  __shared__ float w_t[41*82];    // in_proj xs-half transposed [k][e] (LDS!)
  __shared__ float s_cw[4*82];    // conv w transposed [k][d]
  __shared__ float s_dtw[3*82];   // dt w transposed [k][d]
  __shared__ float s_cb[82], s_dtb[82], s_A0[82], s_Dv[82];
  __shared__ int   s_flag[82];
  // ~39.8 KB -> 4 blocks/CU

  const int tid = threadIdx.x;
  const int tile = blockIdx.x, b = blockIdx.y;
  const int base_pos = off + tile*T0;

  for (int i=tid;i<41*82;i+=256){ int k=i/82,e=i-k*82; w_t[i]=w_in[e*41+k]; }
  for (int i=tid;i<328;i+=256){ int dd=i/4,k=i-dd*4; s_cw[k*82+dd]=w_conv[i]; }
  for (int i=tid;i<246;i+=256){ int dd=i/3,k=i-dd*3; s_dtw[k*82+dd]=w_dt[i]; }
  if (tid<82){
    s_cb[tid]=b_conv[tid]; s_dtb[tid]=b_dt[tid]; s_Dv[tid]=Dvec[tid];
    float A0=-expf(A_log[tid*16]); s_A0[tid]=A0;
    bool ok=(A0<0.f);
#pragma unroll
    for (int s=1;s<16;s++){
      float As=-expf(A_log[tid*16+s]);
      ok = ok && (fabsf(As-(float)(s+1)*A0) <= 1e-3f*(float)(s+1)*fabsf(A0));
    }
    s_flag[tid]=ok?1:0;
  }
  __syncthreads();

  const int d = tid>>1, sg = tid&1;
  float h[8], As[8], A0d=-1.f, Dp=0.f;
  int flag=1;
  if (tid<164){
    flag = s_flag[d]; A0d = s_A0[d];
    if (!flag){
#pragma unroll
      for (int i=0;i<8;i++) As[i]=-expf(A_log[d*16+sg*8+i]);
    }
#pragma unroll
    for (int i=0;i<8;i++) h[i]=0.f;
  }

  for (int it=0; it<T0/16; ++it){
    const int p0 = base_pos + it*16;
    // ---- A: halo shift (float2) + raw x load ----
    if (it>0){
      for (int i=tid;i<123;i+=256){
        const int r=i/41, m=i-r*41;
        *(float2*)&s_xs[r*82+2*m] = *(const float2*)&s_xs[(16+r)*82+2*m];
      }
    }
    {
      const int rlo=(it==0)?0:3, cnt=(19-rlo)*41;
      for (int i=tid;i<cnt;i+=256){
        int r=rlo+i/41, k=i-(i/41)*41;
        int pos=p0-3+r;
        s_x[r*44+k] = (pos>=0) ? xg[((size_t)b*SEQ+(size_t)pos)*41+k] : 0.f;
      }
    }
    __syncthreads();
    // ---- B: in_proj (xs half), 2 threads/column, weights in LDS ----
    if (tid<164){
      const int e=(tid<82)?tid:tid-82, rh=(tid>=82);
      if (it==0){ if(!rh) inproj_rows<10>(0,e,s_x,w_t,s_xs); else inproj_rows<9>(10,e,s_x,w_t,s_xs); }
      else      { inproj_rows<8>(rh?11:3,e,s_x,w_t,s_xs); }
    }
    __syncthreads();
    // ---- C: conv + silu -> s_xc ----
    for (int w=tid;w<1312;w+=256){
      const int l=w&15, dd=w>>4;
      float a=s_cb[dd];
#pragma unroll
      for (int k=0;k<4;k++) a=fmaf(s_xs[(l+k)*82+dd], s_cw[k*82+dd], a);
      s_xc[l*82+dd]=silu_f(a);
    }
    __syncthreads();
    // ---- D: x_proj (35 rows), 2 cols/thread (s_xc row read reused 2x) ----
    for (int w=tid;w<288;w+=256){
      const int l=w&15, jp=w>>4;            // jp 0..17
      const int j0=2*jp;
      const int j1=(jp<17)?(j0+1):34;       // jp=17 duplicates j=34 (benign)
      const float2* wp0=(const float2*)(w_xproj + j0*82);
      const float2* wp1=(const float2*)(w_xproj + j1*82);
      const float2* gp=(const float2*)&s_xc[l*82];
      float a0=0.f, a1=0.f;
#pragma unroll
      for (int dq=0;dq<41;dq++){
        const float2 gv=gp[dq];
        const float2 wv0=wp0[dq], wv1=wp1[dq];
        a0=fmaf(gv.x,wv0.x,a0); a0=fmaf(gv.y,wv0.y,a0);
        a1=fmaf(gv.x,wv1.x,a1); a1=fmaf(gv.y,wv1.y,a1);
      }
      const int c0=(j0<3)?j0:j0+1;
      const int c1=(j1<3)?j1:j1+1;
      s_db[l*36+c0]=a0;
      s_db[l*36+c1]=a1;
    }
    __syncthreads();
    // ---- D2: dt_proj + softplus -> delta ----
    for (int w=tid;w<1312;w+=256){
      const int l=w&15, dd=w>>4;
      float a=s_dtb[dd];
      a=fmaf(s_db[l*36+0],s_dtw[0*82+dd],a);
      a=fmaf(s_db[l*36+1],s_dtw[1*82+dd],a);
      a=fmaf(s_db[l*36+2],s_dtw[2*82+dd],a);
      s_q[l*82+dd]=softplus_f(a);
    }
    __syncthreads();
    // ---- E: local scan; stage yloc into s_xc, Dp into s_q (in place) ----
    if (tid<164){
#pragma unroll 1
      for (int l=0;l<16;l++){
        const float dl  = s_q[l*82+d];
        const float xc  = s_xc[l*82+d];
        const float dxc = dl*xc;
        Dp += dl;
        const float4 B0=*(const float4*)&s_db[l*36+4+sg*8];
        const float4 B1=*(const float4*)&s_db[l*36+8+sg*8];
        const float4 C0=*(const float4*)&s_db[l*36+20+sg*8];
        const float4 C1=*(const float4*)&s_db[l*36+24+sg*8];
        const float Bv[8]={B0.x,B0.y,B0.z,B0.w,B1.x,B1.y,B1.z,B1.w};
        const float Cv[8]={C0.x,C0.y,C0.z,C0.w,C1.x,C1.y,C1.z,C1.w};
        float y=0.f;
        if (flag){
          const float q=__expf(dl*A0d);
          const float q2=q*q, q4=q2*q2;
          float e = sg ? q4*q4*q : q;
#pragma unroll
          for (int s=0;s<8;s++){
            h[s]=fmaf(e,h[s],dxc*Bv[s]);
            y=fmaf(h[s],Cv[s],y);
            if(s<7) e*=q;
          }
        } else {
#pragma unroll
          for (int s=0;s<8;s++){
            const float e=__expf(dl*As[s]);
            h[s]=fmaf(e,h[s],dxc*Bv[s]);
            y=fmaf(h[s],Cv[s],y);
          }
        }
        y += __shfl_down(y,1);
        if (sg==0){
          // pair lanes are lockstep: both read xc/dl above before these writes
          s_xc[l*82+d] = y + xc*s_Dv[d];   // yloc
          s_q [l*82+d] = Dp;               // prefix-sum of delta
        }
      }
    }
    __syncthreads();
    // ---- F: batched record writeout (720 float4 = 16 recs x 180 floats) ----
    {
      float* fb = feat + ((size_t)b*SEG + (size_t)(tile*T0+it*16))*FREC;
      for (int i=tid;i<720;i+=256){
        const int l=i/45, q=i-l*45;
        const int f=4*q;
        float4 v;
        if (q<20){
          v.x=s_xc[l*82+f+0]; v.y=s_xc[l*82+f+1];
          v.z=s_xc[l*82+f+2]; v.w=s_xc[l*82+f+3];
        } else if (q==20){
          v.x=s_xc[l*82+80]; v.y=s_xc[l*82+81];
          v.z=s_q[l*82+0];   v.w=s_q[l*82+1];
        } else if (q<=40){
          v.x=s_q[l*82+f-82]; v.y=s_q[l*82+f-81];
          v.z=s_q[l*82+f-80]; v.w=s_q[l*82+f-79];
        } else {
          const int c=f-164;
          v.x=s_db[l*36+20+c+0]; v.y=s_db[l*36+20+c+1];
          v.z=s_db[l*36+20+c+2]; v.w=s_db[l*36+20+c+3];
        }
        *(float4*)&fb[(size_t)l*FREC + f] = v;
      }
    }
    // no trailing barrier: next C/D2 writes to s_xc/s_q are 2+ barriers away
  }

  if (tid<164){
    float Pv[8];
    if (flag){
      const float Qt=__expf(Dp*A0d);
      const float Q2=Qt*Qt, Q4=Q2*Q2, Q8=Q4*Q4;
      float c = sg ? Q8*Qt : Qt;
#pragma unroll
      for (int i=0;i<8;i++){ Pv[i]=c; c*=Qt; }
    } else {
#pragma unroll
      for (int i=0;i<8;i++) Pv[i]=__expf(Dp*As[i]);
    }
    const size_t base = ((size_t)(b*gridDim.x+tile))*1312 + (size_t)d*16 + sg*8;
    *(float4*)&Pg[base]   = make_float4(Pv[0],Pv[1],Pv[2],Pv[3]);
    *(float4*)&Pg[base+4] = make_float4(Pv[4],Pv[5],Pv[6],Pv[7]);
    *(float4*)&Hg[base]   = make_float4(h[0],h[1],h[2],h[3]);
    *(float4*)&Hg[base+4] = make_float4(h[4],h[5],h[6],h[7]);
  }
}

__global__ __launch_bounds__(256) void k2_comb(
    const float* __restrict__ Pg, const float* __restrict__ Hg,
    float* __restrict__ Hin, float* __restrict__ carry, int TPP, int first)
{
  const int g = blockIdx.x*256 + threadIdx.x;   // < 32*1312
  const int b = g/1312, r = g - b*1312;
  float h = first ? 0.f : carry[g];
#pragma unroll 4
  for (int t=0;t<TPP;t++){
    const size_t idx = ((size_t)(b*TPP+t))*1312 + r;
    Hin[idx]=h;
    h = fmaf(Pg[idx], h, Hg[idx]);
  }
  carry[g]=h;
}

__launch_bounds__(256, 4)
__global__ void k4_out(
    const float* __restrict__ xg, const float* __restrict__ w_in,
    const float* __restrict__ A_log, const float* __restrict__ Mg,
    const float* __restrict__ b_cls, int off, int SEG,
    const float* __restrict__ feat, const float* __restrict__ Hin,
    float* __restrict__ outg)
{
  __shared__ float s_x[16*44];    // raw x rows
  __shared__ float w_zt[41*82];   // in_proj z-half transposed [k][e] (LDS!)
  __shared__ float s_z[16*82];    // silu(z)
  __shared__ float s_g[16*82];    // gated value
  __shared__ float s_c[16*16];    // C rows
  __shared__ float s_hin[1312];   // s-major [s*82+d]
  __shared__ float s_M[10*82];    // fused Wc*Wo
  __shared__ float s_A0[82], s_bc[10];
  __shared__ int   s_flag[82];
  // ~37.1 KB -> 4 blocks/CU

  const int tid = threadIdx.x;
  const int tile = blockIdx.x, b = blockIdx.y;

  for (int i=tid;i<41*82;i+=256){ int k=i/82,e=i-k*82; w_zt[i]=w_in[(82+e)*41+k]; }
  for (int i=tid;i<1312;i+=256){
    const int dd=i>>4, s=i&15;
    s_hin[s*82+dd] = Hin[((size_t)(b*gridDim.x+tile))*1312 + i];
  }
  for (int i=tid;i<820;i+=256) s_M[i]=Mg[i];
  if (tid<10) s_bc[tid]=b_cls[tid];
  if (tid<82){
    float A0=-expf(A_log[tid*16]); s_A0[tid]=A0;
    bool ok=(A0<0.f);
#pragma unroll
    for (int s=1;s<16;s++){
      float As=-expf(A_log[tid*16+s]);
      ok = ok && (fabsf(As-(float)(s+1)*A0) <= 1e-3f*(float)(s+1)*fabsf(A0));
    }
    s_flag[tid]=ok?1:0;
  }
  // hoisted (l,d) decomposition for the 1312-item stage
  int lk[6], dk[6];
#pragma unroll
  for (int k=0;k<6;k++){ const int w=tid+256*k; lk[k]=w/82; dk[k]=w-lk[k]*82; }

  for (int it=0; it<T0/16; ++it){
    const int lp0 = tile*T0 + it*16;
    const int gp0 = off + lp0;
    __syncthreads();
    // ---- A: load raw x + C rows ----
    for (int i=tid;i<656;i+=256){
      const int r=i/41, k=i-r*41;
      s_x[r*44+k] = xg[((size_t)b*SEQ+(size_t)(gp0+r))*41+k];
    }
    for (int i=tid;i<64;i+=256){
      const int l=i>>2, q=i&3;
      ((float4*)&s_c[l*16])[q] =
          ((const float4*)(feat + ((size_t)b*SEG+(size_t)(lp0+l))*FREC + 164))[q];
    }
    __syncthreads();
    // ---- B: z-proj (LDS weights), 2 threads/column, 8 rows -> silu ----
    if (tid<164){
      const int e=(tid<82)?tid:tid-82, l0=(tid>=82)?8:0;
      float acc[8];
#pragma unroll
      for (int i=0;i<8;i++) acc[i]=0.f;
#pragma unroll
      for (int kq=0;kq<40;kq+=4){
        const float w0=w_zt[(kq+0)*82+e], w1=w_zt[(kq+1)*82+e];
        const float w2=w_zt[(kq+2)*82+e], w3=w_zt[(kq+3)*82+e];
#pragma unroll
        for (int i=0;i<8;i++){
          const float4 xv=*(const float4*)&s_x[(l0+i)*44+kq];
          acc[i]=fmaf(xv.x,w0,acc[i]); acc[i]=fmaf(xv.y,w1,acc[i]);
          acc[i]=fmaf(xv.z,w2,acc[i]); acc[i]=fmaf(xv.w,w3,acc[i]);
        }
      }
      const float wl=w_zt[40*82+e];
#pragma unroll
      for (int i=0;i<8;i++)
        s_z[(l0+i)*82+e] = silu_f(fmaf(s_x[(l0+i)*44+40], wl, acc[i]));
    }
    __syncthreads();
    // ---- C: closed-form correction + gate ----
#pragma unroll
    for (int k=0;k<6;k++){
      const int w=tid+256*k;
      if (w>=1312) break;
      const int l=lk[k], dd=dk[k];
      const float* fp = feat + ((size_t)b*SEG+(size_t)(lp0+l))*FREC;
      const float yl = fp[dd];
      const float Dp = fp[82+dd];
      float acc=yl;
      if (s_flag[dd]){
        const float Qt=__expf(s_A0[dd]*Dp);
        float e=Qt;
#pragma unroll
        for (int s=0;s<16;s++){
          acc = fmaf(s_c[l*16+s]*e, s_hin[s*82+dd], acc);
          if (s<15) e*=Qt;
        }
      } else {
#pragma unroll
        for (int s=0;s<16;s++){
          const float As = -__expf(A_log[dd*16+s]);
          acc = fmaf(s_c[l*16+s]*__expf(As*Dp), s_hin[s*82+dd], acc);
        }
      }
      s_g[l*82+dd] = acc * s_z[l*82+dd];
    }
    __syncthreads();
    // ---- D: fused logits = M*g + b, contiguous store ----
    if (tid<160){
      const int l=tid/10, n=tid-(tid/10)*10;
      float a=s_bc[n];
      const float2* gp=(const float2*)&s_g[l*82];
      const float2* mp=(const float2*)&s_M[n*82];
#pragma unroll
      for (int q=0;q<41;q++){
        const float2 gv=gp[q], mv=mp[q];
        a=fmaf(gv.x,mv.x,a); a=fmaf(gv.y,mv.y,a);
      }
      outg[((size_t)b*SEQ+(size_t)gp0)*10 + tid] = a;
    }
    // no trailing barrier: top-of-loop sync protects s_x/s_c overwrite
  }
}

// ============================================================================
// OLD PATH (proven fallback)
// ============================================================================

template <int PASS>
__launch_bounds__(256, 2)
__global__ void mamba_chunk(
    const float* __restrict__ xg, const float* __restrict__ w_in,
    const float* __restrict__ w_conv, const float* __restrict__ b_conv,
    const float* __restrict__ w_xproj, const float* __restrict__ w_dt,
    const float* __restrict__ b_dt, const float* __restrict__ A_log,
    const float* __restrict__ Dvec, const float* __restrict__ w_out,
    const float* __restrict__ w_cls, const float* __restrict__ b_cls,
    float* __restrict__ Pg, float* __restrict__ Hg,
    const float* __restrict__ Hin, float* __restrict__ outg)
{
  __shared__ float s_x[RWS*XPAD];
  __shared__ float s_xs[RWS*SPAD];
  __shared__ float s_xc[TSUB*CPAD];
  __shared__ float s_z[TSUB*SPAD];
  __shared__ float s_xdbc[TSUB*JPAD];
  __shared__ float w_in_t[DMODEL*164];
  __shared__ float w_xp_t[DIN*35];
  __shared__ float s_cw[DIN*4];
  __shared__ float s_cb[DIN];
  __shared__ float s_dtw[DIN*3];
  __shared__ float s_dtb[DIN];

  const int tid=threadIdx.x;
  const int b=blockIdx.x/NCHUNK, c=blockIdx.x%NCHUNK, l0c=c*CHUNK;
  constexpr int NJ=(PASS==3)?35:19;
  constexpr int NE=(PASS==3)?164:DIN;

  for (int i=tid;i<DMODEL*164;i+=256){ int k=i/164,e=i-k*164; w_in_t[i]=w_in[e*DMODEL+k]; }
  for (int i=tid;i<DIN*35;i+=256){ int dd=i/35,j=i-dd*35; w_xp_t[i]=w_xproj[j*DIN+dd]; }
  for (int i=tid;i<DIN*4;i+=256) s_cw[i]=w_conv[i];
  for (int i=tid;i<DIN*3;i+=256) s_dtw[i]=w_dt[i];
  if (tid<DIN){ s_cb[tid]=b_conv[tid]; s_dtb[tid]=b_dt[tid]; }

  float h[NSTATE], Pp[NSTATE], As[NSTATE];
  float A0=-1.f, Dd=0.f;
  bool structured=true;
  if (tid<DIN){
#pragma unroll
    for (int s=0;s<NSTATE;++s) As[s]=-expf(A_log[tid*NSTATE+s]);
    A0=As[0];
#pragma unroll
    for (int s=0;s<NSTATE;++s)
      structured = structured && (fabsf(As[s]-(float)(s+1)*A0)<=1e-3f*(float)(s+1)*fabsf(A0));
    structured = structured && (A0<0.f);
    if (PASS==3){
      Dd=Dvec[tid];
      size_t base=((size_t)(b*NCHUNK+c))*(DIN*NSTATE)+(size_t)tid*NSTATE;
#pragma unroll
      for (int s=0;s<NSTATE;++s) h[s]=Hin[base+s];
    } else {
#pragma unroll
      for (int s=0;s<NSTATE;++s){ h[s]=0.f; Pp[s]=1.f; }
    }
  }
  __syncthreads();

  for (int t=0;t<NSUB;++t){
    const int p0=l0c+t*TSUB;
    for (int i=tid;i<RWS*DMODEL;i+=256){
      int r=i/DMODEL,k=i-r*DMODEL;
      int pos=p0-3+r;
      s_x[r*XPAD+k]=(pos>=0)?xg[(size_t)b*SEQ*DMODEL+(size_t)pos*DMODEL+k]:0.f;
    }
    __syncthreads();
    {
      const int e=tid;
      if (e<NE){
        float acc[RWS];
#pragma unroll
        for (int r=0;r<RWS;++r) acc[r]=0.f;
#pragma unroll
        for (int kq=0;kq<40;kq+=4){
          const float w0=w_in_t[(kq+0)*164+e], w1=w_in_t[(kq+1)*164+e];
          const float w2=w_in_t[(kq+2)*164+e], w3=w_in_t[(kq+3)*164+e];
#pragma unroll
          for (int r=0;r<RWS;++r){
            const float4 xv=*(const float4*)&s_x[r*XPAD+kq];
            acc[r]=fmaf(xv.x,w0,acc[r]); acc[r]=fmaf(xv.y,w1,acc[r]);
            acc[r]=fmaf(xv.z,w2,acc[r]); acc[r]=fmaf(xv.w,w3,acc[r]);
          }
        }
        const float wl=w_in_t[40*164+e];
#pragma unroll
        for (int r=0;r<RWS;++r) acc[r]=fmaf(s_x[r*XPAD+40],wl,acc[r]);
        if (e<DIN){
#pragma unroll
          for (int r=0;r<RWS;++r) s_xs[r*SPAD+e]=acc[r];
        } else {
#pragma unroll
          for (int r=3;r<RWS;++r) s_z[(r-3)*SPAD+(e-DIN)]=acc[r];
        }
      }
    }
    __syncthreads();
    for (int w=tid;w<TSUB*DIN;w+=256){
      const int l=w&15,e=w>>4;
      float a=s_cb[e];
#pragma unroll
      for (int k=0;k<4;++k) a=fmaf(s_xs[(l+k)*SPAD+e],s_cw[e*4+k],a);
      s_xc[l*CPAD+e]=siluf(a);
    }
    __syncthreads();
    for (int w=tid;w<TSUB*NJ;w+=256){
      const int l=w&15,j=w>>4;
      float a=0.f;
#pragma unroll
      for (int dq=0;dq<80;dq+=4){
        const float4 xv=*(const float4*)&s_xc[l*CPAD+dq];
        a=fmaf(xv.x,w_xp_t[(dq+0)*35+j],a); a=fmaf(xv.y,w_xp_t[(dq+1)*35+j],a);
        a=fmaf(xv.z,w_xp_t[(dq+2)*35+j],a); a=fmaf(xv.w,w_xp_t[(dq+3)*35+j],a);
      }
      a=fmaf(s_xc[l*CPAD+80],w_xp_t[80*35+j],a);
      a=fmaf(s_xc[l*CPAD+81],w_xp_t[81*35+j],a);
      const int col=(j<3)?j:j+1;
      s_xdbc[l*JPAD+col]=a;
    }
    __syncthreads();
    for (int w=tid;w<TSUB*DIN;w+=256){
      const int l=w&15,dd=w>>4;
      float a=s_dtb[dd];
      a=fmaf(s_xdbc[l*JPAD+0],s_dtw[dd*3+0],a);
      a=fmaf(s_xdbc[l*JPAD+1],s_dtw[dd*3+1],a);
      a=fmaf(s_xdbc[l*JPAD+2],s_dtw[dd*3+2],a);
      s_xs[l*SPAD+dd]=softplusf(a);
    }
    __syncthreads();
    if (tid<DIN){
      const int dd=tid;
#pragma unroll 1
      for (int l=0;l<TSUB;++l){
        const float dl=s_xs[l*SPAD+dd];
        const float xcd=s_xc[l*CPAD+dd];
        const float dxc=dl*xcd;
        const float4 B0=*(const float4*)&s_xdbc[l*JPAD+4];
        const float4 B1=*(const float4*)&s_xdbc[l*JPAD+8];
        const float4 B2=*(const float4*)&s_xdbc[l*JPAD+12];
        const float4 B3=*(const float4*)&s_xdbc[l*JPAD+16];
        const float Bv[NSTATE]={B0.x,B0.y,B0.z,B0.w,B1.x,B1.y,B1.z,B1.w,
                                B2.x,B2.y,B2.z,B2.w,B3.x,B3.y,B3.z,B3.w};
        float Cv[NSTATE];
        if (PASS==3){
          const float4 C0=*(const float4*)&s_xdbc[l*JPAD+20];
          const float4 C1=*(const float4*)&s_xdbc[l*JPAD+24];
          const float4 C2=*(const float4*)&s_xdbc[l*JPAD+28];
          const float4 C3=*(const float4*)&s_xdbc[l*JPAD+32];
          Cv[0]=C0.x;Cv[1]=C0.y;Cv[2]=C0.z;Cv[3]=C0.w;
          Cv[4]=C1.x;Cv[5]=C1.y;Cv[6]=C1.z;Cv[7]=C1.w;
          Cv[8]=C2.x;Cv[9]=C2.y;Cv[10]=C2.z;Cv[11]=C2.w;
          Cv[12]=C3.x;Cv[13]=C3.y;Cv[14]=C3.z;Cv[15]=C3.w;
        }
        float y=(PASS==3)?Dd*xcd:0.f;
        if (structured){
          const float q=expf(dl*A0);
          float e=q;
#pragma unroll
          for (int s=0;s<NSTATE;++s){
            h[s]=fmaf(e,h[s],dxc*Bv[s]);
            if (PASS==1) Pp[s]*=e; else y=fmaf(h[s],Cv[s],y);
            if (s<NSTATE-1) e*=q;
          }
        } else {
#pragma unroll
          for (int s=0;s<NSTATE;++s){
            const float e=expf(dl*As[s]);
            h[s]=fmaf(e,h[s],dxc*Bv[s]);
            if (PASS==1) Pp[s]*=e; else y=fmaf(h[s],Cv[s],y);
          }
        }
        if (PASS==3) s_xs[l*SPAD+dd]=y;
      }
    }
    __syncthreads();
    if (PASS==3){
      for (int w=tid;w<TSUB*DIN;w+=256){
        const int l=w&15,dd=w>>4;
        s_xc[l*CPAD+dd]=s_xs[l*SPAD+dd]*siluf(s_z[l*SPAD+dd]);
      }
      __syncthreads();
      for (int w=tid;w<TSUB*DMODEL;w+=256){
        const int l=w&15,dm=w>>4;
        const float2* wp=(const float2*)(w_out+dm*DIN);
        const float2* gp=(const float2*)&s_xc[l*CPAD];
        float a=0.f;
#pragma unroll
        for (int dq=0;dq<41;++dq){
          const float2 wv=wp[dq], gv=gp[dq];
          a=fmaf(wv.x,gv.x,a); a=fmaf(wv.y,gv.y,a);
        }
        s_x[l*XPAD+dm]=a;
      }
      __syncthreads();
      for (int w=tid;w<TSUB*NLAB;w+=256){
        const int l=w&15,n=w>>4;
        float a=b_cls[n];
#pragma unroll
        for (int dm=0;dm<DMODEL;++dm) a=fmaf(w_cls[n*DMODEL+dm],s_x[l*XPAD+dm],a);
        s_xdbc[l*NLAB+n]=a;
      }
      __syncthreads();
      for (int i=tid;i<TSUB*NLAB;i+=256)
        outg[((size_t)(b*SEQ+p0))*NLAB+i]=s_xdbc[i];
      __syncthreads();
    }
  }

  if (PASS==1 && tid<DIN){
    size_t base=((size_t)(b*NCHUNK+c))*(DIN*NSTATE)+(size_t)tid*NSTATE;
#pragma unroll
    for (int s=0;s<NSTATE;++s){ Pg[base+s]=Pp[s]; Hg[base+s]=h[s]; }
  }
}

__global__ __launch_bounds__(256) void mamba_combine(
    const float* __restrict__ P, const float* __restrict__ H, float* __restrict__ Hin){
  const int g=blockIdx.x*256+threadIdx.x;
  const int b=g/(DIN*NSTATE), ds=g-b*(DIN*NSTATE);
  float h=0.f;
#pragma unroll 1
  for (int c=0;c<NCHUNK;++c){
    const size_t idx=((size_t)(b*NCHUNK+c))*(DIN*NSTATE)+ds;
    Hin[idx]=h;
    h=fmaf(P[idx],h,H[idx]);
  }
}

// ============================================================================

extern "C" void kernel_launch(void* const* d_in, const int* in_sizes, int n_in,
                              void* d_out, int out_size, void* d_ws, size_t ws_size,
                              hipStream_t stream) {
  const float* xg     = (const float*)d_in[0];
  const float* w_in   = (const float*)d_in[1];
  const float* w_conv = (const float*)d_in[2];
  const float* b_conv = (const float*)d_in[3];
  const float* w_xp   = (const float*)d_in[4];
  const float* w_dt   = (const float*)d_in[5];
  const float* b_dt   = (const float*)d_in[6];
  const float* A_log  = (const float*)d_in[7];
  const float* Dv     = (const float*)d_in[8];
  const float* w_out  = (const float*)d_in[9];
  const float* w_cls  = (const float*)d_in[10];
  const float* b_cls  = (const float*)d_in[11];
  float* outg = (float*)d_out;

  int P = 0;
  for (int p : {1,2,4,8}) if (ws_size >= tier_bytes(p)) { P = p; break; }

  if (P) {
    const int SEG = SEQ/P, tiles = SEG/T0;
    const size_t featF = (size_t)BATCH*SEG*FREC;
    const size_t phF   = (size_t)BATCH*tiles*1312;
    float* feat  = (float*)d_ws;
    float* Pg    = feat + featF;
    float* Hg    = Pg + phF;
    float* Hin   = Hg + phF;
    float* carry = Hin + phF;
    float* Mg    = carry + (size_t)BATCH*1312;
    k_pre<<<dim3(4),256,0,stream>>>(w_out, w_cls, Mg);
    for (int p=0;p<P;p++){
      const int off = p*SEG;
      k0_feat<<<dim3(tiles,BATCH),256,0,stream>>>(
          xg,w_in,w_conv,b_conv,w_xp,w_dt,b_dt,A_log,Dv,off,SEG,feat,Pg,Hg);
      k2_comb<<<dim3((BATCH*1312)/256),256,0,stream>>>(Pg,Hg,Hin,carry,tiles,p==0?1:0);
      k4_out<<<dim3(tiles,BATCH),256,0,stream>>>(
          xg,w_in,A_log,Mg,b_cls,off,SEG,feat,Hin,outg);
    }
  } else {
    float* Pg  = (float*)d_ws;
    float* Hg  = Pg + NPH_OLD;
    float* Hin = Hg + NPH_OLD;
    dim3 grid(BATCH*NCHUNK), blk(256);
    mamba_chunk<1><<<grid,blk,0,stream>>>(xg,w_in,w_conv,b_conv,w_xp,w_dt,b_dt,
                                          A_log,Dv,w_out,w_cls,b_cls,Pg,Hg,nullptr,nullptr);
    mamba_combine<<<dim3((BATCH*DIN*NSTATE)/256),blk,0,stream>>>(Pg,Hg,Hin);
    mamba_chunk<3><<<grid,blk,0,stream>>>(xg,w_in,w_conv,b_conv,w_xp,w_dt,b_dt,
                                          A_log,Dv,w_out,w_cls,b_cls,nullptr,nullptr,Hin,outg);
  }
}

// Round 6
// 643.156 us; speedup vs baseline: 1.2976x; 1.0207x over previous
//
#include <hip/hip_runtime.h>
#include <math.h>

// Mamba block, fp32, single-scan + closed-form seeding + fused epilogue.
// k_pre  : M = w_cls@w_out (10x82) into ws.
// k0_feat: features once + local scan -> per-pos (yloc, Dp, C) record staged in
//          LDS, then ONE batched float4 writeout per subtile (full-line writes,
//          no partial-dirty-line RMW). Weights in LDS.
// k2_comb: sequential combine over tiles -> Hin per tile (carry across phases).
// k4_out : z-proj (LDS weights), closed-form corr, gate, fused M-GEMM logits.
// R13: VERBATIM RESTORE of R7 (proven 644.4us, absmax 5.96e-8).
// Session evidence (R8-R12): this kernel sits exactly at the 64-VGPR cap of
// __launch_bounds__(256,4); EVERY phase reshaping attempted (reg-weights,
// (256,2), stride-84 vectorization, D-2col, E-fold, A-float2) spilled to
// scratch (FETCH 50->77..210MB) or halved residency, regressing k0 346->358..
// 501us. Non-k0 time is stable at ~298us across all variants. The envelope:
//  - (256,n): n = resident blocks AND VGPR cap ~256/n. (256,4) is mandatory
//    (4 blocks/CU); 64-VGPR cap leaves ZERO headroom over R7's liveness.
//  - k0/k4 are LDS-pipe/issue bound; occupancy is not the lever (R8: LDS
//    ceiling 4->6 blocks left occupancy at 43%). HBM at 13% is not the lever.
//  - weights MUST be in LDS (R7): global weights miss under feat streaming.
// OLD path (proven): fallback if ws too small.

namespace {
constexpr int DMODEL=41, DIN=82, NSTATE=16, NLAB=10, BATCH=32, SEQ=8192;
// old path
constexpr int CHUNK=512, NCHUNK=SEQ/CHUNK, TSUB=16, NSUB=CHUNK/TSUB, RWS=TSUB+3;
constexpr int XPAD=44, SPAD=83, CPAD=84, JPAD=36;
constexpr int NPH_OLD = BATCH*NCHUNK*DIN*NSTATE;
// new path
constexpr int T0 = 64;              // positions per k0/k4 tile
constexpr int FREC = 180;           // yloc@0(82) | Dp@82(82) | C@164(16)
inline size_t tier_bytes(int P){
  size_t SEG = (size_t)SEQ/P, tiles = SEG/T0;
  return ((size_t)BATCH*SEG*FREC + 3*((size_t)BATCH*tiles*1312)
          + (size_t)BATCH*1312 + 4096)*4;
}
}

__device__ __forceinline__ float siluf(float v)     { return v / (1.f + expf(-v)); }
__device__ __forceinline__ float softplusf(float v) { return (v > 20.f) ? v : log1pf(expf(v)); }
// fast variants (validated R4/R5: absmax unchanged at 5.96e-8)
__device__ __forceinline__ float silu_f(float v){
  return v * __builtin_amdgcn_rcpf(1.f + __expf(-v));
}
__device__ __forceinline__ float softplus_f(float v){
  return (v > 20.f) ? v : __logf(1.f + __expf(v));
}

// in_proj helper: NR rows from r0, col e(<82), weights in LDS [k*82+e],
// x stride 44, out stride 82
template<int NR>
__device__ __forceinline__ void inproj_rows(int r0, int e,
    const float* __restrict__ sx, const float* __restrict__ wt,
    float* __restrict__ sxs) {
  float acc[NR];
#pragma unroll
  for (int i=0;i<NR;i++) acc[i]=0.f;
#pragma unroll
  for (int kq=0;kq<40;kq+=4){
    const float w0=wt[(kq+0)*82+e], w1=wt[(kq+1)*82+e];
    const float w2=wt[(kq+2)*82+e], w3=wt[(kq+3)*82+e];
#pragma unroll
    for (int i=0;i<NR;i++){
      const float4 xv = *(const float4*)&sx[(r0+i)*44+kq];
      acc[i]=fmaf(xv.x,w0,acc[i]); acc[i]=fmaf(xv.y,w1,acc[i]);
      acc[i]=fmaf(xv.z,w2,acc[i]); acc[i]=fmaf(xv.w,w3,acc[i]);
    }
  }
  const float wl = wt[40*82+e];
#pragma unroll
  for (int i=0;i<NR;i++)
    sxs[(r0+i)*82+e] = fmaf(sx[(r0+i)*44+40], wl, acc[i]);
}

// ============================================================================
// NEW PATH
// ============================================================================

__global__ __launch_bounds__(256) void k_pre(
    const float* __restrict__ w_out, const float* __restrict__ w_cls,
    float* __restrict__ M){
  const int w = blockIdx.x*256 + threadIdx.x;
  if (w < NLAB*DIN){
    const int n = w/82, dd = w - n*82;
    float a = 0.f;
#pragma unroll
    for (int dm=0;dm<41;dm++) a = fmaf(w_cls[n*41+dm], w_out[dm*82+dd], a);
    M[w] = a;
  }
}

__launch_bounds__(256, 4)
__global__ void k0_feat(
    const float* __restrict__ xg, const float* __restrict__ w_in,
    const float* __restrict__ w_conv, const float* __restrict__ b_conv,
    const float* __restrict__ w_xproj, const float* __restrict__ w_dt,
    const float* __restrict__ b_dt, const float* __restrict__ A_log,
    const float* __restrict__ Dvec, int off, int SEG,
    float* __restrict__ feat, float* __restrict__ Pg, float* __restrict__ Hg)
{
  __shared__ float s_x[19*44];    // raw x rows (pos p0-3 .. p0+15)
  __shared__ float s_xs[19*82];   // xs rows incl conv halo
  __shared__ float s_xc[16*82];   // xc; scan overwrites with yloc
  __shared__ float s_q[16*82];    // delta; scan overwrites with Dp
  __shared__ float s_db[16*36];   // dt@0..2, B@4..19, C@20..35
  __shared__ float w_t[41*82];    // in_proj xs-half transposed [k][e] (LDS!)
  __shared__ float s_cw[4*82];    // conv w transposed [k][d]
  __shared__ float s_dtw[3*82];   // dt w transposed [k][d]
  __shared__ float s_cb[82], s_dtb[82], s_A0[82], s_Dv[82];
  __shared__ int   s_flag[82];
  // ~39.8 KB -> 4 blocks/CU

  const int tid = threadIdx.x;
  const int tile = blockIdx.x, b = blockIdx.y;
  const int base_pos = off + tile*T0;

  for (int i=tid;i<41*82;i+=256){ int k=i/82,e=i-k*82; w_t[i]=w_in[e*41+k]; }
  for (int i=tid;i<328;i+=256){ int dd=i/4,k=i-dd*4; s_cw[k*82+dd]=w_conv[i]; }
  for (int i=tid;i<246;i+=256){ int dd=i/3,k=i-dd*3; s_dtw[k*82+dd]=w_dt[i]; }
  if (tid<82){
    s_cb[tid]=b_conv[tid]; s_dtb[tid]=b_dt[tid]; s_Dv[tid]=Dvec[tid];
    float A0=-expf(A_log[tid*16]); s_A0[tid]=A0;
    bool ok=(A0<0.f);
#pragma unroll
    for (int s=1;s<16;s++){
      float As=-expf(A_log[tid*16+s]);
      ok = ok && (fabsf(As-(float)(s+1)*A0) <= 1e-3f*(float)(s+1)*fabsf(A0));
    }
    s_flag[tid]=ok?1:0;
  }
  __syncthreads();

  const int d = tid>>1, sg = tid&1;
  float h[8], As[8], A0d=-1.f, Dp=0.f;
  int flag=1;
  if (tid<164){
    flag = s_flag[d]; A0d = s_A0[d];
    if (!flag){
#pragma unroll
      for (int i=0;i<8;i++) As[i]=-expf(A_log[d*16+sg*8+i]);
    }
#pragma unroll
    for (int i=0;i<8;i++) h[i]=0.f;
  }

  for (int it=0; it<T0/16; ++it){
    const int p0 = base_pos + it*16;
    // ---- A: halo shift + raw x load ----
    if (it>0){
      for (int i=tid;i<246;i+=256){ int r=i/82, dd=i-r*82; s_xs[r*82+dd]=s_xs[(16+r)*82+dd]; }
    }
    {
      const int rlo=(it==0)?0:3, cnt=(19-rlo)*41;
      for (int i=tid;i<cnt;i+=256){
        int r=rlo+i/41, k=i-(i/41)*41;
        int pos=p0-3+r;
        s_x[r*44+k] = (pos>=0) ? xg[((size_t)b*SEQ+(size_t)pos)*41+k] : 0.f;
      }
    }
    __syncthreads();
    // ---- B: in_proj (xs half), 2 threads/column, weights in LDS ----
    if (tid<164){
      const int e=(tid<82)?tid:tid-82, rh=(tid>=82);
      if (it==0){ if(!rh) inproj_rows<10>(0,e,s_x,w_t,s_xs); else inproj_rows<9>(10,e,s_x,w_t,s_xs); }
      else      { inproj_rows<8>(rh?11:3,e,s_x,w_t,s_xs); }
    }
    __syncthreads();
    // ---- C: conv + silu -> s_xc ----
    for (int w=tid;w<1312;w+=256){
      const int l=w&15, dd=w>>4;
      float a=s_cb[dd];
#pragma unroll
      for (int k=0;k<4;k++) a=fmaf(s_xs[(l+k)*82+dd], s_cw[k*82+dd], a);
      s_xc[l*82+dd]=silu_f(a);
    }
    __syncthreads();
    // ---- D: x_proj (35 rows) -> dt/B/C in s_db only ----
    for (int w=tid;w<560;w+=256){
      const int l=w&15, j=w>>4;
      const float2* wp=(const float2*)(w_xproj + j*82);
      const float2* gp=(const float2*)&s_xc[l*82];
      float a=0.f;
#pragma unroll
      for (int dq=0;dq<41;dq++){
        const float2 wv=wp[dq], gv=gp[dq];
        a=fmaf(wv.x,gv.x,a); a=fmaf(wv.y,gv.y,a);
      }
      const int col=(j<3)?j:j+1;
      s_db[l*36+col]=a;
    }
    __syncthreads();
    // ---- D2: dt_proj + softplus -> delta ----
    for (int w=tid;w<1312;w+=256){
      const int l=w&15, dd=w>>4;
      float a=s_dtb[dd];
      a=fmaf(s_db[l*36+0],s_dtw[0*82+dd],a);
      a=fmaf(s_db[l*36+1],s_dtw[1*82+dd],a);
      a=fmaf(s_db[l*36+2],s_dtw[2*82+dd],a);
      s_q[l*82+dd]=softplus_f(a);
    }
    __syncthreads();
    // ---- E: local scan; stage yloc into s_xc, Dp into s_q (in place) ----
    if (tid<164){
#pragma unroll 1
      for (int l=0;l<16;l++){
        const float dl  = s_q[l*82+d];
        const float xc  = s_xc[l*82+d];
        const float dxc = dl*xc;
        Dp += dl;
        const float4 B0=*(const float4*)&s_db[l*36+4+sg*8];
        const float4 B1=*(const float4*)&s_db[l*36+8+sg*8];
        const float4 C0=*(const float4*)&s_db[l*36+20+sg*8];
        const float4 C1=*(const float4*)&s_db[l*36+24+sg*8];
        const float Bv[8]={B0.x,B0.y,B0.z,B0.w,B1.x,B1.y,B1.z,B1.w};
        const float Cv[8]={C0.x,C0.y,C0.z,C0.w,C1.x,C1.y,C1.z,C1.w};
        float y=0.f;
        if (flag){
          const float q=__expf(dl*A0d);
          const float q2=q*q, q4=q2*q2;
          float e = sg ? q4*q4*q : q;
#pragma unroll
          for (int s=0;s<8;s++){
            h[s]=fmaf(e,h[s],dxc*Bv[s]);
            y=fmaf(h[s],Cv[s],y);
            if(s<7) e*=q;
          }
        } else {
#pragma unroll
          for (int s=0;s<8;s++){
            const float e=__expf(dl*As[s]);
            h[s]=fmaf(e,h[s],dxc*Bv[s]);
            y=fmaf(h[s],Cv[s],y);
          }
        }
        y += __shfl_down(y,1);
        if (sg==0){
          // pair lanes are lockstep: both read xc/dl above before these writes
          s_xc[l*82+d] = y + xc*s_Dv[d];   // yloc
          s_q [l*82+d] = Dp;               // prefix-sum of delta
        }
      }
    }
    __syncthreads();
    // ---- F: batched record writeout (720 float4 = 16 recs x 180 floats) ----
    {
      float* fb = feat + ((size_t)b*SEG + (size_t)(tile*T0+it*16))*FREC;
      for (int i=tid;i<720;i+=256){
        const int l=i/45, q=i-l*45;
        const int f=4*q;
        float4 v;
        if (q<20){
          v.x=s_xc[l*82+f+0]; v.y=s_xc[l*82+f+1];
          v.z=s_xc[l*82+f+2]; v.w=s_xc[l*82+f+3];
        } else if (q==20){
          v.x=s_xc[l*82+80]; v.y=s_xc[l*82+81];
          v.z=s_q[l*82+0];   v.w=s_q[l*82+1];
        } else if (q<=40){
          v.x=s_q[l*82+f-82]; v.y=s_q[l*82+f-81];
          v.z=s_q[l*82+f-80]; v.w=s_q[l*82+f-79];
        } else {
          const int c=f-164;
          v.x=s_db[l*36+20+c+0]; v.y=s_db[l*36+20+c+1];
          v.z=s_db[l*36+20+c+2]; v.w=s_db[l*36+20+c+3];
        }
        *(float4*)&fb[(size_t)l*FREC + f] = v;
      }
    }
    // no trailing barrier: next C/D2 writes to s_xc/s_q are 2+ barriers away
  }

  if (tid<164){
    float Pv[8];
    if (flag){
      const float Qt=__expf(Dp*A0d);
      const float Q2=Qt*Qt, Q4=Q2*Q2, Q8=Q4*Q4;
      float c = sg ? Q8*Qt : Qt;
#pragma unroll
      for (int i=0;i<8;i++){ Pv[i]=c; c*=Qt; }
    } else {
#pragma unroll
      for (int i=0;i<8;i++) Pv[i]=__expf(Dp*As[i]);
    }
    const size_t base = ((size_t)(b*gridDim.x+tile))*1312 + (size_t)d*16 + sg*8;
    *(float4*)&Pg[base]   = make_float4(Pv[0],Pv[1],Pv[2],Pv[3]);
    *(float4*)&Pg[base+4] = make_float4(Pv[4],Pv[5],Pv[6],Pv[7]);
    *(float4*)&Hg[base]   = make_float4(h[0],h[1],h[2],h[3]);
    *(float4*)&Hg[base+4] = make_float4(h[4],h[5],h[6],h[7]);
  }
}

__global__ __launch_bounds__(256) void k2_comb(
    const float* __restrict__ Pg, const float* __restrict__ Hg,
    float* __restrict__ Hin, float* __restrict__ carry, int TPP, int first)
{
  const int g = blockIdx.x*256 + threadIdx.x;   // < 32*1312
  const int b = g/1312, r = g - b*1312;
  float h = first ? 0.f : carry[g];
#pragma unroll 4
  for (int t=0;t<TPP;t++){
    const size_t idx = ((size_t)(b*TPP+t))*1312 + r;
    Hin[idx]=h;
    h = fmaf(Pg[idx], h, Hg[idx]);
  }
  carry[g]=h;
}

__launch_bounds__(256, 4)
__global__ void k4_out(
    const float* __restrict__ xg, const float* __restrict__ w_in,
    const float* __restrict__ A_log, const float* __restrict__ Mg,
    const float* __restrict__ b_cls, int off, int SEG,
    const float* __restrict__ feat, const float* __restrict__ Hin,
    float* __restrict__ outg)
{
  __shared__ float s_x[16*44];    // raw x rows
  __shared__ float w_zt[41*82];   // in_proj z-half transposed [k][e] (LDS!)
  __shared__ float s_z[16*82];    // silu(z)
  __shared__ float s_g[16*82];    // gated value
  __shared__ float s_c[16*16];    // C rows
  __shared__ float s_hin[1312];   // s-major [s*82+d]
  __shared__ float s_M[10*82];    // fused Wc*Wo
  __shared__ float s_A0[82], s_bc[10];
  __shared__ int   s_flag[82];
  // ~37.1 KB -> 4 blocks/CU

  const int tid = threadIdx.x;
  const int tile = blockIdx.x, b = blockIdx.y;

  for (int i=tid;i<41*82;i+=256){ int k=i/82,e=i-k*82; w_zt[i]=w_in[(82+e)*41+k]; }
  for (int i=tid;i<1312;i+=256){
    const int dd=i>>4, s=i&15;
    s_hin[s*82+dd] = Hin[((size_t)(b*gridDim.x+tile))*1312 + i];
  }
  for (int i=tid;i<820;i+=256) s_M[i]=Mg[i];
  if (tid<10) s_bc[tid]=b_cls[tid];
  if (tid<82){
    float A0=-expf(A_log[tid*16]); s_A0[tid]=A0;
    bool ok=(A0<0.f);
#pragma unroll
    for (int s=1;s<16;s++){
      float As=-expf(A_log[tid*16+s]);
      ok = ok && (fabsf(As-(float)(s+1)*A0) <= 1e-3f*(float)(s+1)*fabsf(A0));
    }
    s_flag[tid]=ok?1:0;
  }
  // hoisted (l,d) decomposition for the 1312-item stage
  int lk[6], dk[6];
#pragma unroll
  for (int k=0;k<6;k++){ const int w=tid+256*k; lk[k]=w/82; dk[k]=w-lk[k]*82; }

  for (int it=0; it<T0/16; ++it){
    const int lp0 = tile*T0 + it*16;
    const int gp0 = off + lp0;
    __syncthreads();
    // ---- A: load raw x + C rows ----
    for (int i=tid;i<656;i+=256){
      const int r=i/41, k=i-r*41;
      s_x[r*44+k] = xg[((size_t)b*SEQ+(size_t)(gp0+r))*41+k];
    }
    for (int i=tid;i<64;i+=256){
      const int l=i>>2, q=i&3;
      ((float4*)&s_c[l*16])[q] =
          ((const float4*)(feat + ((size_t)b*SEG+(size_t)(lp0+l))*FREC + 164))[q];
    }
    __syncthreads();
    // ---- B: z-proj (LDS weights), 2 threads/column, 8 rows -> silu ----
    if (tid<164){
      const int e=(tid<82)?tid:tid-82, l0=(tid>=82)?8:0;
      float acc[8];
#pragma unroll
      for (int i=0;i<8;i++) acc[i]=0.f;
#pragma unroll
      for (int kq=0;kq<40;kq+=4){
        const float w0=w_zt[(kq+0)*82+e], w1=w_zt[(kq+1)*82+e];
        const float w2=w_zt[(kq+2)*82+e], w3=w_zt[(kq+3)*82+e];
#pragma unroll
        for (int i=0;i<8;i++){
          const float4 xv=*(const float4*)&s_x[(l0+i)*44+kq];
          acc[i]=fmaf(xv.x,w0,acc[i]); acc[i]=fmaf(xv.y,w1,acc[i]);
          acc[i]=fmaf(xv.z,w2,acc[i]); acc[i]=fmaf(xv.w,w3,acc[i]);
        }
      }
      const float wl=w_zt[40*82+e];
#pragma unroll
      for (int i=0;i<8;i++)
        s_z[(l0+i)*82+e] = silu_f(fmaf(s_x[(l0+i)*44+40], wl, acc[i]));
    }
    __syncthreads();
    // ---- C: closed-form correction + gate ----
#pragma unroll
    for (int k=0;k<6;k++){
      const int w=tid+256*k;
      if (w>=1312) break;
      const int l=lk[k], dd=dk[k];
      const float* fp = feat + ((size_t)b*SEG+(size_t)(lp0+l))*FREC;
      const float yl = fp[dd];
      const float Dp = fp[82+dd];
      float acc=yl;
      if (s_flag[dd]){
        const float Qt=__expf(s_A0[dd]*Dp);
        float e=Qt;
#pragma unroll
        for (int s=0;s<16;s++){
          acc = fmaf(s_c[l*16+s]*e, s_hin[s*82+dd], acc);
          if (s<15) e*=Qt;
        }
      } else {
#pragma unroll
        for (int s=0;s<16;s++){
          const float As = -__expf(A_log[dd*16+s]);
          acc = fmaf(s_c[l*16+s]*__expf(As*Dp), s_hin[s*82+dd], acc);
        }
      }
      s_g[l*82+dd] = acc * s_z[l*82+dd];
    }
    __syncthreads();
    // ---- D: fused logits = M*g + b, contiguous store ----
    if (tid<160){
      const int l=tid/10, n=tid-(tid/10)*10;
      float a=s_bc[n];
      const float2* gp=(const float2*)&s_g[l*82];
      const float2* mp=(const float2*)&s_M[n*82];
#pragma unroll
      for (int q=0;q<41;q++){
        const float2 gv=gp[q], mv=mp[q];
        a=fmaf(gv.x,mv.x,a); a=fmaf(gv.y,mv.y,a);
      }
      outg[((size_t)b*SEQ+(size_t)gp0)*10 + tid] = a;
    }
    // no trailing barrier: top-of-loop sync protects s_x/s_c overwrite
  }
}

// ============================================================================
// OLD PATH (proven fallback)
// ============================================================================

template <int PASS>
__launch_bounds__(256, 2)
__global__ void mamba_chunk(
    const float* __restrict__ xg, const float* __restrict__ w_in,
    const float* __restrict__ w_conv, const float* __restrict__ b_conv,
    const float* __restrict__ w_xproj, const float* __restrict__ w_dt,
    const float* __restrict__ b_dt, const float* __restrict__ A_log,
    const float* __restrict__ Dvec, const float* __restrict__ w_out,
    const float* __restrict__ w_cls, const float* __restrict__ b_cls,
    float* __restrict__ Pg, float* __restrict__ Hg,
    const float* __restrict__ Hin, float* __restrict__ outg)
{
  __shared__ float s_x[RWS*XPAD];
  __shared__ float s_xs[RWS*SPAD];
  __shared__ float s_xc[TSUB*CPAD];
  __shared__ float s_z[TSUB*SPAD];
  __shared__ float s_xdbc[TSUB*JPAD];
  __shared__ float w_in_t[DMODEL*164];
  __shared__ float w_xp_t[DIN*35];
  __shared__ float s_cw[DIN*4];
  __shared__ float s_cb[DIN];
  __shared__ float s_dtw[DIN*3];
  __shared__ float s_dtb[DIN];

  const int tid=threadIdx.x;
  const int b=blockIdx.x/NCHUNK, c=blockIdx.x%NCHUNK, l0c=c*CHUNK;
  constexpr int NJ=(PASS==3)?35:19;
  constexpr int NE=(PASS==3)?164:DIN;

  for (int i=tid;i<DMODEL*164;i+=256){ int k=i/164,e=i-k*164; w_in_t[i]=w_in[e*DMODEL+k]; }
  for (int i=tid;i<DIN*35;i+=256){ int dd=i/35,j=i-dd*35; w_xp_t[i]=w_xproj[j*DIN+dd]; }
  for (int i=tid;i<DIN*4;i+=256) s_cw[i]=w_conv[i];
  for (int i=tid;i<DIN*3;i+=256) s_dtw[i]=w_dt[i];
  if (tid<DIN){ s_cb[tid]=b_conv[tid]; s_dtb[tid]=b_dt[tid]; }

  float h[NSTATE], Pp[NSTATE], As[NSTATE];
  float A0=-1.f, Dd=0.f;
  bool structured=true;
  if (tid<DIN){
#pragma unroll
    for (int s=0;s<NSTATE;++s) As[s]=-expf(A_log[tid*NSTATE+s]);
    A0=As[0];
#pragma unroll
    for (int s=0;s<NSTATE;++s)
      structured = structured && (fabsf(As[s]-(float)(s+1)*A0)<=1e-3f*(float)(s+1)*fabsf(A0));
    structured = structured && (A0<0.f);
    if (PASS==3){
      Dd=Dvec[tid];
      size_t base=((size_t)(b*NCHUNK+c))*(DIN*NSTATE)+(size_t)tid*NSTATE;
#pragma unroll
      for (int s=0;s<NSTATE;++s) h[s]=Hin[base+s];
    } else {
#pragma unroll
      for (int s=0;s<NSTATE;++s){ h[s]=0.f; Pp[s]=1.f; }
    }
  }
  __syncthreads();

  for (int t=0;t<NSUB;++t){
    const int p0=l0c+t*TSUB;
    for (int i=tid;i<RWS*DMODEL;i+=256){
      int r=i/DMODEL,k=i-r*DMODEL;
      int pos=p0-3+r;
      s_x[r*XPAD+k]=(pos>=0)?xg[(size_t)b*SEQ*DMODEL+(size_t)pos*DMODEL+k]:0.f;
    }
    __syncthreads();
    {
      const int e=tid;
      if (e<NE){
        float acc[RWS];
#pragma unroll
        for (int r=0;r<RWS;++r) acc[r]=0.f;
#pragma unroll
        for (int kq=0;kq<40;kq+=4){
          const float w0=w_in_t[(kq+0)*164+e], w1=w_in_t[(kq+1)*164+e];
          const float w2=w_in_t[(kq+2)*164+e], w3=w_in_t[(kq+3)*164+e];
#pragma unroll
          for (int r=0;r<RWS;++r){
            const float4 xv=*(const float4*)&s_x[r*XPAD+kq];
            acc[r]=fmaf(xv.x,w0,acc[r]); acc[r]=fmaf(xv.y,w1,acc[r]);
            acc[r]=fmaf(xv.z,w2,acc[r]); acc[r]=fmaf(xv.w,w3,acc[r]);
          }
        }
        const float wl=w_in_t[40*164+e];
#pragma unroll
        for (int r=0;r<RWS;++r) acc[r]=fmaf(s_x[r*XPAD+40],wl,acc[r]);
        if (e<DIN){
#pragma unroll
          for (int r=0;r<RWS;++r) s_xs[r*SPAD+e]=acc[r];
        } else {
#pragma unroll
          for (int r=3;r<RWS;++r) s_z[(r-3)*SPAD+(e-DIN)]=acc[r];
        }
      }
    }
    __syncthreads();
    for (int w=tid;w<TSUB*DIN;w+=256){
      const int l=w&15,e=w>>4;
      float a=s_cb[e];
#pragma unroll
      for (int k=0;k<4;++k) a=fmaf(s_xs[(l+k)*SPAD+e],s_cw[e*4+k],a);
      s_xc[l*CPAD+e]=siluf(a);
    }
    __syncthreads();
    for (int w=tid;w<TSUB*NJ;w+=256){
      const int l=w&15,j=w>>4;
      float a=0.f;
#pragma unroll
      for (int dq=0;dq<80;dq+=4){
        const float4 xv=*(const float4*)&s_xc[l*CPAD+dq];
        a=fmaf(xv.x,w_xp_t[(dq+0)*35+j],a); a=fmaf(xv.y,w_xp_t[(dq+1)*35+j],a);
        a=fmaf(xv.z,w_xp_t[(dq+2)*35+j],a); a=fmaf(xv.w,w_xp_t[(dq+3)*35+j],a);
      }
      a=fmaf(s_xc[l*CPAD+80],w_xp_t[80*35+j],a);
      a=fmaf(s_xc[l*CPAD+81],w_xp_t[81*35+j],a);
      const int col=(j<3)?j:j+1;
      s_xdbc[l*JPAD+col]=a;
    }
    __syncthreads();
    for (int w=tid;w<TSUB*DIN;w+=256){
      const int l=w&15,dd=w>>4;
      float a=s_dtb[dd];
      a=fmaf(s_xdbc[l*JPAD+0],s_dtw[dd*3+0],a);
      a=fmaf(s_xdbc[l*JPAD+1],s_dtw[dd*3+1],a);
      a=fmaf(s_xdbc[l*JPAD+2],s_dtw[dd*3+2],a);
      s_xs[l*SPAD+dd]=softplusf(a);
    }
    __syncthreads();
    if (tid<DIN){
      const int dd=tid;
#pragma unroll 1
      for (int l=0;l<TSUB;++l){
        const float dl=s_xs[l*SPAD+dd];
        const float xcd=s_xc[l*CPAD+dd];
        const float dxc=dl*xcd;
        const float4 B0=*(const float4*)&s_xdbc[l*JPAD+4];
        const float4 B1=*(const float4*)&s_xdbc[l*JPAD+8];
        const float4 B2=*(const float4*)&s_xdbc[l*JPAD+12];
        const float4 B3=*(const float4*)&s_xdbc[l*JPAD+16];
        const float Bv[NSTATE]={B0.x,B0.y,B0.z,B0.w,B1.x,B1.y,B1.z,B1.w,
                                B2.x,B2.y,B2.z,B2.w,B3.x,B3.y,B3.z,B3.w};
        float Cv[NSTATE];
        if (PASS==3){
          const float4 C0=*(const float4*)&s_xdbc[l*JPAD+20];
          const float4 C1=*(const float4*)&s_xdbc[l*JPAD+24];
          const float4 C2=*(const float4*)&s_xdbc[l*JPAD+28];
          const float4 C3=*(const float4*)&s_xdbc[l*JPAD+32];
          Cv[0]=C0.x;Cv[1]=C0.y;Cv[2]=C0.z;Cv[3]=C0.w;
          Cv[4]=C1.x;Cv[5]=C1.y;Cv[6]=C1.z;Cv[7]=C1.w;
          Cv[8]=C2.x;Cv[9]=C2.y;Cv[10]=C2.z;Cv[11]=C2.w;
          Cv[12]=C3.x;Cv[13]=C3.y;Cv[14]=C3.z;Cv[15]=C3.w;
        }
        float y=(PASS==3)?Dd*xcd:0.f;
        if (structured){
          const float q=expf(dl*A0);
          float e=q;
#pragma unroll
          for (int s=0;s<NSTATE;++s){
            h[s]=fmaf(e,h[s],dxc*Bv[s]);
            if (PASS==1) Pp[s]*=e; else y=fmaf(h[s],Cv[s],y);
            if (s<NSTATE-1) e*=q;
          }
        } else {
#pragma unroll
          for (int s=0;s<NSTATE;++s){
            const float e=expf(dl*As[s]);
            h[s]=fmaf(e,h[s],dxc*Bv[s]);
            if (PASS==1) Pp[s]*=e; else y=fmaf(h[s],Cv[s],y);
          }
        }
        if (PASS==3) s_xs[l*SPAD+dd]=y;
      }
    }
    __syncthreads();
    if (PASS==3){
      for (int w=tid;w<TSUB*DIN;w+=256){
        const int l=w&15,dd=w>>4;
        s_xc[l*CPAD+dd]=s_xs[l*SPAD+dd]*siluf(s_z[l*SPAD+dd]);
      }
      __syncthreads();
      for (int w=tid;w<TSUB*DMODEL;w+=256){
        const int l=w&15,dm=w>>4;
        const float2* wp=(const float2*)(w_out+dm*DIN);
        const float2* gp=(const float2*)&s_xc[l*CPAD];
        float a=0.f;
#pragma unroll
        for (int dq=0;dq<41;++dq){
          const float2 wv=wp[dq], gv=gp[dq];
          a=fmaf(wv.x,gv.x,a); a=fmaf(wv.y,gv.y,a);
        }
        s_x[l*XPAD+dm]=a;
      }
      __syncthreads();
      for (int w=tid;w<TSUB*NLAB;w+=256){
        const int l=w&15,n=w>>4;
        float a=b_cls[n];
#pragma unroll
        for (int dm=0;dm<DMODEL;++dm) a=fmaf(w_cls[n*DMODEL+dm],s_x[l*XPAD+dm],a);
        s_xdbc[l*NLAB+n]=a;
      }
      __syncthreads();
      for (int i=tid;i<TSUB*NLAB;i+=256)
        outg[((size_t)(b*SEQ+p0))*NLAB+i]=s_xdbc[i];
      __syncthreads();
    }
  }

  if (PASS==1 && tid<DIN){
    size_t base=((size_t)(b*NCHUNK+c))*(DIN*NSTATE)+(size_t)tid*NSTATE;
#pragma unroll
    for (int s=0;s<NSTATE;++s){ Pg[base+s]=Pp[s]; Hg[base+s]=h[s]; }
  }
}

__global__ __launch_bounds__(256) void mamba_combine(
    const float* __restrict__ P, const float* __restrict__ H, float* __restrict__ Hin){
  const int g=blockIdx.x*256+threadIdx.x;
  const int b=g/(DIN*NSTATE), ds=g-b*(DIN*NSTATE);
  float h=0.f;
#pragma unroll 1
  for (int c=0;c<NCHUNK;++c){
    const size_t idx=((size_t)(b*NCHUNK+c))*(DIN*NSTATE)+ds;
    Hin[idx]=h;
    h=fmaf(P[idx],h,H[idx]);
  }
}

// ============================================================================

extern "C" void kernel_launch(void* const* d_in, const int* in_sizes, int n_in,
                              void* d_out, int out_size, void* d_ws, size_t ws_size,
                              hipStream_t stream) {
  const float* xg     = (const float*)d_in[0];
  const float* w_in   = (const float*)d_in[1];
  const float* w_conv = (const float*)d_in[2];
  const float* b_conv = (const float*)d_in[3];
  const float* w_xp   = (const float*)d_in[4];
  const float* w_dt   = (const float*)d_in[5];
  const float* b_dt   = (const float*)d_in[6];
  const float* A_log  = (const float*)d_in[7];
  const float* Dv     = (const float*)d_in[8];
  const float* w_out  = (const float*)d_in[9];
  const float* w_cls  = (const float*)d_in[10];
  const float* b_cls  = (const float*)d_in[11];
  float* outg = (float*)d_out;

  int P = 0;
  for (int p : {1,2,4,8}) if (ws_size >= tier_bytes(p)) { P = p; break; }

  if (P) {
    const int SEG = SEQ/P, tiles = SEG/T0;
    const size_t featF = (size_t)BATCH*SEG*FREC;
    const size_t phF   = (size_t)BATCH*tiles*1312;
    float* feat  = (float*)d_ws;
    float* Pg    = feat + featF;
    float* Hg    = Pg + phF;
    float* Hin   = Hg + phF;
    float* carry = Hin + phF;
    float* Mg    = carry + (size_t)BATCH*1312;
    k_pre<<<dim3(4),256,0,stream>>>(w_out, w_cls, Mg);
    for (int p=0;p<P;p++){
      const int off = p*SEG;
      k0_feat<<<dim3(tiles,BATCH),256,0,stream>>>(
          xg,w_in,w_conv,b_conv,w_xp,w_dt,b_dt,A_log,Dv,off,SEG,feat,Pg,Hg);
      k2_comb<<<dim3((BATCH*1312)/256),256,0,stream>>>(Pg,Hg,Hin,carry,tiles,p==0?1:0);
      k4_out<<<dim3(tiles,BATCH),256,0,stream>>>(
          xg,w_in,A_log,Mg,b_cls,off,SEG,feat,Hin,outg);
    }
  } else {
    float* Pg  = (float*)d_ws;
    float* Hg  = Pg + NPH_OLD;
    float* Hin = Hg + NPH_OLD;
    dim3 grid(BATCH*NCHUNK), blk(256);
    mamba_chunk<1><<<grid,blk,0,stream>>>(xg,w_in,w_conv,b_conv,w_xp,w_dt,b_dt,
                                          A_log,Dv,w_out,w_cls,b_cls,Pg,Hg,nullptr,nullptr);
    mamba_combine<<<dim3((BATCH*DIN*NSTATE)/256),blk,0,stream>>>(Pg,Hg,Hin);
    mamba_chunk<3><<<grid,blk,0,stream>>>(xg,w_in,w_conv,b_conv,w_xp,w_dt,b_dt,
                                          A_log,Dv,w_out,w_cls,b_cls,nullptr,nullptr,Hin,outg);
  }
}

// Round 7
// 585.451 us; speedup vs baseline: 1.4255x; 1.0986x over previous
//
#include <hip/hip_runtime.h>
#include <math.h>

// Mamba block, fp32, single-scan + closed-form seeding + fused epilogue.
// k_pre  : M = w_cls@w_out (10x82) into ws.
// k0_feat: features once + local scan -> per-pos (yloc, Dp, C) record staged in
//          LDS, then ONE batched float4 writeout per subtile (full-line writes,
//          no partial-dirty-line RMW). Weights in LDS.
// k2_comb: sequential combine over tiles -> Hin per tile (carry across phases).
// k4_out : z-proj (LDS weights), closed-form corr, gate, fused M-GEMM logits.
// R14: R13 (=R7, proven 643.2us) with ONE change: T0 64 -> 128.
//   Register/LDS/phase-body neutral (only outer trip count + grid dims):
//   halves per-block weight-staging prologue share in k0/k4, halves k2 length.
//   Numerics: A structured (A=-(s+1)); Dp~90 over 128 pos -> exp underflow
//   to 0 is the mathematically-correct vanishing contribution (no NaN path).
// HARD-WON CONSTRAINTS (R8-R12 post-mortems):
//  - (256,n): n = resident blocks AND VGPR cap ~256/n. (256,4) mandatory;
//    64-VGPR cap leaves ZERO headroom: EVERY phase-body reshaping attempted
//    (reg-weights, (256,2), stride-84 vec, D-2col, E-fold, A-float2) spilled
//    (FETCH 50->77..210MB) or halved residency. Phase bodies are FROZEN.
//  - k0/k4 are LDS-pipe/issue bound; occupancy not the lever (R8); HBM 13%
//    not the lever. Broadcast LDS reads ~free (R11 k4-C neutral).
//  - weights MUST be in LDS (R7): global weights miss under feat streaming.
// OLD path (proven): fallback if ws too small.

namespace {
constexpr int DMODEL=41, DIN=82, NSTATE=16, NLAB=10, BATCH=32, SEQ=8192;
// old path
constexpr int CHUNK=512, NCHUNK=SEQ/CHUNK, TSUB=16, NSUB=CHUNK/TSUB, RWS=TSUB+3;
constexpr int XPAD=44, SPAD=83, CPAD=84, JPAD=36;
constexpr int NPH_OLD = BATCH*NCHUNK*DIN*NSTATE;
// new path
constexpr int T0 = 128;             // positions per k0/k4 tile (R14: 64->128)
constexpr int FREC = 180;           // yloc@0(82) | Dp@82(82) | C@164(16)
inline size_t tier_bytes(int P){
  size_t SEG = (size_t)SEQ/P, tiles = SEG/T0;
  return ((size_t)BATCH*SEG*FREC + 3*((size_t)BATCH*tiles*1312)
          + (size_t)BATCH*1312 + 4096)*4;
}
}

__device__ __forceinline__ float siluf(float v)     { return v / (1.f + expf(-v)); }
__device__ __forceinline__ float softplusf(float v) { return (v > 20.f) ? v : log1pf(expf(v)); }
// fast variants (validated R4/R5: absmax unchanged at 5.96e-8)
__device__ __forceinline__ float silu_f(float v){
  return v * __builtin_amdgcn_rcpf(1.f + __expf(-v));
}
__device__ __forceinline__ float softplus_f(float v){
  return (v > 20.f) ? v : __logf(1.f + __expf(v));
}

// in_proj helper: NR rows from r0, col e(<82), weights in LDS [k*82+e],
// x stride 44, out stride 82
template<int NR>
__device__ __forceinline__ void inproj_rows(int r0, int e,
    const float* __restrict__ sx, const float* __restrict__ wt,
    float* __restrict__ sxs) {
  float acc[NR];
#pragma unroll
  for (int i=0;i<NR;i++) acc[i]=0.f;
#pragma unroll
  for (int kq=0;kq<40;kq+=4){
    const float w0=wt[(kq+0)*82+e], w1=wt[(kq+1)*82+e];
    const float w2=wt[(kq+2)*82+e], w3=wt[(kq+3)*82+e];
#pragma unroll
    for (int i=0;i<NR;i++){
      const float4 xv = *(const float4*)&sx[(r0+i)*44+kq];
      acc[i]=fmaf(xv.x,w0,acc[i]); acc[i]=fmaf(xv.y,w1,acc[i]);
      acc[i]=fmaf(xv.z,w2,acc[i]); acc[i]=fmaf(xv.w,w3,acc[i]);
    }
  }
  const float wl = wt[40*82+e];
#pragma unroll
  for (int i=0;i<NR;i++)
    sxs[(r0+i)*82+e] = fmaf(sx[(r0+i)*44+40], wl, acc[i]);
}

// ============================================================================
// NEW PATH
// ============================================================================

__global__ __launch_bounds__(256) void k_pre(
    const float* __restrict__ w_out, const float* __restrict__ w_cls,
    float* __restrict__ M){
  const int w = blockIdx.x*256 + threadIdx.x;
  if (w < NLAB*DIN){
    const int n = w/82, dd = w - n*82;
    float a = 0.f;
#pragma unroll
    for (int dm=0;dm<41;dm++) a = fmaf(w_cls[n*41+dm], w_out[dm*82+dd], a);
    M[w] = a;
  }
}

__launch_bounds__(256, 4)
__global__ void k0_feat(
    const float* __restrict__ xg, const float* __restrict__ w_in,
    const float* __restrict__ w_conv, const float* __restrict__ b_conv,
    const float* __restrict__ w_xproj, const float* __restrict__ w_dt,
    const float* __restrict__ b_dt, const float* __restrict__ A_log,
    const float* __restrict__ Dvec, int off, int SEG,
    float* __restrict__ feat, float* __restrict__ Pg, float* __restrict__ Hg)
{
  __shared__ float s_x[19*44];    // raw x rows (pos p0-3 .. p0+15)
  __shared__ float s_xs[19*82];   // xs rows incl conv halo
  __shared__ float s_xc[16*82];   // xc; scan overwrites with yloc
  __shared__ float s_q[16*82];    // delta; scan overwrites with Dp
  __shared__ float s_db[16*36];   // dt@0..2, B@4..19, C@20..35
  __shared__ float w_t[41*82];    // in_proj xs-half transposed [k][e] (LDS!)
  __shared__ float s_cw[4*82];    // conv w transposed [k][d]
  __shared__ float s_dtw[3*82];   // dt w transposed [k][d]
  __shared__ float s_cb[82], s_dtb[82], s_A0[82], s_Dv[82];
  __shared__ int   s_flag[82];
  // ~39.8 KB -> 4 blocks/CU

  const int tid = threadIdx.x;
  const int tile = blockIdx.x, b = blockIdx.y;
  const int base_pos = off + tile*T0;

  for (int i=tid;i<41*82;i+=256){ int k=i/82,e=i-k*82; w_t[i]=w_in[e*41+k]; }
  for (int i=tid;i<328;i+=256){ int dd=i/4,k=i-dd*4; s_cw[k*82+dd]=w_conv[i]; }
  for (int i=tid;i<246;i+=256){ int dd=i/3,k=i-dd*3; s_dtw[k*82+dd]=w_dt[i]; }
  if (tid<82){
    s_cb[tid]=b_conv[tid]; s_dtb[tid]=b_dt[tid]; s_Dv[tid]=Dvec[tid];
    float A0=-expf(A_log[tid*16]); s_A0[tid]=A0;
    bool ok=(A0<0.f);
#pragma unroll
    for (int s=1;s<16;s++){
      float As=-expf(A_log[tid*16+s]);
      ok = ok && (fabsf(As-(float)(s+1)*A0) <= 1e-3f*(float)(s+1)*fabsf(A0));
    }
    s_flag[tid]=ok?1:0;
  }
  __syncthreads();

  const int d = tid>>1, sg = tid&1;
  float h[8], As[8], A0d=-1.f, Dp=0.f;
  int flag=1;
  if (tid<164){
    flag = s_flag[d]; A0d = s_A0[d];
    if (!flag){
#pragma unroll
      for (int i=0;i<8;i++) As[i]=-expf(A_log[d*16+sg*8+i]);
    }
#pragma unroll
    for (int i=0;i<8;i++) h[i]=0.f;
  }

  for (int it=0; it<T0/16; ++it){
    const int p0 = base_pos + it*16;
    // ---- A: halo shift + raw x load ----
    if (it>0){
      for (int i=tid;i<246;i+=256){ int r=i/82, dd=i-r*82; s_xs[r*82+dd]=s_xs[(16+r)*82+dd]; }
    }
    {
      const int rlo=(it==0)?0:3, cnt=(19-rlo)*41;
      for (int i=tid;i<cnt;i+=256){
        int r=rlo+i/41, k=i-(i/41)*41;
        int pos=p0-3+r;
        s_x[r*44+k] = (pos>=0) ? xg[((size_t)b*SEQ+(size_t)pos)*41+k] : 0.f;
      }
    }
    __syncthreads();
    // ---- B: in_proj (xs half), 2 threads/column, weights in LDS ----
    if (tid<164){
      const int e=(tid<82)?tid:tid-82, rh=(tid>=82);
      if (it==0){ if(!rh) inproj_rows<10>(0,e,s_x,w_t,s_xs); else inproj_rows<9>(10,e,s_x,w_t,s_xs); }
      else      { inproj_rows<8>(rh?11:3,e,s_x,w_t,s_xs); }
    }
    __syncthreads();
    // ---- C: conv + silu -> s_xc ----
    for (int w=tid;w<1312;w+=256){
      const int l=w&15, dd=w>>4;
      float a=s_cb[dd];
#pragma unroll
      for (int k=0;k<4;k++) a=fmaf(s_xs[(l+k)*82+dd], s_cw[k*82+dd], a);
      s_xc[l*82+dd]=silu_f(a);
    }
    __syncthreads();
    // ---- D: x_proj (35 rows) -> dt/B/C in s_db only ----
    for (int w=tid;w<560;w+=256){
      const int l=w&15, j=w>>4;
      const float2* wp=(const float2*)(w_xproj + j*82);
      const float2* gp=(const float2*)&s_xc[l*82];
      float a=0.f;
#pragma unroll
      for (int dq=0;dq<41;dq++){
        const float2 wv=wp[dq], gv=gp[dq];
        a=fmaf(wv.x,gv.x,a); a=fmaf(wv.y,gv.y,a);
      }
      const int col=(j<3)?j:j+1;
      s_db[l*36+col]=a;
    }
    __syncthreads();
    // ---- D2: dt_proj + softplus -> delta ----
    for (int w=tid;w<1312;w+=256){
      const int l=w&15, dd=w>>4;
      float a=s_dtb[dd];
      a=fmaf(s_db[l*36+0],s_dtw[0*82+dd],a);
      a=fmaf(s_db[l*36+1],s_dtw[1*82+dd],a);
      a=fmaf(s_db[l*36+2],s_dtw[2*82+dd],a);
      s_q[l*82+dd]=softplus_f(a);
    }
    __syncthreads();
    // ---- E: local scan; stage yloc into s_xc, Dp into s_q (in place) ----
    if (tid<164){
#pragma unroll 1
      for (int l=0;l<16;l++){
        const float dl  = s_q[l*82+d];
        const float xc  = s_xc[l*82+d];
        const float dxc = dl*xc;
        Dp += dl;
        const float4 B0=*(const float4*)&s_db[l*36+4+sg*8];
        const float4 B1=*(const float4*)&s_db[l*36+8+sg*8];
        const float4 C0=*(const float4*)&s_db[l*36+20+sg*8];
        const float4 C1=*(const float4*)&s_db[l*36+24+sg*8];
        const float Bv[8]={B0.x,B0.y,B0.z,B0.w,B1.x,B1.y,B1.z,B1.w};
        const float Cv[8]={C0.x,C0.y,C0.z,C0.w,C1.x,C1.y,C1.z,C1.w};
        float y=0.f;
        if (flag){
          const float q=__expf(dl*A0d);
          const float q2=q*q, q4=q2*q2;
          float e = sg ? q4*q4*q : q;
#pragma unroll
          for (int s=0;s<8;s++){
            h[s]=fmaf(e,h[s],dxc*Bv[s]);
            y=fmaf(h[s],Cv[s],y);
            if(s<7) e*=q;
          }
        } else {
#pragma unroll
          for (int s=0;s<8;s++){
            const float e=__expf(dl*As[s]);
            h[s]=fmaf(e,h[s],dxc*Bv[s]);
            y=fmaf(h[s],Cv[s],y);
          }
        }
        y += __shfl_down(y,1);
        if (sg==0){
          // pair lanes are lockstep: both read xc/dl above before these writes
          s_xc[l*82+d] = y + xc*s_Dv[d];   // yloc
          s_q [l*82+d] = Dp;               // prefix-sum of delta
        }
      }
    }
    __syncthreads();
    // ---- F: batched record writeout (720 float4 = 16 recs x 180 floats) ----
    {
      float* fb = feat + ((size_t)b*SEG + (size_t)(tile*T0+it*16))*FREC;
      for (int i=tid;i<720;i+=256){
        const int l=i/45, q=i-l*45;
        const int f=4*q;
        float4 v;
        if (q<20){
          v.x=s_xc[l*82+f+0]; v.y=s_xc[l*82+f+1];
          v.z=s_xc[l*82+f+2]; v.w=s_xc[l*82+f+3];
        } else if (q==20){
          v.x=s_xc[l*82+80]; v.y=s_xc[l*82+81];
          v.z=s_q[l*82+0];   v.w=s_q[l*82+1];
        } else if (q<=40){
          v.x=s_q[l*82+f-82]; v.y=s_q[l*82+f-81];
          v.z=s_q[l*82+f-80]; v.w=s_q[l*82+f-79];
        } else {
          const int c=f-164;
          v.x=s_db[l*36+20+c+0]; v.y=s_db[l*36+20+c+1];
          v.z=s_db[l*36+20+c+2]; v.w=s_db[l*36+20+c+3];
        }
        *(float4*)&fb[(size_t)l*FREC + f] = v;
      }
    }
    // no trailing barrier: next C/D2 writes to s_xc/s_q are 2+ barriers away
  }

  if (tid<164){
    float Pv[8];
    if (flag){
      const float Qt=__expf(Dp*A0d);
      const float Q2=Qt*Qt, Q4=Q2*Q2, Q8=Q4*Q4;
      float c = sg ? Q8*Qt : Qt;
#pragma unroll
      for (int i=0;i<8;i++){ Pv[i]=c; c*=Qt; }
    } else {
#pragma unroll
      for (int i=0;i<8;i++) Pv[i]=__expf(Dp*As[i]);
    }
    const size_t base = ((size_t)(b*gridDim.x+tile))*1312 + (size_t)d*16 + sg*8;
    *(float4*)&Pg[base]   = make_float4(Pv[0],Pv[1],Pv[2],Pv[3]);
    *(float4*)&Pg[base+4] = make_float4(Pv[4],Pv[5],Pv[6],Pv[7]);
    *(float4*)&Hg[base]   = make_float4(h[0],h[1],h[2],h[3]);
    *(float4*)&Hg[base+4] = make_float4(h[4],h[5],h[6],h[7]);
  }
}

__global__ __launch_bounds__(256) void k2_comb(
    const float* __restrict__ Pg, const float* __restrict__ Hg,
    float* __restrict__ Hin, float* __restrict__ carry, int TPP, int first)
{
  const int g = blockIdx.x*256 + threadIdx.x;   // < 32*1312
  const int b = g/1312, r = g - b*1312;
  float h = first ? 0.f : carry[g];
#pragma unroll 4
  for (int t=0;t<TPP;t++){
    const size_t idx = ((size_t)(b*TPP+t))*1312 + r;
    Hin[idx]=h;
    h = fmaf(Pg[idx], h, Hg[idx]);
  }
  carry[g]=h;
}

__launch_bounds__(256, 4)
__global__ void k4_out(
    const float* __restrict__ xg, const float* __restrict__ w_in,
    const float* __restrict__ A_log, const float* __restrict__ Mg,
    const float* __restrict__ b_cls, int off, int SEG,
    const float* __restrict__ feat, const float* __restrict__ Hin,
    float* __restrict__ outg)
{
  __shared__ float s_x[16*44];    // raw x rows
  __shared__ float w_zt[41*82];   // in_proj z-half transposed [k][e] (LDS!)
  __shared__ float s_z[16*82];    // silu(z)
  __shared__ float s_g[16*82];    // gated value
  __shared__ float s_c[16*16];    // C rows
  __shared__ float s_hin[1312];   // s-major [s*82+d]
  __shared__ float s_M[10*82];    // fused Wc*Wo
  __shared__ float s_A0[82], s_bc[10];
  __shared__ int   s_flag[82];
  // ~37.1 KB -> 4 blocks/CU

  const int tid = threadIdx.x;
  const int tile = blockIdx.x, b = blockIdx.y;

  for (int i=tid;i<41*82;i+=256){ int k=i/82,e=i-k*82; w_zt[i]=w_in[(82+e)*41+k]; }
  for (int i=tid;i<1312;i+=256){
    const int dd=i>>4, s=i&15;
    s_hin[s*82+dd] = Hin[((size_t)(b*gridDim.x+tile))*1312 + i];
  }
  for (int i=tid;i<820;i+=256) s_M[i]=Mg[i];
  if (tid<10) s_bc[tid]=b_cls[tid];
  if (tid<82){
    float A0=-expf(A_log[tid*16]); s_A0[tid]=A0;
    bool ok=(A0<0.f);
#pragma unroll
    for (int s=1;s<16;s++){
      float As=-expf(A_log[tid*16+s]);
      ok = ok && (fabsf(As-(float)(s+1)*A0) <= 1e-3f*(float)(s+1)*fabsf(A0));
    }
    s_flag[tid]=ok?1:0;
  }
  // hoisted (l,d) decomposition for the 1312-item stage
  int lk[6], dk[6];
#pragma unroll
  for (int k=0;k<6;k++){ const int w=tid+256*k; lk[k]=w/82; dk[k]=w-lk[k]*82; }

  for (int it=0; it<T0/16; ++it){
    const int lp0 = tile*T0 + it*16;
    const int gp0 = off + lp0;
    __syncthreads();
    // ---- A: load raw x + C rows ----
    for (int i=tid;i<656;i+=256){
      const int r=i/41, k=i-r*41;
      s_x[r*44+k] = xg[((size_t)b*SEQ+(size_t)(gp0+r))*41+k];
    }
    for (int i=tid;i<64;i+=256){
      const int l=i>>2, q=i&3;
      ((float4*)&s_c[l*16])[q] =
          ((const float4*)(feat + ((size_t)b*SEG+(size_t)(lp0+l))*FREC + 164))[q];
    }
    __syncthreads();
    // ---- B: z-proj (LDS weights), 2 threads/column, 8 rows -> silu ----
    if (tid<164){
      const int e=(tid<82)?tid:tid-82, l0=(tid>=82)?8:0;
      float acc[8];
#pragma unroll
      for (int i=0;i<8;i++) acc[i]=0.f;
#pragma unroll
      for (int kq=0;kq<40;kq+=4){
        const float w0=w_zt[(kq+0)*82+e], w1=w_zt[(kq+1)*82+e];
        const float w2=w_zt[(kq+2)*82+e], w3=w_zt[(kq+3)*82+e];
#pragma unroll
        for (int i=0;i<8;i++){
          const float4 xv=*(const float4*)&s_x[(l0+i)*44+kq];
          acc[i]=fmaf(xv.x,w0,acc[i]); acc[i]=fmaf(xv.y,w1,acc[i]);
          acc[i]=fmaf(xv.z,w2,acc[i]); acc[i]=fmaf(xv.w,w3,acc[i]);
        }
      }
      const float wl=w_zt[40*82+e];
#pragma unroll
      for (int i=0;i<8;i++)
        s_z[(l0+i)*82+e] = silu_f(fmaf(s_x[(l0+i)*44+40], wl, acc[i]));
    }
    __syncthreads();
    // ---- C: closed-form correction + gate ----
#pragma unroll
    for (int k=0;k<6;k++){
      const int w=tid+256*k;
      if (w>=1312) break;
      const int l=lk[k], dd=dk[k];
      const float* fp = feat + ((size_t)b*SEG+(size_t)(lp0+l))*FREC;
      const float yl = fp[dd];
      const float Dp = fp[82+dd];
      float acc=yl;
      if (s_flag[dd]){
        const float Qt=__expf(s_A0[dd]*Dp);
        float e=Qt;
#pragma unroll
        for (int s=0;s<16;s++){
          acc = fmaf(s_c[l*16+s]*e, s_hin[s*82+dd], acc);
          if (s<15) e*=Qt;
        }
      } else {
#pragma unroll
        for (int s=0;s<16;s++){
          const float As = -__expf(A_log[dd*16+s]);
          acc = fmaf(s_c[l*16+s]*__expf(As*Dp), s_hin[s*82+dd], acc);
        }
      }
      s_g[l*82+dd] = acc * s_z[l*82+dd];
    }
    __syncthreads();
    // ---- D: fused logits = M*g + b, contiguous store ----
    if (tid<160){
      const int l=tid/10, n=tid-(tid/10)*10;
      float a=s_bc[n];
      const float2* gp=(const float2*)&s_g[l*82];
      const float2* mp=(const float2*)&s_M[n*82];
#pragma unroll
      for (int q=0;q<41;q++){
        const float2 gv=gp[q], mv=mp[q];
        a=fmaf(gv.x,mv.x,a); a=fmaf(gv.y,mv.y,a);
      }
      outg[((size_t)b*SEQ+(size_t)gp0)*10 + tid] = a;
    }
    // no trailing barrier: top-of-loop sync protects s_x/s_c overwrite
  }
}

// ============================================================================
// OLD PATH (proven fallback)
// ============================================================================

template <int PASS>
__launch_bounds__(256, 2)
__global__ void mamba_chunk(
    const float* __restrict__ xg, const float* __restrict__ w_in,
    const float* __restrict__ w_conv, const float* __restrict__ b_conv,
    const float* __restrict__ w_xproj, const float* __restrict__ w_dt,
    const float* __restrict__ b_dt, const float* __restrict__ A_log,
    const float* __restrict__ Dvec, const float* __restrict__ w_out,
    const float* __restrict__ w_cls, const float* __restrict__ b_cls,
    float* __restrict__ Pg, float* __restrict__ Hg,
    const float* __restrict__ Hin, float* __restrict__ outg)
{
  __shared__ float s_x[RWS*XPAD];
  __shared__ float s_xs[RWS*SPAD];
  __shared__ float s_xc[TSUB*CPAD];
  __shared__ float s_z[TSUB*SPAD];
  __shared__ float s_xdbc[TSUB*JPAD];
  __shared__ float w_in_t[DMODEL*164];
  __shared__ float w_xp_t[DIN*35];
  __shared__ float s_cw[DIN*4];
  __shared__ float s_cb[DIN];
  __shared__ float s_dtw[DIN*3];
  __shared__ float s_dtb[DIN];

  const int tid=threadIdx.x;
  const int b=blockIdx.x/NCHUNK, c=blockIdx.x%NCHUNK, l0c=c*CHUNK;
  constexpr int NJ=(PASS==3)?35:19;
  constexpr int NE=(PASS==3)?164:DIN;

  for (int i=tid;i<DMODEL*164;i+=256){ int k=i/164,e=i-k*164; w_in_t[i]=w_in[e*DMODEL+k]; }
  for (int i=tid;i<DIN*35;i+=256){ int dd=i/35,j=i-dd*35; w_xp_t[i]=w_xproj[j*DIN+dd]; }
  for (int i=tid;i<DIN*4;i+=256) s_cw[i]=w_conv[i];
  for (int i=tid;i<DIN*3;i+=256) s_dtw[i]=w_dt[i];
  if (tid<DIN){ s_cb[tid]=b_conv[tid]; s_dtb[tid]=b_dt[tid]; }

  float h[NSTATE], Pp[NSTATE], As[NSTATE];
  float A0=-1.f, Dd=0.f;
  bool structured=true;
  if (tid<DIN){
#pragma unroll
    for (int s=0;s<NSTATE;++s) As[s]=-expf(A_log[tid*NSTATE+s]);
    A0=As[0];
#pragma unroll
    for (int s=0;s<NSTATE;++s)
      structured = structured && (fabsf(As[s]-(float)(s+1)*A0)<=1e-3f*(float)(s+1)*fabsf(A0));
    structured = structured && (A0<0.f);
    if (PASS==3){
      Dd=Dvec[tid];
      size_t base=((size_t)(b*NCHUNK+c))*(DIN*NSTATE)+(size_t)tid*NSTATE;
#pragma unroll
      for (int s=0;s<NSTATE;++s) h[s]=Hin[base+s];
    } else {
#pragma unroll
      for (int s=0;s<NSTATE;++s){ h[s]=0.f; Pp[s]=1.f; }
    }
  }
  __syncthreads();

  for (int t=0;t<NSUB;++t){
    const int p0=l0c+t*TSUB;
    for (int i=tid;i<RWS*DMODEL;i+=256){
      int r=i/DMODEL,k=i-r*DMODEL;
      int pos=p0-3+r;
      s_x[r*XPAD+k]=(pos>=0)?xg[(size_t)b*SEQ*DMODEL+(size_t)pos*DMODEL+k]:0.f;
    }
    __syncthreads();
    {
      const int e=tid;
      if (e<NE){
        float acc[RWS];
#pragma unroll
        for (int r=0;r<RWS;++r) acc[r]=0.f;
#pragma unroll
        for (int kq=0;kq<40;kq+=4){
          const float w0=w_in_t[(kq+0)*164+e], w1=w_in_t[(kq+1)*164+e];
          const float w2=w_in_t[(kq+2)*164+e], w3=w_in_t[(kq+3)*164+e];
#pragma unroll
          for (int r=0;r<RWS;++r){
            const float4 xv=*(const float4*)&s_x[r*XPAD+kq];
            acc[r]=fmaf(xv.x,w0,acc[r]); acc[r]=fmaf(xv.y,w1,acc[r]);
            acc[r]=fmaf(xv.z,w2,acc[r]); acc[r]=fmaf(xv.w,w3,acc[r]);
          }
        }
        const float wl=w_in_t[40*164+e];
#pragma unroll
        for (int r=0;r<RWS;++r) acc[r]=fmaf(s_x[r*XPAD+40],wl,acc[r]);
        if (e<DIN){
#pragma unroll
          for (int r=0;r<RWS;++r) s_xs[r*SPAD+e]=acc[r];
        } else {
#pragma unroll
          for (int r=3;r<RWS;++r) s_z[(r-3)*SPAD+(e-DIN)]=acc[r];
        }
      }
    }
    __syncthreads();
    for (int w=tid;w<TSUB*DIN;w+=256){
      const int l=w&15,e=w>>4;
      float a=s_cb[e];
#pragma unroll
      for (int k=0;k<4;++k) a=fmaf(s_xs[(l+k)*SPAD+e],s_cw[e*4+k],a);
      s_xc[l*CPAD+e]=siluf(a);
    }
    __syncthreads();
    for (int w=tid;w<TSUB*NJ;w+=256){
      const int l=w&15,j=w>>4;
      float a=0.f;
#pragma unroll
      for (int dq=0;dq<80;dq+=4){
        const float4 xv=*(const float4*)&s_xc[l*CPAD+dq];
        a=fmaf(xv.x,w_xp_t[(dq+0)*35+j],a); a=fmaf(xv.y,w_xp_t[(dq+1)*35+j],a);
        a=fmaf(xv.z,w_xp_t[(dq+2)*35+j],a); a=fmaf(xv.w,w_xp_t[(dq+3)*35+j],a);
      }
      a=fmaf(s_xc[l*CPAD+80],w_xp_t[80*35+j],a);
      a=fmaf(s_xc[l*CPAD+81],w_xp_t[81*35+j],a);
      const int col=(j<3)?j:j+1;
      s_xdbc[l*JPAD+col]=a;
    }
    __syncthreads();
    for (int w=tid;w<TSUB*DIN;w+=256){
      const int l=w&15,dd=w>>4;
      float a=s_dtb[dd];
      a=fmaf(s_xdbc[l*JPAD+0],s_dtw[dd*3+0],a);
      a=fmaf(s_xdbc[l*JPAD+1],s_dtw[dd*3+1],a);
      a=fmaf(s_xdbc[l*JPAD+2],s_dtw[dd*3+2],a);
      s_xs[l*SPAD+dd]=softplusf(a);
    }
    __syncthreads();
    if (tid<DIN){
      const int dd=tid;
#pragma unroll 1
      for (int l=0;l<TSUB;++l){
        const float dl=s_xs[l*SPAD+dd];
        const float xcd=s_xc[l*CPAD+dd];
        const float dxc=dl*xcd;
        const float4 B0=*(const float4*)&s_xdbc[l*JPAD+4];
        const float4 B1=*(const float4*)&s_xdbc[l*JPAD+8];
        const float4 B2=*(const float4*)&s_xdbc[l*JPAD+12];
        const float4 B3=*(const float4*)&s_xdbc[l*JPAD+16];
        const float Bv[NSTATE]={B0.x,B0.y,B0.z,B0.w,B1.x,B1.y,B1.z,B1.w,
                                B2.x,B2.y,B2.z,B2.w,B3.x,B3.y,B3.z,B3.w};
        float Cv[NSTATE];
        if (PASS==3){
          const float4 C0=*(const float4*)&s_xdbc[l*JPAD+20];
          const float4 C1=*(const float4*)&s_xdbc[l*JPAD+24];
          const float4 C2=*(const float4*)&s_xdbc[l*JPAD+28];
          const float4 C3=*(const float4*)&s_xdbc[l*JPAD+32];
          Cv[0]=C0.x;Cv[1]=C0.y;Cv[2]=C0.z;Cv[3]=C0.w;
          Cv[4]=C1.x;Cv[5]=C1.y;Cv[6]=C1.z;Cv[7]=C1.w;
          Cv[8]=C2.x;Cv[9]=C2.y;Cv[10]=C2.z;Cv[11]=C2.w;
          Cv[12]=C3.x;Cv[13]=C3.y;Cv[14]=C3.z;Cv[15]=C3.w;
        }
        float y=(PASS==3)?Dd*xcd:0.f;
        if (structured){
          const float q=expf(dl*A0);
          float e=q;
#pragma unroll
          for (int s=0;s<NSTATE;++s){
            h[s]=fmaf(e,h[s],dxc*Bv[s]);
            if (PASS==1) Pp[s]*=e; else y=fmaf(h[s],Cv[s],y);
            if (s<NSTATE-1) e*=q;
          }
        } else {
#pragma unroll
          for (int s=0;s<NSTATE;++s){
            const float e=expf(dl*As[s]);
            h[s]=fmaf(e,h[s],dxc*Bv[s]);
            if (PASS==1) Pp[s]*=e; else y=fmaf(h[s],Cv[s],y);
          }
        }
        if (PASS==3) s_xs[l*SPAD+dd]=y;
      }
    }
    __syncthreads();
    if (PASS==3){
      for (int w=tid;w<TSUB*DIN;w+=256){
        const int l=w&15,dd=w>>4;
        s_xc[l*CPAD+dd]=s_xs[l*SPAD+dd]*siluf(s_z[l*SPAD+dd]);
      }
      __syncthreads();
      for (int w=tid;w<TSUB*DMODEL;w+=256){
        const int l=w&15,dm=w>>4;
        const float2* wp=(const float2*)(w_out+dm*DIN);
        const float2* gp=(const float2*)&s_xc[l*CPAD];
        float a=0.f;
#pragma unroll
        for (int dq=0;dq<41;++dq){
          const float2 wv=wp[dq], gv=gp[dq];
          a=fmaf(wv.x,gv.x,a); a=fmaf(wv.y,gv.y,a);
        }
        s_x[l*XPAD+dm]=a;
      }
      __syncthreads();
      for (int w=tid;w<TSUB*NLAB;w+=256){
        const int l=w&15,n=w>>4;
        float a=b_cls[n];
#pragma unroll
        for (int dm=0;dm<DMODEL;++dm) a=fmaf(w_cls[n*DMODEL+dm],s_x[l*XPAD+dm],a);
        s_xdbc[l*NLAB+n]=a;
      }
      __syncthreads();
      for (int i=tid;i<TSUB*NLAB;i+=256)
        outg[((size_t)(b*SEQ+p0))*NLAB+i]=s_xdbc[i];
      __syncthreads();
    }
  }

  if (PASS==1 && tid<DIN){
    size_t base=((size_t)(b*NCHUNK+c))*(DIN*NSTATE)+(size_t)tid*NSTATE;
#pragma unroll
    for (int s=0;s<NSTATE;++s){ Pg[base+s]=Pp[s]; Hg[base+s]=h[s]; }
  }
}

__global__ __launch_bounds__(256) void mamba_combine(
    const float* __restrict__ P, const float* __restrict__ H, float* __restrict__ Hin){
  const int g=blockIdx.x*256+threadIdx.x;
  const int b=g/(DIN*NSTATE), ds=g-b*(DIN*NSTATE);
  float h=0.f;
#pragma unroll 1
  for (int c=0;c<NCHUNK;++c){
    const size_t idx=((size_t)(b*NCHUNK+c))*(DIN*NSTATE)+ds;
    Hin[idx]=h;
    h=fmaf(P[idx],h,H[idx]);
  }
}

// ============================================================================

extern "C" void kernel_launch(void* const* d_in, const int* in_sizes, int n_in,
                              void* d_out, int out_size, void* d_ws, size_t ws_size,
                              hipStream_t stream) {
  const float* xg     = (const float*)d_in[0];
  const float* w_in   = (const float*)d_in[1];
  const float* w_conv = (const float*)d_in[2];
  const float* b_conv = (const float*)d_in[3];
  const float* w_xp   = (const float*)d_in[4];
  const float* w_dt   = (const float*)d_in[5];
  const float* b_dt   = (const float*)d_in[6];
  const float* A_log  = (const float*)d_in[7];
  const float* Dv     = (const float*)d_in[8];
  const float* w_out  = (const float*)d_in[9];
  const float* w_cls  = (const float*)d_in[10];
  const float* b_cls  = (const float*)d_in[11];
  float* outg = (float*)d_out;

  int P = 0;
  for (int p : {1,2,4,8}) if (ws_size >= tier_bytes(p)) { P = p; break; }

  if (P) {
    const int SEG = SEQ/P, tiles = SEG/T0;
    const size_t featF = (size_t)BATCH*SEG*FREC;
    const size_t phF   = (size_t)BATCH*tiles*1312;
    float* feat  = (float*)d_ws;
    float* Pg    = feat + featF;
    float* Hg    = Pg + phF;
    float* Hin   = Hg + phF;
    float* carry = Hin + phF;
    float* Mg    = carry + (size_t)BATCH*1312;
    k_pre<<<dim3(4),256,0,stream>>>(w_out, w_cls, Mg);
    for (int p=0;p<P;p++){
      const int off = p*SEG;
      k0_feat<<<dim3(tiles,BATCH),256,0,stream>>>(
          xg,w_in,w_conv,b_conv,w_xp,w_dt,b_dt,A_log,Dv,off,SEG,feat,Pg,Hg);
      k2_comb<<<dim3((BATCH*1312)/256),256,0,stream>>>(Pg,Hg,Hin,carry,tiles,p==0?1:0);
      k4_out<<<dim3(tiles,BATCH),256,0,stream>>>(
          xg,w_in,A_log,Mg,b_cls,off,SEG,feat,Hin,outg);
    }
  } else {
    float* Pg  = (float*)d_ws;
    float* Hg  = Pg + NPH_OLD;
    float* Hin = Hg + NPH_OLD;
    dim3 grid(BATCH*NCHUNK), blk(256);
    mamba_chunk<1><<<grid,blk,0,stream>>>(xg,w_in,w_conv,b_conv,w_xp,w_dt,b_dt,
                                          A_log,Dv,w_out,w_cls,b_cls,Pg,Hg,nullptr,nullptr);
    mamba_combine<<<dim3((BATCH*DIN*NSTATE)/256),blk,0,stream>>>(Pg,Hg,Hin);
    mamba_chunk<3><<<grid,blk,0,stream>>>(xg,w_in,w_conv,b_conv,w_xp,w_dt,b_dt,
                                          A_log,Dv,w_out,w_cls,b_cls,nullptr,nullptr,Hin,outg);
  }
}

// Round 8
// 548.282 us; speedup vs baseline: 1.5221x; 1.0678x over previous
//
#include <hip/hip_runtime.h>
#include <math.h>

// Mamba block, fp32, single-scan + closed-form seeding + fused epilogue.
// k_pre  : M = w_cls@w_out (10x82) into ws.
// k0_feat: features once + local scan -> per-pos (yloc, Dp, C) record staged in
//          LDS, then ONE batched float4 writeout per subtile (full-line writes,
//          no partial-dirty-line RMW). Weights in LDS.
// k2_comb: sequential combine over tiles -> Hin per tile (carry across phases).
// k4_out : z-proj (LDS weights), closed-form corr, gate, fused M-GEMM logits.
// R15: R14 (proven 585.5us) with ONE change: T0 128 -> 256.
//   Grid becomes 32x32=1024 blocks = EXACTLY 4/CU x 256 CUs (one residency
//   round, no tail). Prologues/CU 8->4 (measured ~2.9us each from R14's
//   16->8 = -23us on k0). k2 TPP 64->32; Pg/Hg/Hin now ~5.4MB (L2-resident).
//   T0=512 would drop to 2 blocks/CU (R9: -34%) -> 256 is this lever's end.
//   Numerics: structured A; Dp~180 over 256 pos -> exp underflow to 0 is the
//   correct vanishing contribution (no NaN path). R14 split-point change
//   left absmax at 5.96e-8.
// HARD-WON CONSTRAINTS (R8-R12 post-mortems):
//  - (256,n): n = resident blocks AND VGPR cap ~256/n. (256,4) mandatory;
//    64-VGPR cap leaves ZERO headroom: EVERY phase-body reshaping attempted
//    (reg-weights, (256,2), stride-84 vec, D-2col, E-fold, A-float2) spilled
//    (FETCH 50->77..210MB) or halved residency. Phase bodies are FROZEN.
//  - k0/k4 are LDS-pipe/issue bound; occupancy not the lever (R8); HBM 13%
//    not the lever. Broadcast LDS reads ~free (R11 k4-C neutral).
//  - weights MUST be in LDS (R7): global weights miss under feat streaming.
//  - T0 (tile length) is the ONLY register-safe lever: touches trip count
//    and grid only. R14: 64->128 = -57.7us total.
// OLD path (proven): fallback if ws too small.

namespace {
constexpr int DMODEL=41, DIN=82, NSTATE=16, NLAB=10, BATCH=32, SEQ=8192;
// old path
constexpr int CHUNK=512, NCHUNK=SEQ/CHUNK, TSUB=16, NSUB=CHUNK/TSUB, RWS=TSUB+3;
constexpr int XPAD=44, SPAD=83, CPAD=84, JPAD=36;
constexpr int NPH_OLD = BATCH*NCHUNK*DIN*NSTATE;
// new path
constexpr int T0 = 256;             // positions per k0/k4 tile (R15: 128->256)
constexpr int FREC = 180;           // yloc@0(82) | Dp@82(82) | C@164(16)
inline size_t tier_bytes(int P){
  size_t SEG = (size_t)SEQ/P, tiles = SEG/T0;
  return ((size_t)BATCH*SEG*FREC + 3*((size_t)BATCH*tiles*1312)
          + (size_t)BATCH*1312 + 4096)*4;
}
}

__device__ __forceinline__ float siluf(float v)     { return v / (1.f + expf(-v)); }
__device__ __forceinline__ float softplusf(float v) { return (v > 20.f) ? v : log1pf(expf(v)); }
// fast variants (validated R4/R5: absmax unchanged at 5.96e-8)
__device__ __forceinline__ float silu_f(float v){
  return v * __builtin_amdgcn_rcpf(1.f + __expf(-v));
}
__device__ __forceinline__ float softplus_f(float v){
  return (v > 20.f) ? v : __logf(1.f + __expf(v));
}

// in_proj helper: NR rows from r0, col e(<82), weights in LDS [k*82+e],
// x stride 44, out stride 82
template<int NR>
__device__ __forceinline__ void inproj_rows(int r0, int e,
    const float* __restrict__ sx, const float* __restrict__ wt,
    float* __restrict__ sxs) {
  float acc[NR];
#pragma unroll
  for (int i=0;i<NR;i++) acc[i]=0.f;
#pragma unroll
  for (int kq=0;kq<40;kq+=4){
    const float w0=wt[(kq+0)*82+e], w1=wt[(kq+1)*82+e];
    const float w2=wt[(kq+2)*82+e], w3=wt[(kq+3)*82+e];
#pragma unroll
    for (int i=0;i<NR;i++){
      const float4 xv = *(const float4*)&sx[(r0+i)*44+kq];
      acc[i]=fmaf(xv.x,w0,acc[i]); acc[i]=fmaf(xv.y,w1,acc[i]);
      acc[i]=fmaf(xv.z,w2,acc[i]); acc[i]=fmaf(xv.w,w3,acc[i]);
    }
  }
  const float wl = wt[40*82+e];
#pragma unroll
  for (int i=0;i<NR;i++)
    sxs[(r0+i)*82+e] = fmaf(sx[(r0+i)*44+40], wl, acc[i]);
}

// ============================================================================
// NEW PATH
// ============================================================================

__global__ __launch_bounds__(256) void k_pre(
    const float* __restrict__ w_out, const float* __restrict__ w_cls,
    float* __restrict__ M){
  const int w = blockIdx.x*256 + threadIdx.x;
  if (w < NLAB*DIN){
    const int n = w/82, dd = w - n*82;
    float a = 0.f;
#pragma unroll
    for (int dm=0;dm<41;dm++) a = fmaf(w_cls[n*41+dm], w_out[dm*82+dd], a);
    M[w] = a;
  }
}

__launch_bounds__(256, 4)
__global__ void k0_feat(
    const float* __restrict__ xg, const float* __restrict__ w_in,
    const float* __restrict__ w_conv, const float* __restrict__ b_conv,
    const float* __restrict__ w_xproj, const float* __restrict__ w_dt,
    const float* __restrict__ b_dt, const float* __restrict__ A_log,
    const float* __restrict__ Dvec, int off, int SEG,
    float* __restrict__ feat, float* __restrict__ Pg, float* __restrict__ Hg)
{
  __shared__ float s_x[19*44];    // raw x rows (pos p0-3 .. p0+15)
  __shared__ float s_xs[19*82];   // xs rows incl conv halo
  __shared__ float s_xc[16*82];   // xc; scan overwrites with yloc
  __shared__ float s_q[16*82];    // delta; scan overwrites with Dp
  __shared__ float s_db[16*36];   // dt@0..2, B@4..19, C@20..35
  __shared__ float w_t[41*82];    // in_proj xs-half transposed [k][e] (LDS!)
  __shared__ float s_cw[4*82];    // conv w transposed [k][d]
  __shared__ float s_dtw[3*82];   // dt w transposed [k][d]
  __shared__ float s_cb[82], s_dtb[82], s_A0[82], s_Dv[82];
  __shared__ int   s_flag[82];
  // ~39.8 KB -> 4 blocks/CU

  const int tid = threadIdx.x;
  const int tile = blockIdx.x, b = blockIdx.y;
  const int base_pos = off + tile*T0;

  for (int i=tid;i<41*82;i+=256){ int k=i/82,e=i-k*82; w_t[i]=w_in[e*41+k]; }
  for (int i=tid;i<328;i+=256){ int dd=i/4,k=i-dd*4; s_cw[k*82+dd]=w_conv[i]; }
  for (int i=tid;i<246;i+=256){ int dd=i/3,k=i-dd*3; s_dtw[k*82+dd]=w_dt[i]; }
  if (tid<82){
    s_cb[tid]=b_conv[tid]; s_dtb[tid]=b_dt[tid]; s_Dv[tid]=Dvec[tid];
    float A0=-expf(A_log[tid*16]); s_A0[tid]=A0;
    bool ok=(A0<0.f);
#pragma unroll
    for (int s=1;s<16;s++){
      float As=-expf(A_log[tid*16+s]);
      ok = ok && (fabsf(As-(float)(s+1)*A0) <= 1e-3f*(float)(s+1)*fabsf(A0));
    }
    s_flag[tid]=ok?1:0;
  }
  __syncthreads();

  const int d = tid>>1, sg = tid&1;
  float h[8], As[8], A0d=-1.f, Dp=0.f;
  int flag=1;
  if (tid<164){
    flag = s_flag[d]; A0d = s_A0[d];
    if (!flag){
#pragma unroll
      for (int i=0;i<8;i++) As[i]=-expf(A_log[d*16+sg*8+i]);
    }
#pragma unroll
    for (int i=0;i<8;i++) h[i]=0.f;
  }

  for (int it=0; it<T0/16; ++it){
    const int p0 = base_pos + it*16;
    // ---- A: halo shift + raw x load ----
    if (it>0){
      for (int i=tid;i<246;i+=256){ int r=i/82, dd=i-r*82; s_xs[r*82+dd]=s_xs[(16+r)*82+dd]; }
    }
    {
      const int rlo=(it==0)?0:3, cnt=(19-rlo)*41;
      for (int i=tid;i<cnt;i+=256){
        int r=rlo+i/41, k=i-(i/41)*41;
        int pos=p0-3+r;
        s_x[r*44+k] = (pos>=0) ? xg[((size_t)b*SEQ+(size_t)pos)*41+k] : 0.f;
      }
    }
    __syncthreads();
    // ---- B: in_proj (xs half), 2 threads/column, weights in LDS ----
    if (tid<164){
      const int e=(tid<82)?tid:tid-82, rh=(tid>=82);
      if (it==0){ if(!rh) inproj_rows<10>(0,e,s_x,w_t,s_xs); else inproj_rows<9>(10,e,s_x,w_t,s_xs); }
      else      { inproj_rows<8>(rh?11:3,e,s_x,w_t,s_xs); }
    }
    __syncthreads();
    // ---- C: conv + silu -> s_xc ----
    for (int w=tid;w<1312;w+=256){
      const int l=w&15, dd=w>>4;
      float a=s_cb[dd];
#pragma unroll
      for (int k=0;k<4;k++) a=fmaf(s_xs[(l+k)*82+dd], s_cw[k*82+dd], a);
      s_xc[l*82+dd]=silu_f(a);
    }
    __syncthreads();
    // ---- D: x_proj (35 rows) -> dt/B/C in s_db only ----
    for (int w=tid;w<560;w+=256){
      const int l=w&15, j=w>>4;
      const float2* wp=(const float2*)(w_xproj + j*82);
      const float2* gp=(const float2*)&s_xc[l*82];
      float a=0.f;
#pragma unroll
      for (int dq=0;dq<41;dq++){
        const float2 wv=wp[dq], gv=gp[dq];
        a=fmaf(wv.x,gv.x,a); a=fmaf(wv.y,gv.y,a);
      }
      const int col=(j<3)?j:j+1;
      s_db[l*36+col]=a;
    }
    __syncthreads();
    // ---- D2: dt_proj + softplus -> delta ----
    for (int w=tid;w<1312;w+=256){
      const int l=w&15, dd=w>>4;
      float a=s_dtb[dd];
      a=fmaf(s_db[l*36+0],s_dtw[0*82+dd],a);
      a=fmaf(s_db[l*36+1],s_dtw[1*82+dd],a);
      a=fmaf(s_db[l*36+2],s_dtw[2*82+dd],a);
      s_q[l*82+dd]=softplus_f(a);
    }
    __syncthreads();
    // ---- E: local scan; stage yloc into s_xc, Dp into s_q (in place) ----
    if (tid<164){
#pragma unroll 1
      for (int l=0;l<16;l++){
        const float dl  = s_q[l*82+d];
        const float xc  = s_xc[l*82+d];
        const float dxc = dl*xc;
        Dp += dl;
        const float4 B0=*(const float4*)&s_db[l*36+4+sg*8];
        const float4 B1=*(const float4*)&s_db[l*36+8+sg*8];
        const float4 C0=*(const float4*)&s_db[l*36+20+sg*8];
        const float4 C1=*(const float4*)&s_db[l*36+24+sg*8];
        const float Bv[8]={B0.x,B0.y,B0.z,B0.w,B1.x,B1.y,B1.z,B1.w};
        const float Cv[8]={C0.x,C0.y,C0.z,C0.w,C1.x,C1.y,C1.z,C1.w};
        float y=0.f;
        if (flag){
          const float q=__expf(dl*A0d);
          const float q2=q*q, q4=q2*q2;
          float e = sg ? q4*q4*q : q;
#pragma unroll
          for (int s=0;s<8;s++){
            h[s]=fmaf(e,h[s],dxc*Bv[s]);
            y=fmaf(h[s],Cv[s],y);
            if(s<7) e*=q;
          }
        } else {
#pragma unroll
          for (int s=0;s<8;s++){
            const float e=__expf(dl*As[s]);
            h[s]=fmaf(e,h[s],dxc*Bv[s]);
            y=fmaf(h[s],Cv[s],y);
          }
        }
        y += __shfl_down(y,1);
        if (sg==0){
          // pair lanes are lockstep: both read xc/dl above before these writes
          s_xc[l*82+d] = y + xc*s_Dv[d];   // yloc
          s_q [l*82+d] = Dp;               // prefix-sum of delta
        }
      }
    }
    __syncthreads();
    // ---- F: batched record writeout (720 float4 = 16 recs x 180 floats) ----
    {
      float* fb = feat + ((size_t)b*SEG + (size_t)(tile*T0+it*16))*FREC;
      for (int i=tid;i<720;i+=256){
        const int l=i/45, q=i-l*45;
        const int f=4*q;
        float4 v;
        if (q<20){
          v.x=s_xc[l*82+f+0]; v.y=s_xc[l*82+f+1];
          v.z=s_xc[l*82+f+2]; v.w=s_xc[l*82+f+3];
        } else if (q==20){
          v.x=s_xc[l*82+80]; v.y=s_xc[l*82+81];
          v.z=s_q[l*82+0];   v.w=s_q[l*82+1];
        } else if (q<=40){
          v.x=s_q[l*82+f-82]; v.y=s_q[l*82+f-81];
          v.z=s_q[l*82+f-80]; v.w=s_q[l*82+f-79];
        } else {
          const int c=f-164;
          v.x=s_db[l*36+20+c+0]; v.y=s_db[l*36+20+c+1];
          v.z=s_db[l*36+20+c+2]; v.w=s_db[l*36+20+c+3];
        }
        *(float4*)&fb[(size_t)l*FREC + f] = v;
      }
    }
    // no trailing barrier: next C/D2 writes to s_xc/s_q are 2+ barriers away
  }

  if (tid<164){
    float Pv[8];
    if (flag){
      const float Qt=__expf(Dp*A0d);
      const float Q2=Qt*Qt, Q4=Q2*Q2, Q8=Q4*Q4;
      float c = sg ? Q8*Qt : Qt;
#pragma unroll
      for (int i=0;i<8;i++){ Pv[i]=c; c*=Qt; }
    } else {
#pragma unroll
      for (int i=0;i<8;i++) Pv[i]=__expf(Dp*As[i]);
    }
    const size_t base = ((size_t)(b*gridDim.x+tile))*1312 + (size_t)d*16 + sg*8;
    *(float4*)&Pg[base]   = make_float4(Pv[0],Pv[1],Pv[2],Pv[3]);
    *(float4*)&Pg[base+4] = make_float4(Pv[4],Pv[5],Pv[6],Pv[7]);
    *(float4*)&Hg[base]   = make_float4(h[0],h[1],h[2],h[3]);
    *(float4*)&Hg[base+4] = make_float4(h[4],h[5],h[6],h[7]);
  }
}

__global__ __launch_bounds__(256) void k2_comb(
    const float* __restrict__ Pg, const float* __restrict__ Hg,
    float* __restrict__ Hin, float* __restrict__ carry, int TPP, int first)
{
  const int g = blockIdx.x*256 + threadIdx.x;   // < 32*1312
  const int b = g/1312, r = g - b*1312;
  float h = first ? 0.f : carry[g];
#pragma unroll 4
  for (int t=0;t<TPP;t++){
    const size_t idx = ((size_t)(b*TPP+t))*1312 + r;
    Hin[idx]=h;
    h = fmaf(Pg[idx], h, Hg[idx]);
  }
  carry[g]=h;
}

__launch_bounds__(256, 4)
__global__ void k4_out(
    const float* __restrict__ xg, const float* __restrict__ w_in,
    const float* __restrict__ A_log, const float* __restrict__ Mg,
    const float* __restrict__ b_cls, int off, int SEG,
    const float* __restrict__ feat, const float* __restrict__ Hin,
    float* __restrict__ outg)
{
  __shared__ float s_x[16*44];    // raw x rows
  __shared__ float w_zt[41*82];   // in_proj z-half transposed [k][e] (LDS!)
  __shared__ float s_z[16*82];    // silu(z)
  __shared__ float s_g[16*82];    // gated value
  __shared__ float s_c[16*16];    // C rows
  __shared__ float s_hin[1312];   // s-major [s*82+d]
  __shared__ float s_M[10*82];    // fused Wc*Wo
  __shared__ float s_A0[82], s_bc[10];
  __shared__ int   s_flag[82];
  // ~37.1 KB -> 4 blocks/CU

  const int tid = threadIdx.x;
  const int tile = blockIdx.x, b = blockIdx.y;

  for (int i=tid;i<41*82;i+=256){ int k=i/82,e=i-k*82; w_zt[i]=w_in[(82+e)*41+k]; }
  for (int i=tid;i<1312;i+=256){
    const int dd=i>>4, s=i&15;
    s_hin[s*82+dd] = Hin[((size_t)(b*gridDim.x+tile))*1312 + i];
  }
  for (int i=tid;i<820;i+=256) s_M[i]=Mg[i];
  if (tid<10) s_bc[tid]=b_cls[tid];
  if (tid<82){
    float A0=-expf(A_log[tid*16]); s_A0[tid]=A0;
    bool ok=(A0<0.f);
#pragma unroll
    for (int s=1;s<16;s++){
      float As=-expf(A_log[tid*16+s]);
      ok = ok && (fabsf(As-(float)(s+1)*A0) <= 1e-3f*(float)(s+1)*fabsf(A0));
    }
    s_flag[tid]=ok?1:0;
  }
  // hoisted (l,d) decomposition for the 1312-item stage
  int lk[6], dk[6];
#pragma unroll
  for (int k=0;k<6;k++){ const int w=tid+256*k; lk[k]=w/82; dk[k]=w-lk[k]*82; }

  for (int it=0; it<T0/16; ++it){
    const int lp0 = tile*T0 + it*16;
    const int gp0 = off + lp0;
    __syncthreads();
    // ---- A: load raw x + C rows ----
    for (int i=tid;i<656;i+=256){
      const int r=i/41, k=i-r*41;
      s_x[r*44+k] = xg[((size_t)b*SEQ+(size_t)(gp0+r))*41+k];
    }
    for (int i=tid;i<64;i+=256){
      const int l=i>>2, q=i&3;
      ((float4*)&s_c[l*16])[q] =
          ((const float4*)(feat + ((size_t)b*SEG+(size_t)(lp0+l))*FREC + 164))[q];
    }
    __syncthreads();
    // ---- B: z-proj (LDS weights), 2 threads/column, 8 rows -> silu ----
    if (tid<164){
      const int e=(tid<82)?tid:tid-82, l0=(tid>=82)?8:0;
      float acc[8];
#pragma unroll
      for (int i=0;i<8;i++) acc[i]=0.f;
#pragma unroll
      for (int kq=0;kq<40;kq+=4){
        const float w0=w_zt[(kq+0)*82+e], w1=w_zt[(kq+1)*82+e];
        const float w2=w_zt[(kq+2)*82+e], w3=w_zt[(kq+3)*82+e];
#pragma unroll
        for (int i=0;i<8;i++){
          const float4 xv=*(const float4*)&s_x[(l0+i)*44+kq];
          acc[i]=fmaf(xv.x,w0,acc[i]); acc[i]=fmaf(xv.y,w1,acc[i]);
          acc[i]=fmaf(xv.z,w2,acc[i]); acc[i]=fmaf(xv.w,w3,acc[i]);
        }
      }
      const float wl=w_zt[40*82+e];
#pragma unroll
      for (int i=0;i<8;i++)
        s_z[(l0+i)*82+e] = silu_f(fmaf(s_x[(l0+i)*44+40], wl, acc[i]));
    }
    __syncthreads();
    // ---- C: closed-form correction + gate ----
#pragma unroll
    for (int k=0;k<6;k++){
      const int w=tid+256*k;
      if (w>=1312) break;
      const int l=lk[k], dd=dk[k];
      const float* fp = feat + ((size_t)b*SEG+(size_t)(lp0+l))*FREC;
      const float yl = fp[dd];
      const float Dp = fp[82+dd];
      float acc=yl;
      if (s_flag[dd]){
        const float Qt=__expf(s_A0[dd]*Dp);
        float e=Qt;
#pragma unroll
        for (int s=0;s<16;s++){
          acc = fmaf(s_c[l*16+s]*e, s_hin[s*82+dd], acc);
          if (s<15) e*=Qt;
        }
      } else {
#pragma unroll
        for (int s=0;s<16;s++){
          const float As = -__expf(A_log[dd*16+s]);
          acc = fmaf(s_c[l*16+s]*__expf(As*Dp), s_hin[s*82+dd], acc);
        }
      }
      s_g[l*82+dd] = acc * s_z[l*82+dd];
    }
    __syncthreads();
    // ---- D: fused logits = M*g + b, contiguous store ----
    if (tid<160){
      const int l=tid/10, n=tid-(tid/10)*10;
      float a=s_bc[n];
      const float2* gp=(const float2*)&s_g[l*82];
      const float2* mp=(const float2*)&s_M[n*82];
#pragma unroll
      for (int q=0;q<41;q++){
        const float2 gv=gp[q], mv=mp[q];
        a=fmaf(gv.x,mv.x,a); a=fmaf(gv.y,mv.y,a);
      }
      outg[((size_t)b*SEQ+(size_t)gp0)*10 + tid] = a;
    }
    // no trailing barrier: top-of-loop sync protects s_x/s_c overwrite
  }
}

// ============================================================================
// OLD PATH (proven fallback)
// ============================================================================

template <int PASS>
__launch_bounds__(256, 2)
__global__ void mamba_chunk(
    const float* __restrict__ xg, const float* __restrict__ w_in,
    const float* __restrict__ w_conv, const float* __restrict__ b_conv,
    const float* __restrict__ w_xproj, const float* __restrict__ w_dt,
    const float* __restrict__ b_dt, const float* __restrict__ A_log,
    const float* __restrict__ Dvec, const float* __restrict__ w_out,
    const float* __restrict__ w_cls, const float* __restrict__ b_cls,
    float* __restrict__ Pg, float* __restrict__ Hg,
    const float* __restrict__ Hin, float* __restrict__ outg)
{
  __shared__ float s_x[RWS*XPAD];
  __shared__ float s_xs[RWS*SPAD];
  __shared__ float s_xc[TSUB*CPAD];
  __shared__ float s_z[TSUB*SPAD];
  __shared__ float s_xdbc[TSUB*JPAD];
  __shared__ float w_in_t[DMODEL*164];
  __shared__ float w_xp_t[DIN*35];
  __shared__ float s_cw[DIN*4];
  __shared__ float s_cb[DIN];
  __shared__ float s_dtw[DIN*3];
  __shared__ float s_dtb[DIN];

  const int tid=threadIdx.x;
  const int b=blockIdx.x/NCHUNK, c=blockIdx.x%NCHUNK, l0c=c*CHUNK;
  constexpr int NJ=(PASS==3)?35:19;
  constexpr int NE=(PASS==3)?164:DIN;

  for (int i=tid;i<DMODEL*164;i+=256){ int k=i/164,e=i-k*164; w_in_t[i]=w_in[e*DMODEL+k]; }
  for (int i=tid;i<DIN*35;i+=256){ int dd=i/35,j=i-dd*35; w_xp_t[i]=w_xproj[j*DIN+dd]; }
  for (int i=tid;i<DIN*4;i+=256) s_cw[i]=w_conv[i];
  for (int i=tid;i<DIN*3;i+=256) s_dtw[i]=w_dt[i];
  if (tid<DIN){ s_cb[tid]=b_conv[tid]; s_dtb[tid]=b_dt[tid]; }

  float h[NSTATE], Pp[NSTATE], As[NSTATE];
  float A0=-1.f, Dd=0.f;
  bool structured=true;
  if (tid<DIN){
#pragma unroll
    for (int s=0;s<NSTATE;++s) As[s]=-expf(A_log[tid*NSTATE+s]);
    A0=As[0];
#pragma unroll
    for (int s=0;s<NSTATE;++s)
      structured = structured && (fabsf(As[s]-(float)(s+1)*A0)<=1e-3f*(float)(s+1)*fabsf(A0));
    structured = structured && (A0<0.f);
    if (PASS==3){
      Dd=Dvec[tid];
      size_t base=((size_t)(b*NCHUNK+c))*(DIN*NSTATE)+(size_t)tid*NSTATE;
#pragma unroll
      for (int s=0;s<NSTATE;++s) h[s]=Hin[base+s];
    } else {
#pragma unroll
      for (int s=0;s<NSTATE;++s){ h[s]=0.f; Pp[s]=1.f; }
    }
  }
  __syncthreads();

  for (int t=0;t<NSUB;++t){
    const int p0=l0c+t*TSUB;
    for (int i=tid;i<RWS*DMODEL;i+=256){
      int r=i/DMODEL,k=i-r*DMODEL;
      int pos=p0-3+r;
      s_x[r*XPAD+k]=(pos>=0)?xg[(size_t)b*SEQ*DMODEL+(size_t)pos*DMODEL+k]:0.f;
    }
    __syncthreads();
    {
      const int e=tid;
      if (e<NE){
        float acc[RWS];
#pragma unroll
        for (int r=0;r<RWS;++r) acc[r]=0.f;
#pragma unroll
        for (int kq=0;kq<40;kq+=4){
          const float w0=w_in_t[(kq+0)*164+e], w1=w_in_t[(kq+1)*164+e];
          const float w2=w_in_t[(kq+2)*164+e], w3=w_in_t[(kq+3)*164+e];
#pragma unroll
          for (int r=0;r<RWS;++r){
            const float4 xv=*(const float4*)&s_x[r*XPAD+kq];
            acc[r]=fmaf(xv.x,w0,acc[r]); acc[r]=fmaf(xv.y,w1,acc[r]);
            acc[r]=fmaf(xv.z,w2,acc[r]); acc[r]=fmaf(xv.w,w3,acc[r]);
          }
        }
        const float wl=w_in_t[40*164+e];
#pragma unroll
        for (int r=0;r<RWS;++r) acc[r]=fmaf(s_x[r*XPAD+40],wl,acc[r]);
        if (e<DIN){
#pragma unroll
          for (int r=0;r<RWS;++r) s_xs[r*SPAD+e]=acc[r];
        } else {
#pragma unroll
          for (int r=3;r<RWS;++r) s_z[(r-3)*SPAD+(e-DIN)]=acc[r];
        }
      }
    }
    __syncthreads();
    for (int w=tid;w<TSUB*DIN;w+=256){
      const int l=w&15,e=w>>4;
      float a=s_cb[e];
#pragma unroll
      for (int k=0;k<4;++k) a=fmaf(s_xs[(l+k)*SPAD+e],s_cw[e*4+k],a);
      s_xc[l*CPAD+e]=siluf(a);
    }
    __syncthreads();
    for (int w=tid;w<TSUB*NJ;w+=256){
      const int l=w&15,j=w>>4;
      float a=0.f;
#pragma unroll
      for (int dq=0;dq<80;dq+=4){
        const float4 xv=*(const float4*)&s_xc[l*CPAD+dq];
        a=fmaf(xv.x,w_xp_t[(dq+0)*35+j],a); a=fmaf(xv.y,w_xp_t[(dq+1)*35+j],a);
        a=fmaf(xv.z,w_xp_t[(dq+2)*35+j],a); a=fmaf(xv.w,w_xp_t[(dq+3)*35+j],a);
      }
      a=fmaf(s_xc[l*CPAD+80],w_xp_t[80*35+j],a);
      a=fmaf(s_xc[l*CPAD+81],w_xp_t[81*35+j],a);
      const int col=(j<3)?j:j+1;
      s_xdbc[l*JPAD+col]=a;
    }
    __syncthreads();
    for (int w=tid;w<TSUB*DIN;w+=256){
      const int l=w&15,dd=w>>4;
      float a=s_dtb[dd];
      a=fmaf(s_xdbc[l*JPAD+0],s_dtw[dd*3+0],a);
      a=fmaf(s_xdbc[l*JPAD+1],s_dtw[dd*3+1],a);
      a=fmaf(s_xdbc[l*JPAD+2],s_dtw[dd*3+2],a);
      s_xs[l*SPAD+dd]=softplusf(a);
    }
    __syncthreads();
    if (tid<DIN){
      const int dd=tid;
#pragma unroll 1
      for (int l=0;l<TSUB;++l){
        const float dl=s_xs[l*SPAD+dd];
        const float xcd=s_xc[l*CPAD+dd];
        const float dxc=dl*xcd;
        const float4 B0=*(const float4*)&s_xdbc[l*JPAD+4];
        const float4 B1=*(const float4*)&s_xdbc[l*JPAD+8];
        const float4 B2=*(const float4*)&s_xdbc[l*JPAD+12];
        const float4 B3=*(const float4*)&s_xdbc[l*JPAD+16];
        const float Bv[NSTATE]={B0.x,B0.y,B0.z,B0.w,B1.x,B1.y,B1.z,B1.w,
                                B2.x,B2.y,B2.z,B2.w,B3.x,B3.y,B3.z,B3.w};
        float Cv[NSTATE];
        if (PASS==3){
          const float4 C0=*(const float4*)&s_xdbc[l*JPAD+20];
          const float4 C1=*(const float4*)&s_xdbc[l*JPAD+24];
          const float4 C2=*(const float4*)&s_xdbc[l*JPAD+28];
          const float4 C3=*(const float4*)&s_xdbc[l*JPAD+32];
          Cv[0]=C0.x;Cv[1]=C0.y;Cv[2]=C0.z;Cv[3]=C0.w;
          Cv[4]=C1.x;Cv[5]=C1.y;Cv[6]=C1.z;Cv[7]=C1.w;
          Cv[8]=C2.x;Cv[9]=C2.y;Cv[10]=C2.z;Cv[11]=C2.w;
          Cv[12]=C3.x;Cv[13]=C3.y;Cv[14]=C3.z;Cv[15]=C3.w;
        }
        float y=(PASS==3)?Dd*xcd:0.f;
        if (structured){
          const float q=expf(dl*A0);
          float e=q;
#pragma unroll
          for (int s=0;s<NSTATE;++s){
            h[s]=fmaf(e,h[s],dxc*Bv[s]);
            if (PASS==1) Pp[s]*=e; else y=fmaf(h[s],Cv[s],y);
            if (s<NSTATE-1) e*=q;
          }
        } else {
#pragma unroll
          for (int s=0;s<NSTATE;++s){
            const float e=expf(dl*As[s]);
            h[s]=fmaf(e,h[s],dxc*Bv[s]);
            if (PASS==1) Pp[s]*=e; else y=fmaf(h[s],Cv[s],y);
          }
        }
        if (PASS==3) s_xs[l*SPAD+dd]=y;
      }
    }
    __syncthreads();
    if (PASS==3){
      for (int w=tid;w<TSUB*DIN;w+=256){
        const int l=w&15,dd=w>>4;
        s_xc[l*CPAD+dd]=s_xs[l*SPAD+dd]*siluf(s_z[l*SPAD+dd]);
      }
      __syncthreads();
      for (int w=tid;w<TSUB*DMODEL;w+=256){
        const int l=w&15,dm=w>>4;
        const float2* wp=(const float2*)(w_out+dm*DIN);
        const float2* gp=(const float2*)&s_xc[l*CPAD];
        float a=0.f;
#pragma unroll
        for (int dq=0;dq<41;++dq){
          const float2 wv=wp[dq], gv=gp[dq];
          a=fmaf(wv.x,gv.x,a); a=fmaf(wv.y,gv.y,a);
        }
        s_x[l*XPAD+dm]=a;
      }
      __syncthreads();
      for (int w=tid;w<TSUB*NLAB;w+=256){
        const int l=w&15,n=w>>4;
        float a=b_cls[n];
#pragma unroll
        for (int dm=0;dm<DMODEL;++dm) a=fmaf(w_cls[n*DMODEL+dm],s_x[l*XPAD+dm],a);
        s_xdbc[l*NLAB+n]=a;
      }
      __syncthreads();
      for (int i=tid;i<TSUB*NLAB;i+=256)
        outg[((size_t)(b*SEQ+p0))*NLAB+i]=s_xdbc[i];
      __syncthreads();
    }
  }

  if (PASS==1 && tid<DIN){
    size_t base=((size_t)(b*NCHUNK+c))*(DIN*NSTATE)+(size_t)tid*NSTATE;
#pragma unroll
    for (int s=0;s<NSTATE;++s){ Pg[base+s]=Pp[s]; Hg[base+s]=h[s]; }
  }
}

__global__ __launch_bounds__(256) void mamba_combine(
    const float* __restrict__ P, const float* __restrict__ H, float* __restrict__ Hin){
  const int g=blockIdx.x*256+threadIdx.x;
  const int b=g/(DIN*NSTATE), ds=g-b*(DIN*NSTATE);
  float h=0.f;
#pragma unroll 1
  for (int c=0;c<NCHUNK;++c){
    const size_t idx=((size_t)(b*NCHUNK+c))*(DIN*NSTATE)+ds;
    Hin[idx]=h;
    h=fmaf(P[idx],h,H[idx]);
  }
}

// ============================================================================

extern "C" void kernel_launch(void* const* d_in, const int* in_sizes, int n_in,
                              void* d_out, int out_size, void* d_ws, size_t ws_size,
                              hipStream_t stream) {
  const float* xg     = (const float*)d_in[0];
  const float* w_in   = (const float*)d_in[1];
  const float* w_conv = (const float*)d_in[2];
  const float* b_conv = (const float*)d_in[3];
  const float* w_xp   = (const float*)d_in[4];
  const float* w_dt   = (const float*)d_in[5];
  const float* b_dt   = (const float*)d_in[6];
  const float* A_log  = (const float*)d_in[7];
  const float* Dv     = (const float*)d_in[8];
  const float* w_out  = (const float*)d_in[9];
  const float* w_cls  = (const float*)d_in[10];
  const float* b_cls  = (const float*)d_in[11];
  float* outg = (float*)d_out;

  int P = 0;
  for (int p : {1,2,4,8}) if (ws_size >= tier_bytes(p)) { P = p; break; }

  if (P) {
    const int SEG = SEQ/P, tiles = SEG/T0;
    const size_t featF = (size_t)BATCH*SEG*FREC;
    const size_t phF   = (size_t)BATCH*tiles*1312;
    float* feat  = (float*)d_ws;
    float* Pg    = feat + featF;
    float* Hg    = Pg + phF;
    float* Hin   = Hg + phF;
    float* carry = Hin + phF;
    float* Mg    = carry + (size_t)BATCH*1312;
    k_pre<<<dim3(4),256,0,stream>>>(w_out, w_cls, Mg);
    for (int p=0;p<P;p++){
      const int off = p*SEG;
      k0_feat<<<dim3(tiles,BATCH),256,0,stream>>>(
          xg,w_in,w_conv,b_conv,w_xp,w_dt,b_dt,A_log,Dv,off,SEG,feat,Pg,Hg);
      k2_comb<<<dim3((BATCH*1312)/256),256,0,stream>>>(Pg,Hg,Hin,carry,tiles,p==0?1:0);
      k4_out<<<dim3(tiles,BATCH),256,0,stream>>>(
          xg,w_in,A_log,Mg,b_cls,off,SEG,feat,Hin,outg);
    }
  } else {
    float* Pg  = (float*)d_ws;
    float* Hg  = Pg + NPH_OLD;
    float* Hin = Hg + NPH_OLD;
    dim3 grid(BATCH*NCHUNK), blk(256);
    mamba_chunk<1><<<grid,blk,0,stream>>>(xg,w_in,w_conv,b_conv,w_xp,w_dt,b_dt,
                                          A_log,Dv,w_out,w_cls,b_cls,Pg,Hg,nullptr,nullptr);
    mamba_combine<<<dim3((BATCH*DIN*NSTATE)/256),blk,0,stream>>>(Pg,Hg,Hin);
    mamba_chunk<3><<<grid,blk,0,stream>>>(xg,w_in,w_conv,b_conv,w_xp,w_dt,b_dt,
                                          A_log,Dv,w_out,w_cls,b_cls,nullptr,nullptr,Hin,outg);
  }
}